// Round 2
// baseline (2703.600 us; speedup 1.0000x reference)
//
#include <hip/hip_runtime.h>

// ---------------- types ----------------
typedef __attribute__((ext_vector_type(4))) float f32x4;
typedef __attribute__((ext_vector_type(8))) __bf16 bf16x8;
typedef __attribute__((ext_vector_type(4))) __bf16 bf16x4;

#define D_MODEL 2560
#define D_INNER 5120
#define N_STATE 128
#define HEADS 80
#define P_HEAD 64
#define CONV_DIM 5376
#define D_INPROJ 10576
#define SEQ 1024
#define NCHUNK 16
#define QCHUNK 64
#define NEXP 16
#define M_INTER 864
#define MS_INTER 1728

__device__ __forceinline__ float siluf(float x) { return x / (1.f + __expf(-x)); }

__device__ __forceinline__ float block_sum256(float v, float* red) {
#pragma unroll
  for (int m = 32; m > 0; m >>= 1) v += __shfl_xor(v, m, 64);
  int w = threadIdx.x >> 6;
  if ((threadIdx.x & 63) == 0) red[w] = v;
  __syncthreads();
  return red[0] + red[1] + red[2] + red[3];
}

// ---------------- RMSNorm ----------------
__global__ __launch_bounds__(256) void k_rmsnorm(const float* __restrict__ in,
                                                 const float* __restrict__ w,
                                                 float* __restrict__ out, int D) {
  __shared__ float red[4];
  int t = blockIdx.x, tid = threadIdx.x;
  const float* x = in + (size_t)t * D;
  int nd4 = D >> 2;
  float ss = 0.f;
  for (int i = tid; i < nd4; i += 256) {
    float4 v = ((const float4*)x)[i];
    ss += v.x * v.x + v.y * v.y + v.z * v.z + v.w * v.w;
  }
  float tot = block_sum256(ss, red);
  float r = rsqrtf(tot / (float)D + 1e-6f);
  for (int i = tid; i < nd4; i += 256) {
    float4 v = ((const float4*)x)[i];
    float4 wv = ((const float4*)w)[i];
    float4 o;
    o.x = wv.x * v.x * r; o.y = wv.y * v.y * r; o.z = wv.z * v.z * r; o.w = wv.w * v.w * r;
    ((float4*)(out + (size_t)t * D))[i] = o;
  }
}

// ---------------- generic bf16-MFMA GEMM, 128x128 tile, BK=32 ----------------
// MODE 0: C = A@B (dense)      MODE 1: C = A@B + res (dense)
// MODE 2: expert, A rows gathered via perm (gate/up)   MODE 3: expert, A rows = slots (down)
// SPLIT: 3-pass split-bf16 (hi/lo) for ~fp32 accuracy — used on the router-feeding path.
template <int MODE, bool SPLIT>
__global__ __launch_bounds__(256) void k_gemm(const float* __restrict__ A,
                                              const float* __restrict__ Bg,
                                              float* __restrict__ C,
                                              const float* __restrict__ res,
                                              const int* __restrict__ perm,
                                              const int* __restrict__ expOff,
                                              const int* __restrict__ expCnt,
                                              int M, int N, int K, long long strideB) {
  __shared__ __bf16 Als[SPLIT ? 2 : 1][128][40];   // [hi/lo][row][k] pad 40
  __shared__ __bf16 Bls[SPLIT ? 2 : 1][4][1088];   // [hi/lo][kgroup][col*8 + (k&7)]
  int tid = threadIdx.x;
  int bm = blockIdx.y, bn = blockIdx.x;
  int cnt = 0, base = 0;
  const float* Bp = Bg;
  if constexpr (MODE >= 2) {
    int e = blockIdx.z;
    cnt = expCnt[e];
    base = expOff[e];
    if (bm * 128 >= cnt) return;
    Bp += (long long)e * strideB;
  }
  int rowBase = bm * 128, colBase = bn * 128;
  int lane = tid & 63, wid = tid >> 6;
  int wr = wid >> 1, wc = wid & 1;
  int kl = lane >> 4, l16 = lane & 15;

  int arow[4]; bool avalid[4];
#pragma unroll
  for (int i = 0; i < 4; i++) {
    int id = tid + 256 * i;
    int rl = rowBase + (id >> 3);
    if constexpr (MODE == 2) { avalid[i] = rl < cnt; arow[i] = avalid[i] ? perm[base + rl] : 0; }
    else if constexpr (MODE == 3) { avalid[i] = rl < cnt; arow[i] = base + rl; }
    else { avalid[i] = rl < M; arow[i] = rl; }
  }

  f32x4 acc[4][4];
#pragma unroll
  for (int mi = 0; mi < 4; mi++)
#pragma unroll
    for (int ni = 0; ni < 4; ni++) acc[mi][ni] = f32x4{0.f, 0.f, 0.f, 0.f};

  for (int k0 = 0; k0 < K; k0 += 32) {
    __syncthreads();
    // stage A: 128x32 f32 -> bf16 (hi, and lo if SPLIT)
#pragma unroll
    for (int i = 0; i < 4; i++) {
      int id = tid + 256 * i;
      int r = id >> 3, k4 = (id & 7) * 4;
      float4 v = float4{0.f, 0.f, 0.f, 0.f};
      if (avalid[i]) v = *(const float4*)&A[(size_t)arow[i] * K + k0 + k4];
      bf16x4 hi; hi[0] = (__bf16)v.x; hi[1] = (__bf16)v.y; hi[2] = (__bf16)v.z; hi[3] = (__bf16)v.w;
      *(bf16x4*)&Als[0][r][k4] = hi;
      if constexpr (SPLIT) {
        bf16x4 lo;
        lo[0] = (__bf16)(v.x - (float)hi[0]); lo[1] = (__bf16)(v.y - (float)hi[1]);
        lo[2] = (__bf16)(v.z - (float)hi[2]); lo[3] = (__bf16)(v.w - (float)hi[3]);
        *(bf16x4*)&Als[1][r][k4] = lo;
      }
    }
    // stage B: 32x128
#pragma unroll
    for (int i = 0; i < 4; i++) {
      int id = tid + 256 * i;       // 0..1023: col = id&127, kq = id>>7 (4 k each)
      int col = id & 127, kq = id >> 7;
      int gc = colBase + col;
      int k = k0 + kq * 4;
      float v0 = 0, v1 = 0, v2 = 0, v3 = 0;
      if (gc < N) {
        v0 = Bp[(size_t)(k + 0) * N + gc];
        v1 = Bp[(size_t)(k + 1) * N + gc];
        v2 = Bp[(size_t)(k + 2) * N + gc];
        v3 = Bp[(size_t)(k + 3) * N + gc];
      }
      bf16x4 hi; hi[0] = (__bf16)v0; hi[1] = (__bf16)v1; hi[2] = (__bf16)v2; hi[3] = (__bf16)v3;
      *(bf16x4*)&Bls[0][kq >> 1][col * 8 + (kq & 1) * 4] = hi;
      if constexpr (SPLIT) {
        bf16x4 lo;
        lo[0] = (__bf16)(v0 - (float)hi[0]); lo[1] = (__bf16)(v1 - (float)hi[1]);
        lo[2] = (__bf16)(v2 - (float)hi[2]); lo[3] = (__bf16)(v3 - (float)hi[3]);
        *(bf16x4*)&Bls[1][kq >> 1][col * 8 + (kq & 1) * 4] = lo;
      }
    }
    __syncthreads();
    bf16x8 ah[4], bh[4];
#pragma unroll
    for (int mi = 0; mi < 4; mi++)
      ah[mi] = *(const bf16x8*)&Als[0][wr * 64 + mi * 16 + l16][kl * 8];
#pragma unroll
    for (int ni = 0; ni < 4; ni++)
      bh[ni] = *(const bf16x8*)&Bls[0][kl][(wc * 64 + ni * 16 + l16) * 8];
#pragma unroll
    for (int mi = 0; mi < 4; mi++)
#pragma unroll
      for (int ni = 0; ni < 4; ni++)
        acc[mi][ni] = __builtin_amdgcn_mfma_f32_16x16x32_bf16(ah[mi], bh[ni], acc[mi][ni], 0, 0, 0);
    if constexpr (SPLIT) {
      bf16x8 al[4], bl[4];
#pragma unroll
      for (int mi = 0; mi < 4; mi++)
        al[mi] = *(const bf16x8*)&Als[1][wr * 64 + mi * 16 + l16][kl * 8];
#pragma unroll
      for (int ni = 0; ni < 4; ni++)
        bl[ni] = *(const bf16x8*)&Bls[1][kl][(wc * 64 + ni * 16 + l16) * 8];
#pragma unroll
      for (int mi = 0; mi < 4; mi++)
#pragma unroll
        for (int ni = 0; ni < 4; ni++) {
          acc[mi][ni] = __builtin_amdgcn_mfma_f32_16x16x32_bf16(ah[mi], bl[ni], acc[mi][ni], 0, 0, 0);
          acc[mi][ni] = __builtin_amdgcn_mfma_f32_16x16x32_bf16(al[mi], bh[ni], acc[mi][ni], 0, 0, 0);
        }
    }
  }
  // epilogue
#pragma unroll
  for (int mi = 0; mi < 4; mi++)
#pragma unroll
    for (int ni = 0; ni < 4; ni++)
#pragma unroll
      for (int r = 0; r < 4; r++) {
        int rl = rowBase + wr * 64 + mi * 16 + (lane >> 4) * 4 + r;
        int col = colBase + wc * 64 + ni * 16 + (lane & 15);
        float v = acc[mi][ni][r];
        if constexpr (MODE >= 2) {
          if (rl < cnt && col < N) C[(size_t)(base + rl) * N + col] = v;
        } else {
          if (rl < M && col < N) {
            if constexpr (MODE == 1) v += res[(size_t)rl * N + col];
            C[(size_t)rl * N + col] = v;
          }
        }
      }
}

// ---------------- dt softplus ----------------
__global__ void k_dt(const float* __restrict__ zx, const float* __restrict__ dt_bias,
                     const float* __restrict__ A_log, float* __restrict__ dtp,
                     float* __restrict__ dtA) {
  int t = blockIdx.x, h = threadIdx.x;
  if (h < HEADS) {
    float v = zx[(size_t)t * D_INPROJ + 10496 + h] + dt_bias[h];
    float sp = fmaxf(v, 0.f) + log1pf(expf(-fabsf(v)));
    dtp[t * HEADS + h] = sp;
    dtA[t * HEADS + h] = sp * (-expf(A_log[h]));
  }
}

// ---------------- causal depthwise conv + SiLU ----------------
__global__ void k_conv(const float* __restrict__ zx, const float* __restrict__ cw,
                       const float* __restrict__ cb, float* __restrict__ xBC) {
  int cidx = blockIdx.x * 256 + threadIdx.x;
  int t = blockIdx.y;
  if (cidx < CONV_DIM) {
    float acc = cb[cidx];
#pragma unroll
    for (int j = 0; j < 4; j++) {
      int tt = t - 3 + j;
      if (tt >= 0) acc += zx[(size_t)tt * D_INPROJ + D_INNER + cidx] * cw[cidx * 4 + j];
    }
    xBC[(size_t)t * CONV_DIM + cidx] = siluf(acc);
  }
}

// ---------------- scan: intra-chunk ----------------
__global__ __launch_bounds__(256) void k_scan_intra(
    const float* __restrict__ xBC, const float* __restrict__ dtp,
    const float* __restrict__ dtA, float* __restrict__ y, float* __restrict__ S,
    float* __restrict__ cumA, float* __restrict__ Atot) {
  __shared__ float Bs[64][132];
  __shared__ float Cs[64][132];
  __shared__ float Xs[64][68];
  __shared__ float Gs[64][65];
  __shared__ float da_s[64], a_s[64], dt_sh[64], w_sh[64];
  int c = blockIdx.x, h = blockIdx.y, tid = threadIdx.x;
  int t0 = c * QCHUNK;
#pragma unroll
  for (int i = 0; i < 8; i++) {
    int id = tid + 256 * i;
    int r = id >> 5, c4 = (id & 31) * 4;
    *(float4*)&Bs[r][c4] = *(const float4*)&xBC[(size_t)(t0 + r) * CONV_DIM + D_INNER + c4];
    *(float4*)&Cs[r][c4] = *(const float4*)&xBC[(size_t)(t0 + r) * CONV_DIM + D_INNER + N_STATE + c4];
  }
#pragma unroll
  for (int i = 0; i < 4; i++) {
    int id = tid + 256 * i;
    int r = id >> 4, p4 = (id & 15) * 4;
    *(float4*)&Xs[r][p4] = *(const float4*)&xBC[(size_t)(t0 + r) * CONV_DIM + h * P_HEAD + p4];
  }
  if (tid < 64) {
    da_s[tid] = dtA[(size_t)(t0 + tid) * HEADS + h];
    dt_sh[tid] = dtp[(size_t)(t0 + tid) * HEADS + h];
  }
  __syncthreads();
  if (tid < 64) {
    float a = 0.f;
    for (int i = 0; i <= tid; i++) a += da_s[i];
    a_s[tid] = a;
    cumA[((size_t)c * HEADS + h) * 64 + tid] = a;
  }
  __syncthreads();
  if (tid < 64) {
    w_sh[tid] = __expf(a_s[63] - a_s[tid]) * dt_sh[tid];
    if (tid == 0) Atot[c * HEADS + h] = a_s[63];
  }
  __syncthreads();
  // G pass: G[t][s] = (C_t . B_s) * exp(a_t - a_s) * dt_s for s<=t
  {
    int tq = tid >> 4, sq = tid & 15;
    float gacc[4][4];
#pragma unroll
    for (int j = 0; j < 4; j++)
#pragma unroll
      for (int jj = 0; jj < 4; jj++) gacc[j][jj] = 0.f;
    for (int n4 = 0; n4 < 128; n4 += 4) {
      float4 cv[4], bv[4];
#pragma unroll
      for (int j = 0; j < 4; j++) cv[j] = *(const float4*)&Cs[tq * 4 + j][n4];
#pragma unroll
      for (int j = 0; j < 4; j++) bv[j] = *(const float4*)&Bs[sq * 4 + j][n4];
#pragma unroll
      for (int j = 0; j < 4; j++)
#pragma unroll
        for (int jj = 0; jj < 4; jj++)
          gacc[j][jj] += cv[j].x * bv[jj].x + cv[j].y * bv[jj].y + cv[j].z * bv[jj].z + cv[j].w * bv[jj].w;
    }
#pragma unroll
    for (int j = 0; j < 4; j++)
#pragma unroll
      for (int jj = 0; jj < 4; jj++) {
        int t = tq * 4 + j, s = sq * 4 + jj;
        float arg = fminf(a_s[t] - a_s[s], 0.f);
        Gs[t][s] = (s <= t) ? gacc[j][jj] * __expf(arg) * dt_sh[s] : 0.f;
      }
  }
  __syncthreads();
  // Y pass: y_intra[t][p] = sum_s G[t][s] * X[s][p]
  {
    int tq = tid >> 4, pq = tid & 15;
    float4 acc[4];
#pragma unroll
    for (int j = 0; j < 4; j++) acc[j] = float4{0.f, 0.f, 0.f, 0.f};
    for (int s = 0; s < 64; s++) {
      float4 xv = *(const float4*)&Xs[s][pq * 4];
#pragma unroll
      for (int j = 0; j < 4; j++) {
        float g = Gs[tq * 4 + j][s];
        acc[j].x += g * xv.x; acc[j].y += g * xv.y; acc[j].z += g * xv.z; acc[j].w += g * xv.w;
      }
    }
#pragma unroll
    for (int j = 0; j < 4; j++) {
      int t = tq * 4 + j;
      *(float4*)&y[(size_t)(t0 + t) * D_INNER + h * P_HEAD + pq * 4] = acc[j];
    }
  }
  // S pass: S[p][n] = sum_s w[s]*X[s][p]*B[s][n]
  {
    int p2 = tid >> 5, n4 = (tid & 31) * 4;
    float4 acc[8];
#pragma unroll
    for (int j = 0; j < 8; j++) acc[j] = float4{0.f, 0.f, 0.f, 0.f};
    for (int s = 0; s < 64; s++) {
      float4 bv = *(const float4*)&Bs[s][n4];
#pragma unroll
      for (int j = 0; j < 8; j++) {
        float xw = Xs[s][p2 * 8 + j] * w_sh[s];
        acc[j].x += xw * bv.x; acc[j].y += xw * bv.y; acc[j].z += xw * bv.z; acc[j].w += xw * bv.w;
      }
    }
    size_t bb = ((size_t)(c * HEADS + h) * 64) * 128;
#pragma unroll
    for (int j = 0; j < 8; j++)
      *(float4*)&S[bb + (size_t)(p2 * 8 + j) * 128 + n4] = acc[j];
  }
}

// ---------------- scan: inter-chunk state recurrence (in-place S -> Hin) ----------------
__global__ void k_scan_state(float* __restrict__ S, const float* __restrict__ Atot) {
  int gid = blockIdx.x * 256 + threadIdx.x;
  int h = gid >> 13;
  int rem = gid & 8191;
  float run = 0.f;
#pragma unroll
  for (int c = 0; c < NCHUNK; c++) {
    size_t idx = ((size_t)(c * HEADS + h) << 13) + rem;
    float s = S[idx];
    S[idx] = run;
    run = run * __expf(Atot[c * HEADS + h]) + s;
  }
}

// ---------------- scan: add inter-chunk contribution + D*x ----------------
__global__ __launch_bounds__(256) void k_scan_inter(
    const float* __restrict__ xBC, const float* __restrict__ Hin,
    const float* __restrict__ cumA, const float* __restrict__ Dv,
    float* __restrict__ y) {
  __shared__ float Hs[64][132];
  __shared__ float Cs[64][132];
  __shared__ float a_l[64];
  int c = blockIdx.x, h = blockIdx.y, tid = threadIdx.x;
  int t0 = c * QCHUNK;
#pragma unroll
  for (int i = 0; i < 8; i++) {
    int id = tid + 256 * i;
    int r = id >> 5, n4 = (id & 31) * 4;
    *(float4*)&Hs[r][n4] = *(const float4*)&Hin[(((size_t)(c * HEADS + h) * 64 + r) << 7) + n4];
    *(float4*)&Cs[r][n4] = *(const float4*)&xBC[(size_t)(t0 + r) * CONV_DIM + D_INNER + N_STATE + n4];
  }
  if (tid < 64) a_l[tid] = cumA[((size_t)c * HEADS + h) * 64 + tid];
  __syncthreads();
  float Dh = Dv[h];
  int tq = tid >> 4, pq = tid & 15;
  float4 acc[4];
#pragma unroll
  for (int j = 0; j < 4; j++) acc[j] = float4{0.f, 0.f, 0.f, 0.f};
  for (int n4 = 0; n4 < 128; n4 += 4) {
    float4 hv[4], cv[4];
#pragma unroll
    for (int jj = 0; jj < 4; jj++) hv[jj] = *(const float4*)&Hs[pq * 4 + jj][n4];
#pragma unroll
    for (int j = 0; j < 4; j++) cv[j] = *(const float4*)&Cs[tq * 4 + j][n4];
#pragma unroll
    for (int j = 0; j < 4; j++) {
      acc[j].x += cv[j].x * hv[0].x + cv[j].y * hv[0].y + cv[j].z * hv[0].z + cv[j].w * hv[0].w;
      acc[j].y += cv[j].x * hv[1].x + cv[j].y * hv[1].y + cv[j].z * hv[1].z + cv[j].w * hv[1].w;
      acc[j].z += cv[j].x * hv[2].x + cv[j].y * hv[2].y + cv[j].z * hv[2].z + cv[j].w * hv[2].w;
      acc[j].w += cv[j].x * hv[3].x + cv[j].y * hv[3].y + cv[j].z * hv[3].z + cv[j].w * hv[3].w;
    }
  }
#pragma unroll
  for (int j = 0; j < 4; j++) {
    int t = tq * 4 + j;
    float e = __expf(a_l[t]);
    float4 xv = *(const float4*)&xBC[(size_t)(t0 + t) * CONV_DIM + h * P_HEAD + pq * 4];
    size_t yoff = (size_t)(t0 + t) * D_INNER + h * P_HEAD + pq * 4;
    float4 yv = *(float4*)&y[yoff];
    yv.x += e * acc[j].x + Dh * xv.x;
    yv.y += e * acc[j].y + Dh * xv.y;
    yv.z += e * acc[j].z + Dh * xv.z;
    yv.w += e * acc[j].w + Dh * xv.w;
    *(float4*)&y[yoff] = yv;
  }
}

// ---------------- gated RMSNorm: y = rms(y * silu(z)) * w ----------------
__global__ __launch_bounds__(256) void k_gatednorm(float* __restrict__ y,
                                                   const float* __restrict__ zx,
                                                   const float* __restrict__ w) {
  __shared__ float vbuf[D_INNER];
  __shared__ float red[4];
  int t = blockIdx.x, tid = threadIdx.x;
  float ss = 0.f;
  for (int i = tid; i < D_INNER / 4; i += 256) {
    float4 yv = *(const float4*)&y[(size_t)t * D_INNER + i * 4];
    float4 zv = *(const float4*)&zx[(size_t)t * D_INPROJ + i * 4];
    float4 v;
    v.x = yv.x * siluf(zv.x); v.y = yv.y * siluf(zv.y);
    v.z = yv.z * siluf(zv.z); v.w = yv.w * siluf(zv.w);
    *(float4*)&vbuf[i * 4] = v;
    ss += v.x * v.x + v.y * v.y + v.z * v.z + v.w * v.w;
  }
  float tot = block_sum256(ss, red);
  float r = rsqrtf(tot / (float)D_INNER + 1e-6f);
  for (int i = tid; i < D_INNER / 4; i += 256) {
    float4 v = *(const float4*)&vbuf[i * 4];
    float4 wv = *(const float4*)&w[i * 4];
    float4 o;
    o.x = wv.x * v.x * r; o.y = wv.y * v.y * r; o.z = wv.z * v.z * r; o.w = wv.w * v.w * r;
    *(float4*)&y[(size_t)t * D_INNER + i * 4] = o;
  }
}

// ---------------- router ----------------
__global__ void k_zero(int* counts, int* cursor) {
  int i = threadIdx.x;
  if (i < NEXP) { counts[i] = 0; cursor[i] = 0; }
}

__global__ __launch_bounds__(256) void k_router(const float* __restrict__ xm,
                                                const float* __restrict__ Wr,
                                                int* __restrict__ top_i,
                                                float* __restrict__ top_v,
                                                int* __restrict__ counts) {
  __shared__ float part[16][17];
  __shared__ float lg[16];
  int t = blockIdx.x, tid = threadIdx.x;
  int e = tid & 15, seg = tid >> 4;
  const float* xr = xm + (size_t)t * D_MODEL;
  float s = 0.f;
  for (int i = 0; i < 160; i++) {
    int k = seg * 160 + i;
    s += xr[k] * Wr[(size_t)k * NEXP + e];
  }
  part[seg][e] = s;
  __syncthreads();
  if (tid < 16) {
    float l = 0.f;
    for (int g = 0; g < 16; g++) l += part[g][tid];
    lg[tid] = l;
  }
  __syncthreads();
  if (tid == 0) {
    float mx = lg[0];
    for (int i = 1; i < 16; i++) mx = fmaxf(mx, lg[i]);
    float pe[16];
    for (int i = 0; i < 16; i++) pe[i] = expf(lg[i] - mx);
    int i0 = 0; float v0 = pe[0];
    for (int i = 1; i < 16; i++) if (pe[i] > v0) { v0 = pe[i]; i0 = i; }
    int i1 = -1; float v1 = -1.f;
    for (int i = 0; i < 16; i++) if (i != i0 && pe[i] > v1) { v1 = pe[i]; i1 = i; }
    float inv = 1.f / (v0 + v1);
    top_i[t * 2] = i0; top_i[t * 2 + 1] = i1;
    top_v[t * 2] = v0 * inv; top_v[t * 2 + 1] = v1 * inv;
    atomicAdd(&counts[i0], 1);
    atomicAdd(&counts[i1], 1);
  }
}

__global__ void k_offsets(const int* counts, int* offs, int* cursor) {
  if (threadIdx.x == 0) {
    int s = 0;
    for (int e = 0; e < NEXP; e++) { offs[e] = s; cursor[e] = s; s += counts[e]; }
  }
}

__global__ void k_scatter(const int* __restrict__ top_i, const float* __restrict__ top_v,
                          int* __restrict__ cursor, int* __restrict__ perm,
                          int* __restrict__ slotOf, float* __restrict__ slotw) {
  int t = blockIdx.x * 256 + threadIdx.x;
  if (t < SEQ) {
    for (int k = 0; k < 2; k++) {
      int e = top_i[t * 2 + k];
      int pos = atomicAdd(&cursor[e], 1);
      perm[pos] = t;
      slotOf[t * 2 + k] = pos;
      slotw[pos] = top_v[t * 2 + k];
    }
  }
}

// ---------------- silu-mul (+ optional per-row scale) ----------------
__global__ void k_silumul(float* __restrict__ g, const float* __restrict__ u,
                          const float* __restrict__ slotw, int cols) {
  int r = blockIdx.x, tid = threadIdx.x;
  float w = slotw ? slotw[r] : 1.f;
  for (int i = tid; i < cols / 4; i += 256) {
    float4 gv = *(const float4*)&g[(size_t)r * cols + i * 4];
    float4 uv = *(const float4*)&u[(size_t)r * cols + i * 4];
    gv.x = siluf(gv.x) * uv.x * w;
    gv.y = siluf(gv.y) * uv.y * w;
    gv.z = siluf(gv.z) * uv.z * w;
    gv.w = siluf(gv.w) * uv.w * w;
    *(float4*)&g[(size_t)r * cols + i * 4] = gv;
  }
}

// ---------------- final combine ----------------
__global__ void k_final(const float* __restrict__ hidden, const float* __restrict__ sh,
                        const float* __restrict__ ds, const int* __restrict__ slotOf,
                        float* __restrict__ out) {
  int t = blockIdx.y;
  int d4 = (blockIdx.x * 256 + threadIdx.x) * 4;
  if (d4 < D_MODEL) {
    int s0 = slotOf[t * 2], s1 = slotOf[t * 2 + 1];
    float4 a = *(const float4*)&hidden[(size_t)t * D_MODEL + d4];
    float4 b = *(const float4*)&sh[(size_t)t * D_MODEL + d4];
    float4 c0 = *(const float4*)&ds[(size_t)s0 * D_MODEL + d4];
    float4 c1 = *(const float4*)&ds[(size_t)s1 * D_MODEL + d4];
    float4 o;
    o.x = a.x + b.x + c0.x + c1.x;
    o.y = a.y + b.y + c0.y + c1.y;
    o.z = a.z + b.z + c0.z + c1.z;
    o.w = a.w + b.w + c0.w + c1.w;
    *(float4*)&out[(size_t)t * D_MODEL + d4] = o;
  }
}

// ---------------- launch ----------------
extern "C" void kernel_launch(void* const* d_in, const int* in_sizes, int n_in,
                              void* d_out, int out_size, void* d_ws, size_t ws_size,
                              hipStream_t stream) {
  const float* hs = (const float*)d_in[0];
  const float* w_in = (const float*)d_in[1];
  const float* conv_w = (const float*)d_in[2];
  const float* conv_b = (const float*)d_in[3];
  const float* dt_bias = (const float*)d_in[4];
  const float* A_log = (const float*)d_in[5];
  const float* Dv = (const float*)d_in[6];
  const float* mnw = (const float*)d_in[7];
  const float* w_out = (const float*)d_in[8];
  const float* ln1 = (const float*)d_in[9];
  const float* ln2 = (const float*)d_in[10];
  const float* router_w = (const float*)d_in[11];
  const float* we_gate = (const float*)d_in[12];
  const float* we_up = (const float*)d_in[13];
  const float* we_down = (const float*)d_in[14];
  const float* ws_gate = (const float*)d_in[15];
  const float* ws_up = (const float*)d_in[16];
  const float* ws_down = (const float*)d_in[17];

  float* ws = (float*)d_ws;
  size_t off = 0;
  auto alloc = [&](size_t n) { float* p = ws + off; off += (n + 3) & ~(size_t)3; return p; };
  float* zx = alloc((size_t)SEQ * D_INPROJ);
  float* xbc = alloc((size_t)SEQ * CONV_DIM);
  float* x1 = alloc((size_t)SEQ * D_MODEL);       // norm1 out; later reused as xm2
  float* dtp = alloc((size_t)SEQ * HEADS);
  float* dtA = alloc((size_t)SEQ * HEADS);
  float* yb = alloc((size_t)SEQ * D_INNER);
  float* cumA = alloc((size_t)NCHUNK * HEADS * 64);
  float* Atot = alloc((size_t)NCHUNK * HEADS);
  float* S = alloc((size_t)NCHUNK * HEADS * 64 * 128);
  float* hidden = alloc((size_t)SEQ * D_MODEL);
  float* shout = alloc((size_t)SEQ * D_MODEL);
  float* gbuf = alloc((size_t)2048 * M_INTER);    // == 1024*1728
  float* ubuf = alloc((size_t)2048 * M_INTER);
  float* dslots = alloc((size_t)2048 * D_MODEL);
  float* top_v = alloc(2048);
  float* slotw = alloc(2048);
  int* top_i = (int*)alloc(2048);
  int* counts = (int*)alloc(16);
  int* offs = (int*)alloc(16);
  int* cursor = (int*)alloc(16);
  int* perm = (int*)alloc(2048);
  int* slotOf = (int*)alloc(2048);

  // ---- Mamba sub-block ----
  k_rmsnorm<<<SEQ, 256, 0, stream>>>(hs, ln1, x1, D_MODEL);
  k_gemm<0, true><<<dim3(83, 8), 256, 0, stream>>>(x1, w_in, zx, nullptr, nullptr, nullptr, nullptr,
                                                   SEQ, D_INPROJ, D_MODEL, 0);
  k_dt<<<SEQ, 128, 0, stream>>>(zx, dt_bias, A_log, dtp, dtA);
  k_conv<<<dim3(21, SEQ), 256, 0, stream>>>(zx, conv_w, conv_b, xbc);
  k_scan_intra<<<dim3(NCHUNK, HEADS), 256, 0, stream>>>(xbc, dtp, dtA, yb, S, cumA, Atot);
  k_scan_state<<<2560, 256, 0, stream>>>(S, Atot);
  k_scan_inter<<<dim3(NCHUNK, HEADS), 256, 0, stream>>>(xbc, S, cumA, Dv, yb);
  k_gatednorm<<<SEQ, 256, 0, stream>>>(yb, zx, mnw);
  k_gemm<1, true><<<dim3(20, 8), 256, 0, stream>>>(yb, w_out, hidden, hs, nullptr, nullptr, nullptr,
                                                   SEQ, D_MODEL, D_INNER, 0);

  // ---- MoE sub-block ----
  k_rmsnorm<<<SEQ, 256, 0, stream>>>(hidden, ln2, x1, D_MODEL);  // x1 = xm2
  k_zero<<<1, 64, 0, stream>>>(counts, cursor);
  k_router<<<SEQ, 256, 0, stream>>>(x1, router_w, top_i, top_v, counts);
  k_offsets<<<1, 32, 0, stream>>>(counts, offs, cursor);
  k_scatter<<<4, 256, 0, stream>>>(top_i, top_v, cursor, perm, slotOf, slotw);

  // shared experts (gbuf/ubuf viewed as [1024][1728])
  k_gemm<0, false><<<dim3(14, 8), 256, 0, stream>>>(x1, ws_gate, gbuf, nullptr, nullptr, nullptr, nullptr,
                                                    SEQ, MS_INTER, D_MODEL, 0);
  k_gemm<0, false><<<dim3(14, 8), 256, 0, stream>>>(x1, ws_up, ubuf, nullptr, nullptr, nullptr, nullptr,
                                                    SEQ, MS_INTER, D_MODEL, 0);
  k_silumul<<<SEQ, 256, 0, stream>>>(gbuf, ubuf, nullptr, MS_INTER);
  k_gemm<0, false><<<dim3(20, 8), 256, 0, stream>>>(gbuf, ws_down, shout, nullptr, nullptr, nullptr, nullptr,
                                                    SEQ, D_MODEL, MS_INTER, 0);

  // routed experts (gbuf/ubuf reused as [2048][864])
  k_gemm<2, false><<<dim3(7, 8, NEXP), 256, 0, stream>>>(x1, we_gate, gbuf, nullptr, perm, offs, counts,
                                                         0, M_INTER, D_MODEL, (long long)D_MODEL * M_INTER);
  k_gemm<2, false><<<dim3(7, 8, NEXP), 256, 0, stream>>>(x1, we_up, ubuf, nullptr, perm, offs, counts,
                                                         0, M_INTER, D_MODEL, (long long)D_MODEL * M_INTER);
  k_silumul<<<2048, 256, 0, stream>>>(gbuf, ubuf, slotw, M_INTER);
  k_gemm<3, false><<<dim3(20, 8, NEXP), 256, 0, stream>>>(gbuf, we_down, dslots, nullptr, perm, offs, counts,
                                                          0, D_MODEL, M_INTER, (long long)M_INTER * D_MODEL);

  k_final<<<dim3(3, SEQ), 256, 0, stream>>>(hidden, shout, dslots, slotOf, (float*)d_out);
}

// Round 3
// 1384.290 us; speedup vs baseline: 1.9531x; 1.9531x over previous
//
#include <hip/hip_runtime.h>

// ---------------- types ----------------
typedef __attribute__((ext_vector_type(4))) float f32x4;
typedef __attribute__((ext_vector_type(8))) __bf16 bf16x8;
typedef __attribute__((ext_vector_type(4))) __bf16 bf16x4;

#define D_MODEL 2560
#define D_INNER 5120
#define N_STATE 128
#define HEADS 80
#define P_HEAD 64
#define CONV_DIM 5376
#define D_INPROJ 10576
#define SEQ 1024
#define NCHUNK 16
#define QCHUNK 64
#define NEXP 16
#define M_INTER 864
#define MS_INTER 1728

__device__ __forceinline__ float siluf(float x) { return x / (1.f + __expf(-x)); }

// swizzled chunk position: within each 32-elem K-group, 16B chunk c stored at c ^ ((row>>1)&3)
__device__ __forceinline__ int swz_p(int k4, int P) {
  return (k4 & ~31) | ((((k4 >> 3) & 3) ^ P) << 3) | (k4 & 7);
}

__device__ __forceinline__ void gl16(const __bf16* g, __bf16* l) {
  __builtin_amdgcn_global_load_lds((const __attribute__((address_space(1))) unsigned int*)g,
                                   (__attribute__((address_space(3))) unsigned int*)l, 16, 0, 0);
}

__device__ __forceinline__ float block_sum256(float v, float* red) {
#pragma unroll
  for (int m = 32; m > 0; m >>= 1) v += __shfl_xor(v, m, 64);
  int w = threadIdx.x >> 6;
  if ((threadIdx.x & 63) == 0) red[w] = v;
  __syncthreads();
  return red[0] + red[1] + red[2] + red[3];
}

// ---------------- RMSNorm -> f32 (optional) + swizzled bf16 planes ----------------
__global__ __launch_bounds__(256) void k_rmsnorm_p(const float* __restrict__ in,
                                                   const float* __restrict__ w,
                                                   float* __restrict__ f32out,
                                                   __bf16* __restrict__ ph,
                                                   __bf16* __restrict__ pl, int D) {
  __shared__ float red[4];
  int t = blockIdx.x, tid = threadIdx.x;
  const float* x = in + (size_t)t * D;
  int nd4 = D >> 2;
  float ss = 0.f;
  for (int i = tid; i < nd4; i += 256) {
    float4 v = ((const float4*)x)[i];
    ss += v.x * v.x + v.y * v.y + v.z * v.z + v.w * v.w;
  }
  float tot = block_sum256(ss, red);
  float r = rsqrtf(tot / (float)D + 1e-6f);
  int P = (t >> 1) & 3;
  for (int i = tid; i < nd4; i += 256) {
    float4 v = ((const float4*)x)[i];
    float4 wv = ((const float4*)w)[i];
    float4 o;
    o.x = wv.x * v.x * r; o.y = wv.y * v.y * r; o.z = wv.z * v.z * r; o.w = wv.w * v.w * r;
    if (f32out) ((float4*)(f32out + (size_t)t * D))[i] = o;
    int p = swz_p(i * 4, P);
    bf16x4 hv;
    hv[0] = (__bf16)o.x; hv[1] = (__bf16)o.y; hv[2] = (__bf16)o.z; hv[3] = (__bf16)o.w;
    *(bf16x4*)&ph[(size_t)t * D + p] = hv;
    if (pl) {
      bf16x4 lv;
      lv[0] = (__bf16)(o.x - (float)hv[0]); lv[1] = (__bf16)(o.y - (float)hv[1]);
      lv[2] = (__bf16)(o.z - (float)hv[2]); lv[3] = (__bf16)(o.w - (float)hv[3]);
      *(bf16x4*)&pl[(size_t)t * D + p] = lv;
    }
  }
}

// ---------------- weight transpose+convert: f32 [K][N] -> bf16 [Npad][K] (swizzled) ----------------
template <bool SPLIT>
__global__ __launch_bounds__(256) void k_transW(const float* __restrict__ W, int K, int N,
                                                __bf16* __restrict__ Th, __bf16* __restrict__ Tl) {
  __shared__ float T[64][65];
  const int n0 = blockIdx.x * 64, k0 = blockIdx.y * 64, tid = threadIdx.x;
#pragma unroll
  for (int i = 0; i < 16; i++) {
    int idx = tid + i * 256;
    int k = idx >> 6, n = idx & 63;
    float v = 0.f;
    if (n0 + n < N) v = W[(size_t)(k0 + k) * N + n0 + n];
    T[k][n] = v;
  }
  __syncthreads();
#pragma unroll
  for (int i = 0; i < 4; i++) {
    int idx = tid + i * 256;
    int n = idx >> 4, p4 = (idx & 15) * 4;
    int nn = n0 + n;
    int P = (nn >> 1) & 3;
    bf16x4 hv, lv;
#pragma unroll
    for (int e = 0; e < 4; e++) {
      int p = p4 + e;
      int kk = (p & ~31) | ((((p >> 3) & 3) ^ P) << 3) | (p & 7);
      float v = T[kk][n];
      __bf16 h = (__bf16)v;
      hv[e] = h;
      if constexpr (SPLIT) lv[e] = (__bf16)(v - (float)h);
    }
    *(bf16x4*)&Th[(size_t)nn * K + k0 + p4] = hv;
    if constexpr (SPLIT) *(bf16x4*)&Tl[(size_t)nn * K + k0 + p4] = lv;
  }
}

// ---------------- m97-style bf16 MFMA GEMM: A[M][K], B^T[Npad][K] planes, 128x128 tile, BK=32 ----------------
template <bool SPLIT>
__global__ __launch_bounds__(256) void k_gemm2(const __bf16* __restrict__ Ah,
                                               const __bf16* __restrict__ Al,
                                               const __bf16* __restrict__ Bh,
                                               const __bf16* __restrict__ Bl,
                                               float* __restrict__ C,
                                               int M, int N, int K, int ks, int nst) {
  __shared__ __bf16 lds[(SPLIT ? 4 : 2) * 4096];
  __bf16* const AsH = lds;
  __bf16* const BsH = lds + (SPLIT ? 2 : 1) * 4096;
  __bf16* const AsL = SPLIT ? (lds + 4096) : nullptr;
  __bf16* const BsL = SPLIT ? (lds + 3 * 4096) : nullptr;

  const int tid = threadIdx.x;
  const int bn = blockIdx.x, bm = blockIdx.y, z = blockIdx.z;
  const int m0 = bm * 128, n0 = bn * 128;
  const int s0 = (int)(((long long)z * nst) / ks);
  const int s1 = (int)(((long long)(z + 1) * nst) / ks);
  float* __restrict__ Cp = C + (size_t)z * M * N;

  const int lane = tid & 63, wid = tid >> 6;
  const int wr = wid >> 1, wc = wid & 1;
  const int l16 = lane & 15, kl = lane >> 4;

  // staging: thread -> (row = tid>>2 [+64], chunk = (tid&3)*8 elements), linear LDS dest
  const int srow = tid >> 2;
  const int schunk = (tid & 3) * 8;
  const size_t aB0 = (size_t)(m0 + srow) * K + schunk;
  const size_t aB1 = aB0 + (size_t)64 * K;
  const size_t bB0 = (size_t)(n0 + srow) * K + schunk;
  const size_t bB1 = bB0 + (size_t)64 * K;
  __bf16* const lA0 = AsH + tid * 8;
  __bf16* const lA1 = AsH + (tid + 256) * 8;
  __bf16* const lB0 = BsH + tid * 8;
  __bf16* const lB1 = BsH + (tid + 256) * 8;

  int aoff[4], boff[4];
#pragma unroll
  for (int mi = 0; mi < 4; mi++) {
    int r = wr * 64 + mi * 16 + l16;
    aoff[mi] = r * 64 + ((kl ^ ((r >> 1) & 3)) << 4);
  }
#pragma unroll
  for (int ni = 0; ni < 4; ni++) {
    int r = wc * 64 + ni * 16 + l16;
    boff[ni] = r * 64 + ((kl ^ ((r >> 1) & 3)) << 4);
  }

  f32x4 acc[4][4];
#pragma unroll
  for (int mi = 0; mi < 4; mi++)
#pragma unroll
    for (int ni = 0; ni < 4; ni++) acc[mi][ni] = f32x4{0.f, 0.f, 0.f, 0.f};

  for (int s = s0; s < s1; ++s) {
    const int k0 = s << 5;
    __syncthreads();
    gl16(Ah + aB0 + k0, lA0);
    gl16(Ah + aB1 + k0, lA1);
    gl16(Bh + bB0 + k0, lB0);
    gl16(Bh + bB1 + k0, lB1);
    if constexpr (SPLIT) {
      gl16(Al + aB0 + k0, AsL + tid * 8);
      gl16(Al + aB1 + k0, AsL + (tid + 256) * 8);
      gl16(Bl + bB0 + k0, BsL + tid * 8);
      gl16(Bl + bB1 + k0, BsL + (tid + 256) * 8);
    }
    __syncthreads();
    bf16x8 ah[4], bh[4];
#pragma unroll
    for (int mi = 0; mi < 4; mi++) ah[mi] = *(const bf16x8*)((const char*)AsH + aoff[mi]);
#pragma unroll
    for (int ni = 0; ni < 4; ni++) bh[ni] = *(const bf16x8*)((const char*)BsH + boff[ni]);
#pragma unroll
    for (int mi = 0; mi < 4; mi++)
#pragma unroll
      for (int ni = 0; ni < 4; ni++)
        acc[mi][ni] = __builtin_amdgcn_mfma_f32_16x16x32_bf16(ah[mi], bh[ni], acc[mi][ni], 0, 0, 0);
    if constexpr (SPLIT) {
      bf16x8 al[4], bl[4];
#pragma unroll
      for (int mi = 0; mi < 4; mi++) al[mi] = *(const bf16x8*)((const char*)AsL + aoff[mi]);
#pragma unroll
      for (int ni = 0; ni < 4; ni++) bl[ni] = *(const bf16x8*)((const char*)BsL + boff[ni]);
#pragma unroll
      for (int mi = 0; mi < 4; mi++)
#pragma unroll
        for (int ni = 0; ni < 4; ni++) {
          acc[mi][ni] = __builtin_amdgcn_mfma_f32_16x16x32_bf16(ah[mi], bl[ni], acc[mi][ni], 0, 0, 0);
          acc[mi][ni] = __builtin_amdgcn_mfma_f32_16x16x32_bf16(al[mi], bh[ni], acc[mi][ni], 0, 0, 0);
        }
    }
  }
#pragma unroll
  for (int mi = 0; mi < 4; mi++)
#pragma unroll
    for (int ni = 0; ni < 4; ni++)
#pragma unroll
      for (int r = 0; r < 4; r++) {
        int row = m0 + wr * 64 + mi * 16 + kl * 4 + r;
        int col = n0 + wc * 64 + ni * 16 + l16;
        if (col < N) Cp[(size_t)row * N + col] = acc[mi][ni][r];
      }
}

// ---------------- partial reduce (+ optional residual) ----------------
template <bool RES>
__global__ void k_reduce(const float* __restrict__ Pp, int np, int n4,
                         const float* __restrict__ res, float* __restrict__ out) {
  int i = blockIdx.x * 256 + threadIdx.x;
  int stride = gridDim.x * 256;
  for (; i < n4; i += stride) {
    float4 a = ((const float4*)Pp)[i];
    for (int z = 1; z < np; z++) {
      float4 b = ((const float4*)Pp)[(size_t)z * n4 + i];
      a.x += b.x; a.y += b.y; a.z += b.z; a.w += b.w;
    }
    if constexpr (RES) {
      float4 r0 = ((const float4*)res)[i];
      a.x += r0.x; a.y += r0.y; a.z += r0.z; a.w += r0.w;
    }
    ((float4*)out)[i] = a;
  }
}

// ---------------- expert GEMM (f32 reg-staged, unchanged from validated r2) ----------------
// MODE 2: A rows gathered via perm (gate/up)   MODE 3: A rows = slots (down)
template <int MODE>
__global__ __launch_bounds__(256) void k_gemmE(const float* __restrict__ A,
                                               const float* __restrict__ Bg,
                                               float* __restrict__ C,
                                               const int* __restrict__ perm,
                                               const int* __restrict__ expOff,
                                               const int* __restrict__ expCnt,
                                               int N, int K, long long strideB) {
  __shared__ __bf16 Als[128][40];
  __shared__ __bf16 Bls[4][1088];
  int tid = threadIdx.x;
  int bm = blockIdx.y, bn = blockIdx.x;
  int e = blockIdx.z;
  int cnt = expCnt[e];
  int base = expOff[e];
  if (bm * 128 >= cnt) return;
  const float* Bp = Bg + (long long)e * strideB;
  int rowBase = bm * 128, colBase = bn * 128;
  int lane = tid & 63, wid = tid >> 6;
  int wr = wid >> 1, wc = wid & 1;
  int kl = lane >> 4, l16 = lane & 15;

  int arow[4]; bool avalid[4];
#pragma unroll
  for (int i = 0; i < 4; i++) {
    int id = tid + 256 * i;
    int rl = rowBase + (id >> 3);
    avalid[i] = rl < cnt;
    if constexpr (MODE == 2) arow[i] = avalid[i] ? perm[base + rl] : 0;
    else arow[i] = base + (avalid[i] ? rl : 0);
  }

  f32x4 acc[4][4];
#pragma unroll
  for (int mi = 0; mi < 4; mi++)
#pragma unroll
    for (int ni = 0; ni < 4; ni++) acc[mi][ni] = f32x4{0.f, 0.f, 0.f, 0.f};

  for (int k0 = 0; k0 < K; k0 += 32) {
    __syncthreads();
#pragma unroll
    for (int i = 0; i < 4; i++) {
      int id = tid + 256 * i;
      int r = id >> 3, k4 = (id & 7) * 4;
      float4 v = float4{0.f, 0.f, 0.f, 0.f};
      if (avalid[i]) v = *(const float4*)&A[(size_t)arow[i] * K + k0 + k4];
      bf16x4 pk; pk[0] = (__bf16)v.x; pk[1] = (__bf16)v.y; pk[2] = (__bf16)v.z; pk[3] = (__bf16)v.w;
      *(bf16x4*)&Als[r][k4] = pk;
    }
#pragma unroll
    for (int i = 0; i < 4; i++) {
      int id = tid + 256 * i;
      int col = id & 127, kq = id >> 7;
      int gc = colBase + col;
      int k = k0 + kq * 4;
      float v0 = 0, v1 = 0, v2 = 0, v3 = 0;
      if (gc < N) {
        v0 = Bp[(size_t)(k + 0) * N + gc];
        v1 = Bp[(size_t)(k + 1) * N + gc];
        v2 = Bp[(size_t)(k + 2) * N + gc];
        v3 = Bp[(size_t)(k + 3) * N + gc];
      }
      bf16x4 pk; pk[0] = (__bf16)v0; pk[1] = (__bf16)v1; pk[2] = (__bf16)v2; pk[3] = (__bf16)v3;
      *(bf16x4*)&Bls[kq >> 1][col * 8 + (kq & 1) * 4] = pk;
    }
    __syncthreads();
    bf16x8 af[4], bfr[4];
#pragma unroll
    for (int mi = 0; mi < 4; mi++)
      af[mi] = *(const bf16x8*)&Als[wr * 64 + mi * 16 + l16][kl * 8];
#pragma unroll
    for (int ni = 0; ni < 4; ni++)
      bfr[ni] = *(const bf16x8*)&Bls[kl][(wc * 64 + ni * 16 + l16) * 8];
#pragma unroll
    for (int mi = 0; mi < 4; mi++)
#pragma unroll
      for (int ni = 0; ni < 4; ni++)
        acc[mi][ni] = __builtin_amdgcn_mfma_f32_16x16x32_bf16(af[mi], bfr[ni], acc[mi][ni], 0, 0, 0);
  }
#pragma unroll
  for (int mi = 0; mi < 4; mi++)
#pragma unroll
    for (int ni = 0; ni < 4; ni++)
#pragma unroll
      for (int r = 0; r < 4; r++) {
        int rl = rowBase + wr * 64 + mi * 16 + kl * 4 + r;
        int col = colBase + wc * 64 + ni * 16 + l16;
        if (rl < cnt && col < N) C[(size_t)(base + rl) * N + col] = acc[mi][ni][r];
      }
}

// ---------------- dt softplus ----------------
__global__ void k_dt(const float* __restrict__ zx, const float* __restrict__ dt_bias,
                     const float* __restrict__ A_log, float* __restrict__ dtp,
                     float* __restrict__ dtA) {
  int t = blockIdx.x, h = threadIdx.x;
  if (h < HEADS) {
    float v = zx[(size_t)t * D_INPROJ + 10496 + h] + dt_bias[h];
    float sp = fmaxf(v, 0.f) + log1pf(expf(-fabsf(v)));
    dtp[t * HEADS + h] = sp;
    dtA[t * HEADS + h] = sp * (-expf(A_log[h]));
  }
}

// ---------------- causal depthwise conv + SiLU ----------------
__global__ void k_conv(const float* __restrict__ zx, const float* __restrict__ cw,
                       const float* __restrict__ cb, float* __restrict__ xBC) {
  int cidx = blockIdx.x * 256 + threadIdx.x;
  int t = blockIdx.y;
  if (cidx < CONV_DIM) {
    float acc = cb[cidx];
#pragma unroll
    for (int j = 0; j < 4; j++) {
      int tt = t - 3 + j;
      if (tt >= 0) acc += zx[(size_t)tt * D_INPROJ + D_INNER + cidx] * cw[cidx * 4 + j];
    }
    xBC[(size_t)t * CONV_DIM + cidx] = siluf(acc);
  }
}

// ---------------- scan: intra-chunk ----------------
__global__ __launch_bounds__(256) void k_scan_intra(
    const float* __restrict__ xBC, const float* __restrict__ dtp,
    const float* __restrict__ dtA, float* __restrict__ y, float* __restrict__ S,
    float* __restrict__ cumA, float* __restrict__ Atot) {
  __shared__ float Bs[64][132];
  __shared__ float Cs[64][132];
  __shared__ float Xs[64][68];
  __shared__ float Gs[64][65];
  __shared__ float da_s[64], a_s[64], dt_sh[64], w_sh[64];
  int c = blockIdx.x, h = blockIdx.y, tid = threadIdx.x;
  int t0 = c * QCHUNK;
#pragma unroll
  for (int i = 0; i < 8; i++) {
    int id = tid + 256 * i;
    int r = id >> 5, c4 = (id & 31) * 4;
    *(float4*)&Bs[r][c4] = *(const float4*)&xBC[(size_t)(t0 + r) * CONV_DIM + D_INNER + c4];
    *(float4*)&Cs[r][c4] = *(const float4*)&xBC[(size_t)(t0 + r) * CONV_DIM + D_INNER + N_STATE + c4];
  }
#pragma unroll
  for (int i = 0; i < 4; i++) {
    int id = tid + 256 * i;
    int r = id >> 4, p4 = (id & 15) * 4;
    *(float4*)&Xs[r][p4] = *(const float4*)&xBC[(size_t)(t0 + r) * CONV_DIM + h * P_HEAD + p4];
  }
  if (tid < 64) {
    da_s[tid] = dtA[(size_t)(t0 + tid) * HEADS + h];
    dt_sh[tid] = dtp[(size_t)(t0 + tid) * HEADS + h];
  }
  __syncthreads();
  if (tid < 64) {
    float a = 0.f;
    for (int i = 0; i <= tid; i++) a += da_s[i];
    a_s[tid] = a;
    cumA[((size_t)c * HEADS + h) * 64 + tid] = a;
  }
  __syncthreads();
  if (tid < 64) {
    w_sh[tid] = __expf(a_s[63] - a_s[tid]) * dt_sh[tid];
    if (tid == 0) Atot[c * HEADS + h] = a_s[63];
  }
  __syncthreads();
  {
    int tq = tid >> 4, sq = tid & 15;
    float gacc[4][4];
#pragma unroll
    for (int j = 0; j < 4; j++)
#pragma unroll
      for (int jj = 0; jj < 4; jj++) gacc[j][jj] = 0.f;
    for (int n4 = 0; n4 < 128; n4 += 4) {
      float4 cv[4], bv[4];
#pragma unroll
      for (int j = 0; j < 4; j++) cv[j] = *(const float4*)&Cs[tq * 4 + j][n4];
#pragma unroll
      for (int j = 0; j < 4; j++) bv[j] = *(const float4*)&Bs[sq * 4 + j][n4];
#pragma unroll
      for (int j = 0; j < 4; j++)
#pragma unroll
        for (int jj = 0; jj < 4; jj++)
          gacc[j][jj] += cv[j].x * bv[jj].x + cv[j].y * bv[jj].y + cv[j].z * bv[jj].z + cv[j].w * bv[jj].w;
    }
#pragma unroll
    for (int j = 0; j < 4; j++)
#pragma unroll
      for (int jj = 0; jj < 4; jj++) {
        int t = tq * 4 + j, s = sq * 4 + jj;
        float arg = fminf(a_s[t] - a_s[s], 0.f);
        Gs[t][s] = (s <= t) ? gacc[j][jj] * __expf(arg) * dt_sh[s] : 0.f;
      }
  }
  __syncthreads();
  {
    int tq = tid >> 4, pq = tid & 15;
    float4 acc[4];
#pragma unroll
    for (int j = 0; j < 4; j++) acc[j] = float4{0.f, 0.f, 0.f, 0.f};
    for (int s = 0; s < 64; s++) {
      float4 xv = *(const float4*)&Xs[s][pq * 4];
#pragma unroll
      for (int j = 0; j < 4; j++) {
        float g = Gs[tq * 4 + j][s];
        acc[j].x += g * xv.x; acc[j].y += g * xv.y; acc[j].z += g * xv.z; acc[j].w += g * xv.w;
      }
    }
#pragma unroll
    for (int j = 0; j < 4; j++) {
      int t = tq * 4 + j;
      *(float4*)&y[(size_t)(t0 + t) * D_INNER + h * P_HEAD + pq * 4] = acc[j];
    }
  }
  {
    int p2 = tid >> 5, n4 = (tid & 31) * 4;
    float4 acc[8];
#pragma unroll
    for (int j = 0; j < 8; j++) acc[j] = float4{0.f, 0.f, 0.f, 0.f};
    for (int s = 0; s < 64; s++) {
      float4 bv = *(const float4*)&Bs[s][n4];
#pragma unroll
      for (int j = 0; j < 8; j++) {
        float xw = Xs[s][p2 * 8 + j] * w_sh[s];
        acc[j].x += xw * bv.x; acc[j].y += xw * bv.y; acc[j].z += xw * bv.z; acc[j].w += xw * bv.w;
      }
    }
    size_t bb = ((size_t)(c * HEADS + h) * 64) * 128;
#pragma unroll
    for (int j = 0; j < 8; j++)
      *(float4*)&S[bb + (size_t)(p2 * 8 + j) * 128 + n4] = acc[j];
  }
}

// ---------------- scan: inter-chunk state recurrence ----------------
__global__ void k_scan_state(float* __restrict__ S, const float* __restrict__ Atot) {
  int gid = blockIdx.x * 256 + threadIdx.x;
  int h = gid >> 13;
  int rem = gid & 8191;
  float run = 0.f;
#pragma unroll
  for (int c = 0; c < NCHUNK; c++) {
    size_t idx = ((size_t)(c * HEADS + h) << 13) + rem;
    float s = S[idx];
    S[idx] = run;
    run = run * __expf(Atot[c * HEADS + h]) + s;
  }
}

// ---------------- scan: inter-chunk contribution + D*x ----------------
__global__ __launch_bounds__(256) void k_scan_inter(
    const float* __restrict__ xBC, const float* __restrict__ Hin,
    const float* __restrict__ cumA, const float* __restrict__ Dv,
    float* __restrict__ y) {
  __shared__ float Hs[64][132];
  __shared__ float Cs[64][132];
  __shared__ float a_l[64];
  int c = blockIdx.x, h = blockIdx.y, tid = threadIdx.x;
  int t0 = c * QCHUNK;
#pragma unroll
  for (int i = 0; i < 8; i++) {
    int id = tid + 256 * i;
    int r = id >> 5, n4 = (id & 31) * 4;
    *(float4*)&Hs[r][n4] = *(const float4*)&Hin[(((size_t)(c * HEADS + h) * 64 + r) << 7) + n4];
    *(float4*)&Cs[r][n4] = *(const float4*)&xBC[(size_t)(t0 + r) * CONV_DIM + D_INNER + N_STATE + n4];
  }
  if (tid < 64) a_l[tid] = cumA[((size_t)c * HEADS + h) * 64 + tid];
  __syncthreads();
  float Dh = Dv[h];
  int tq = tid >> 4, pq = tid & 15;
  float4 acc[4];
#pragma unroll
  for (int j = 0; j < 4; j++) acc[j] = float4{0.f, 0.f, 0.f, 0.f};
  for (int n4 = 0; n4 < 128; n4 += 4) {
    float4 hv[4], cv[4];
#pragma unroll
    for (int jj = 0; jj < 4; jj++) hv[jj] = *(const float4*)&Hs[pq * 4 + jj][n4];
#pragma unroll
    for (int j = 0; j < 4; j++) cv[j] = *(const float4*)&Cs[tq * 4 + j][n4];
#pragma unroll
    for (int j = 0; j < 4; j++) {
      acc[j].x += cv[j].x * hv[0].x + cv[j].y * hv[0].y + cv[j].z * hv[0].z + cv[j].w * hv[0].w;
      acc[j].y += cv[j].x * hv[1].x + cv[j].y * hv[1].y + cv[j].z * hv[1].z + cv[j].w * hv[1].w;
      acc[j].z += cv[j].x * hv[2].x + cv[j].y * hv[2].y + cv[j].z * hv[2].z + cv[j].w * hv[2].w;
      acc[j].w += cv[j].x * hv[3].x + cv[j].y * hv[3].y + cv[j].z * hv[3].z + cv[j].w * hv[3].w;
    }
  }
#pragma unroll
  for (int j = 0; j < 4; j++) {
    int t = tq * 4 + j;
    float e = __expf(a_l[t]);
    float4 xv = *(const float4*)&xBC[(size_t)(t0 + t) * CONV_DIM + h * P_HEAD + pq * 4];
    size_t yoff = (size_t)(t0 + t) * D_INNER + h * P_HEAD + pq * 4;
    float4 yv = *(float4*)&y[yoff];
    yv.x += e * acc[j].x + Dh * xv.x;
    yv.y += e * acc[j].y + Dh * xv.y;
    yv.z += e * acc[j].z + Dh * xv.z;
    yv.w += e * acc[j].w + Dh * xv.w;
    *(float4*)&y[yoff] = yv;
  }
}

// ---------------- gated RMSNorm -> swizzled bf16 planes ----------------
__global__ __launch_bounds__(256) void k_gatednorm_p(const float* __restrict__ y,
                                                     const float* __restrict__ zx,
                                                     const float* __restrict__ w,
                                                     __bf16* __restrict__ ph,
                                                     __bf16* __restrict__ pl) {
  __shared__ float vbuf[D_INNER];
  __shared__ float red[4];
  int t = blockIdx.x, tid = threadIdx.x;
  float ss = 0.f;
  for (int i = tid; i < D_INNER / 4; i += 256) {
    float4 yv = *(const float4*)&y[(size_t)t * D_INNER + i * 4];
    float4 zv = *(const float4*)&zx[(size_t)t * D_INPROJ + i * 4];
    float4 v;
    v.x = yv.x * siluf(zv.x); v.y = yv.y * siluf(zv.y);
    v.z = yv.z * siluf(zv.z); v.w = yv.w * siluf(zv.w);
    *(float4*)&vbuf[i * 4] = v;
    ss += v.x * v.x + v.y * v.y + v.z * v.z + v.w * v.w;
  }
  float tot = block_sum256(ss, red);
  float r = rsqrtf(tot / (float)D_INNER + 1e-6f);
  int P = (t >> 1) & 3;
  for (int i = tid; i < D_INNER / 4; i += 256) {
    float4 v = *(const float4*)&vbuf[i * 4];
    float4 wv = *(const float4*)&w[i * 4];
    float4 o;
    o.x = wv.x * v.x * r; o.y = wv.y * v.y * r; o.z = wv.z * v.z * r; o.w = wv.w * v.w * r;
    int p = swz_p(i * 4, P);
    bf16x4 hv;
    hv[0] = (__bf16)o.x; hv[1] = (__bf16)o.y; hv[2] = (__bf16)o.z; hv[3] = (__bf16)o.w;
    *(bf16x4*)&ph[(size_t)t * D_INNER + p] = hv;
    bf16x4 lv;
    lv[0] = (__bf16)(o.x - (float)hv[0]); lv[1] = (__bf16)(o.y - (float)hv[1]);
    lv[2] = (__bf16)(o.z - (float)hv[2]); lv[3] = (__bf16)(o.w - (float)hv[3]);
    *(bf16x4*)&pl[(size_t)t * D_INNER + p] = lv;
  }
}

// ---------------- router ----------------
__global__ void k_zero(int* counts, int* cursor) {
  int i = threadIdx.x;
  if (i < NEXP) { counts[i] = 0; cursor[i] = 0; }
}

__global__ __launch_bounds__(256) void k_router(const float* __restrict__ xm,
                                                const float* __restrict__ Wr,
                                                int* __restrict__ top_i,
                                                float* __restrict__ top_v,
                                                int* __restrict__ counts) {
  __shared__ float part[16][17];
  __shared__ float lg[16];
  int t = blockIdx.x, tid = threadIdx.x;
  int e = tid & 15, seg = tid >> 4;
  const float* xr = xm + (size_t)t * D_MODEL;
  float s = 0.f;
  for (int i = 0; i < 160; i++) {
    int k = seg * 160 + i;
    s += xr[k] * Wr[(size_t)k * NEXP + e];
  }
  part[seg][e] = s;
  __syncthreads();
  if (tid < 16) {
    float l = 0.f;
    for (int g = 0; g < 16; g++) l += part[g][tid];
    lg[tid] = l;
  }
  __syncthreads();
  if (tid == 0) {
    float mx = lg[0];
    for (int i = 1; i < 16; i++) mx = fmaxf(mx, lg[i]);
    float pe[16];
    for (int i = 0; i < 16; i++) pe[i] = expf(lg[i] - mx);
    int i0 = 0; float v0 = pe[0];
    for (int i = 1; i < 16; i++) if (pe[i] > v0) { v0 = pe[i]; i0 = i; }
    int i1 = -1; float v1 = -1.f;
    for (int i = 0; i < 16; i++) if (i != i0 && pe[i] > v1) { v1 = pe[i]; i1 = i; }
    float inv = 1.f / (v0 + v1);
    top_i[t * 2] = i0; top_i[t * 2 + 1] = i1;
    top_v[t * 2] = v0 * inv; top_v[t * 2 + 1] = v1 * inv;
    atomicAdd(&counts[i0], 1);
    atomicAdd(&counts[i1], 1);
  }
}

__global__ void k_offsets(const int* counts, int* offs, int* cursor) {
  if (threadIdx.x == 0) {
    int s = 0;
    for (int e = 0; e < NEXP; e++) { offs[e] = s; cursor[e] = s; s += counts[e]; }
  }
}

__global__ void k_scatter(const int* __restrict__ top_i, const float* __restrict__ top_v,
                          int* __restrict__ cursor, int* __restrict__ perm,
                          int* __restrict__ slotOf, float* __restrict__ slotw) {
  int t = blockIdx.x * 256 + threadIdx.x;
  if (t < SEQ) {
    for (int k = 0; k < 2; k++) {
      int e = top_i[t * 2 + k];
      int pos = atomicAdd(&cursor[e], 1);
      perm[pos] = t;
      slotOf[t * 2 + k] = pos;
      slotw[pos] = top_v[t * 2 + k];
    }
  }
}

// ---------------- silu-mul: routed (f32, per-row scale) ----------------
__global__ void k_silumul(float* __restrict__ g, const float* __restrict__ u,
                          const float* __restrict__ slotw, int cols) {
  int r = blockIdx.x, tid = threadIdx.x;
  float w = slotw ? slotw[r] : 1.f;
  for (int i = tid; i < cols / 4; i += 256) {
    float4 gv = *(const float4*)&g[(size_t)r * cols + i * 4];
    float4 uv = *(const float4*)&u[(size_t)r * cols + i * 4];
    gv.x = siluf(gv.x) * uv.x * w;
    gv.y = siluf(gv.y) * uv.y * w;
    gv.z = siluf(gv.z) * uv.z * w;
    gv.w = siluf(gv.w) * uv.w * w;
    *(float4*)&g[(size_t)r * cols + i * 4] = gv;
  }
}

// ---------------- silu-mul: shared -> swizzled bf16 plane ----------------
__global__ void k_silumul_sh(const float* __restrict__ g, const float* __restrict__ u,
                             __bf16* __restrict__ outp) {
  int m = blockIdx.x, tid = threadIdx.x;
  int P = (m >> 1) & 3;
  for (int i = tid; i < MS_INTER / 4; i += 256) {
    float4 gv = *(const float4*)&g[(size_t)m * MS_INTER + i * 4];
    float4 uv = *(const float4*)&u[(size_t)m * MS_INTER + i * 4];
    float4 o;
    o.x = siluf(gv.x) * uv.x; o.y = siluf(gv.y) * uv.y;
    o.z = siluf(gv.z) * uv.z; o.w = siluf(gv.w) * uv.w;
    int p = swz_p(i * 4, P);
    bf16x4 hv;
    hv[0] = (__bf16)o.x; hv[1] = (__bf16)o.y; hv[2] = (__bf16)o.z; hv[3] = (__bf16)o.w;
    *(bf16x4*)&outp[(size_t)m * MS_INTER + p] = hv;
  }
}

// ---------------- final combine ----------------
__global__ void k_final(const float* __restrict__ hidden, const float* __restrict__ sh,
                        const float* __restrict__ ds, const int* __restrict__ slotOf,
                        float* __restrict__ out) {
  int t = blockIdx.y;
  int d4 = (blockIdx.x * 256 + threadIdx.x) * 4;
  if (d4 < D_MODEL) {
    int s0 = slotOf[t * 2], s1 = slotOf[t * 2 + 1];
    float4 a = *(const float4*)&hidden[(size_t)t * D_MODEL + d4];
    float4 b = *(const float4*)&sh[(size_t)t * D_MODEL + d4];
    float4 c0 = *(const float4*)&ds[(size_t)s0 * D_MODEL + d4];
    float4 c1 = *(const float4*)&ds[(size_t)s1 * D_MODEL + d4];
    float4 o;
    o.x = a.x + b.x + c0.x + c1.x;
    o.y = a.y + b.y + c0.y + c1.y;
    o.z = a.z + b.z + c0.z + c1.z;
    o.w = a.w + b.w + c0.w + c1.w;
    *(float4*)&out[(size_t)t * D_MODEL + d4] = o;
  }
}

// ---------------- launch ----------------
extern "C" void kernel_launch(void* const* d_in, const int* in_sizes, int n_in,
                              void* d_out, int out_size, void* d_ws, size_t ws_size,
                              hipStream_t stream) {
  const float* hs = (const float*)d_in[0];
  const float* w_in = (const float*)d_in[1];
  const float* conv_w = (const float*)d_in[2];
  const float* conv_b = (const float*)d_in[3];
  const float* dt_bias = (const float*)d_in[4];
  const float* A_log = (const float*)d_in[5];
  const float* Dv = (const float*)d_in[6];
  const float* mnw = (const float*)d_in[7];
  const float* w_out = (const float*)d_in[8];
  const float* ln1 = (const float*)d_in[9];
  const float* ln2 = (const float*)d_in[10];
  const float* router_w = (const float*)d_in[11];
  const float* we_gate = (const float*)d_in[12];
  const float* we_up = (const float*)d_in[13];
  const float* we_down = (const float*)d_in[14];
  const float* ws_gate = (const float*)d_in[15];
  const float* ws_up = (const float*)d_in[16];
  const float* ws_down = (const float*)d_in[17];

  char* base = (char*)d_ws;
  size_t off = 0;
  auto A = [&](size_t bytes) -> void* {
    void* p = base + off;
    off += (bytes + 255) & ~(size_t)255;
    return p;
  };
  float* zx = (float*)A((size_t)SEQ * D_INPROJ * 4);
  float* xbc = (float*)A((size_t)SEQ * CONV_DIM * 4);
  float* xmf = (float*)A((size_t)SEQ * D_MODEL * 4);
  float* dtp = (float*)A((size_t)SEQ * HEADS * 4);
  float* dtA = (float*)A((size_t)SEQ * HEADS * 4);
  float* yf = (float*)A((size_t)SEQ * D_INNER * 4);
  float* cumA = (float*)A((size_t)NCHUNK * HEADS * 64 * 4);
  float* Atot = (float*)A((size_t)NCHUNK * HEADS * 4);
  float* Sbuf = (float*)A((size_t)NCHUNK * HEADS * 64 * 128 * 4);
  float* hidden = (float*)A((size_t)SEQ * D_MODEL * 4);
  float* shout = (float*)A((size_t)SEQ * D_MODEL * 4);
  float* top_v = (float*)A(8192);
  float* slotw = (float*)A(8192);
  int* top_i = (int*)A(8192);
  int* counts = (int*)A(64);
  int* offs = (int*)A(64);
  int* cursor = (int*)A(64);
  int* perm = (int*)A(8192);
  int* slotOf = (int*)A(8192);
  __bf16* xp_h = (__bf16*)A((size_t)SEQ * D_MODEL * 2);
  __bf16* xp_l = (__bf16*)A((size_t)SEQ * D_MODEL * 2);
  __bf16* ybp_h = (__bf16*)A((size_t)SEQ * D_INNER * 2);
  __bf16* ybp_l = (__bf16*)A((size_t)SEQ * D_INNER * 2);
  __bf16* gbuf_bh = (__bf16*)A((size_t)SEQ * MS_INTER * 2);
  float* partials = (float*)A((size_t)4 * SEQ * D_MODEL * 4);
  char* wtbuf = (char*)A((size_t)108789760);
  // aliases inside wtbuf (phase-sequential)
  __bf16* winT_h = (__bf16*)wtbuf;                       // [10624][2560]
  __bf16* winT_l = (__bf16*)(wtbuf + 54394880);
  __bf16* woutT_h = (__bf16*)wtbuf;                      // [2560][5120]
  __bf16* woutT_l = (__bf16*)(wtbuf + 26214400);
  __bf16* gateT = (__bf16*)wtbuf;                        // [1792][2560]
  __bf16* upT = (__bf16*)(wtbuf + 9175040);              // [1792][2560]
  __bf16* downT = (__bf16*)(wtbuf + 18350080);           // [2560][1728]
  float* gbufF = (float*)(wtbuf + 27197440);             // [1024][1728] / [2048][864]
  float* ubufF = (float*)(wtbuf + 34275328);
  float* dslots = (float*)(wtbuf + 41353216);            // [2048][2560]

  // ---- Mamba sub-block ----
  k_rmsnorm_p<<<SEQ, 256, 0, stream>>>(hs, ln1, nullptr, xp_h, xp_l, D_MODEL);
  k_transW<true><<<dim3(166, 40), 256, 0, stream>>>(w_in, D_MODEL, D_INPROJ, winT_h, winT_l);
  k_gemm2<true><<<dim3(83, 8, 1), 256, 0, stream>>>(xp_h, xp_l, winT_h, winT_l, zx,
                                                    SEQ, D_INPROJ, D_MODEL, 1, 80);
  k_dt<<<SEQ, 128, 0, stream>>>(zx, dt_bias, A_log, dtp, dtA);
  k_conv<<<dim3(21, SEQ), 256, 0, stream>>>(zx, conv_w, conv_b, xbc);
  k_scan_intra<<<dim3(NCHUNK, HEADS), 256, 0, stream>>>(xbc, dtp, dtA, yf, Sbuf, cumA, Atot);
  k_scan_state<<<2560, 256, 0, stream>>>(Sbuf, Atot);
  k_scan_inter<<<dim3(NCHUNK, HEADS), 256, 0, stream>>>(xbc, Sbuf, cumA, Dv, yf);
  k_gatednorm_p<<<SEQ, 256, 0, stream>>>(yf, zx, mnw, ybp_h, ybp_l);
  k_transW<true><<<dim3(40, 80), 256, 0, stream>>>(w_out, D_INNER, D_MODEL, woutT_h, woutT_l);
  k_gemm2<true><<<dim3(20, 8, 4), 256, 0, stream>>>(ybp_h, ybp_l, woutT_h, woutT_l, partials,
                                                    SEQ, D_MODEL, D_INNER, 4, 160);
  k_reduce<true><<<2048, 256, 0, stream>>>(partials, 4, SEQ * D_MODEL / 4, hs, hidden);

  // ---- MoE sub-block ----
  k_rmsnorm_p<<<SEQ, 256, 0, stream>>>(hidden, ln2, xmf, xp_h, nullptr, D_MODEL);
  k_zero<<<1, 64, 0, stream>>>(counts, cursor);
  k_router<<<SEQ, 256, 0, stream>>>(xmf, router_w, top_i, top_v, counts);
  k_offsets<<<1, 32, 0, stream>>>(counts, offs, cursor);
  k_scatter<<<4, 256, 0, stream>>>(top_i, top_v, cursor, perm, slotOf, slotw);

  // shared experts
  k_transW<false><<<dim3(28, 40), 256, 0, stream>>>(ws_gate, D_MODEL, MS_INTER, gateT, nullptr);
  k_gemm2<false><<<dim3(14, 8, 4), 256, 0, stream>>>(xp_h, nullptr, gateT, nullptr, partials,
                                                     SEQ, MS_INTER, D_MODEL, 4, 80);
  k_reduce<false><<<2048, 256, 0, stream>>>(partials, 4, SEQ * MS_INTER / 4, nullptr, gbufF);
  k_transW<false><<<dim3(28, 40), 256, 0, stream>>>(ws_up, D_MODEL, MS_INTER, upT, nullptr);
  k_gemm2<false><<<dim3(14, 8, 4), 256, 0, stream>>>(xp_h, nullptr, upT, nullptr, partials,
                                                     SEQ, MS_INTER, D_MODEL, 4, 80);
  k_reduce<false><<<2048, 256, 0, stream>>>(partials, 4, SEQ * MS_INTER / 4, nullptr, ubufF);
  k_silumul_sh<<<SEQ, 256, 0, stream>>>(gbufF, ubufF, gbuf_bh);
  k_transW<false><<<dim3(40, 27), 256, 0, stream>>>(ws_down, MS_INTER, D_MODEL, downT, nullptr);
  k_gemm2<false><<<dim3(20, 8, 4), 256, 0, stream>>>(gbuf_bh, nullptr, downT, nullptr, partials,
                                                     SEQ, D_MODEL, MS_INTER, 4, 54);
  k_reduce<false><<<2048, 256, 0, stream>>>(partials, 4, SEQ * D_MODEL / 4, nullptr, shout);

  // routed experts
  k_gemmE<2><<<dim3(7, 8, NEXP), 256, 0, stream>>>(xmf, we_gate, gbufF, perm, offs, counts,
                                                   M_INTER, D_MODEL, (long long)D_MODEL * M_INTER);
  k_gemmE<2><<<dim3(7, 8, NEXP), 256, 0, stream>>>(xmf, we_up, ubufF, perm, offs, counts,
                                                   M_INTER, D_MODEL, (long long)D_MODEL * M_INTER);
  k_silumul<<<2048, 256, 0, stream>>>(gbufF, ubufF, slotw, M_INTER);
  k_gemmE<3><<<dim3(20, 8, NEXP), 256, 0, stream>>>(gbufF, we_down, dslots, perm, offs, counts,
                                                    D_MODEL, M_INTER, (long long)M_INTER * D_MODEL);

  k_final<<<dim3(3, SEQ), 256, 0, stream>>>(hidden, shout, dslots, slotOf, (float*)d_out);
}

// Round 4
// 1016.199 us; speedup vs baseline: 2.6605x; 1.3622x over previous
//
#include <hip/hip_runtime.h>

// ---------------- types ----------------
typedef __attribute__((ext_vector_type(4))) float f32x4;
typedef __attribute__((ext_vector_type(8))) __bf16 bf16x8;
typedef __attribute__((ext_vector_type(4))) __bf16 bf16x4;

#define D_MODEL 2560
#define D_INNER 5120
#define N_STATE 128
#define HEADS 80
#define P_HEAD 64
#define CONV_DIM 5376
#define D_INPROJ 10576
#define SEQ 1024
#define NCHUNK 16
#define QCHUNK 64
#define NEXP 16
#define M_INTER 864
#define MS_INTER 1728
#define NSLOT 2048
#define NSLOTP 2176   // padded slot rows

__device__ __forceinline__ float siluf(float x) { return x / (1.f + __expf(-x)); }

// swizzled chunk position: within each 32-elem K-group, 16B chunk c stored at c ^ P
__device__ __forceinline__ int swz_p(int k4, int P) {
  return (k4 & ~31) | ((((k4 >> 3) & 3) ^ P) << 3) | (k4 & 7);
}

__device__ __forceinline__ void gl16(const __bf16* g, __bf16* l) {
  __builtin_amdgcn_global_load_lds((const __attribute__((address_space(1))) unsigned int*)g,
                                   (__attribute__((address_space(3))) unsigned int*)l, 16, 0, 0);
}

__device__ __forceinline__ float block_sum256(float v, float* red) {
#pragma unroll
  for (int m = 32; m > 0; m >>= 1) v += __shfl_xor(v, m, 64);
  int w = threadIdx.x >> 6;
  if ((threadIdx.x & 63) == 0) red[w] = v;
  __syncthreads();
  return red[0] + red[1] + red[2] + red[3];
}

// ---------------- RMSNorm -> f32 (optional) + swizzled bf16 planes ----------------
__global__ __launch_bounds__(256) void k_rmsnorm_p(const float* __restrict__ in,
                                                   const float* __restrict__ w,
                                                   float* __restrict__ f32out,
                                                   __bf16* __restrict__ ph,
                                                   __bf16* __restrict__ pl, int D) {
  __shared__ float red[4];
  int t = blockIdx.x, tid = threadIdx.x;
  const float* x = in + (size_t)t * D;
  int nd4 = D >> 2;
  float ss = 0.f;
  for (int i = tid; i < nd4; i += 256) {
    float4 v = ((const float4*)x)[i];
    ss += v.x * v.x + v.y * v.y + v.z * v.z + v.w * v.w;
  }
  float tot = block_sum256(ss, red);
  float r = rsqrtf(tot / (float)D + 1e-6f);
  int P = (t >> 1) & 3;
  for (int i = tid; i < nd4; i += 256) {
    float4 v = ((const float4*)x)[i];
    float4 wv = ((const float4*)w)[i];
    float4 o;
    o.x = wv.x * v.x * r; o.y = wv.y * v.y * r; o.z = wv.z * v.z * r; o.w = wv.w * v.w * r;
    if (f32out) ((float4*)(f32out + (size_t)t * D))[i] = o;
    int p = swz_p(i * 4, P);
    bf16x4 hv;
    hv[0] = (__bf16)o.x; hv[1] = (__bf16)o.y; hv[2] = (__bf16)o.z; hv[3] = (__bf16)o.w;
    *(bf16x4*)&ph[(size_t)t * D + p] = hv;
    if (pl) {
      bf16x4 lv;
      lv[0] = (__bf16)(o.x - (float)hv[0]); lv[1] = (__bf16)(o.y - (float)hv[1]);
      lv[2] = (__bf16)(o.z - (float)hv[2]); lv[3] = (__bf16)(o.w - (float)hv[3]);
      *(bf16x4*)&pl[(size_t)t * D + p] = lv;
    }
  }
}

// ---------------- weight transpose+convert: f32 [K][N] -> bf16 [Npad][K] (swizzled) ----------------
template <bool SPLIT>
__global__ __launch_bounds__(256) void k_transW(const float* __restrict__ W, int K, int N,
                                                __bf16* __restrict__ Th, __bf16* __restrict__ Tl) {
  __shared__ float T[64][65];
  const int n0 = blockIdx.x * 64, k0 = blockIdx.y * 64, tid = threadIdx.x;
#pragma unroll
  for (int i = 0; i < 16; i++) {
    int idx = tid + i * 256;
    int k = idx >> 6, n = idx & 63;
    float v = 0.f;
    if (n0 + n < N) v = W[(size_t)(k0 + k) * N + n0 + n];
    T[k][n] = v;
  }
  __syncthreads();
#pragma unroll
  for (int i = 0; i < 4; i++) {
    int idx = tid + i * 256;
    int n = idx >> 4, p4 = (idx & 15) * 4;
    int nn = n0 + n;
    int P = (nn >> 1) & 3;
    bf16x4 hv, lv;
#pragma unroll
    for (int e = 0; e < 4; e++) {
      int p = p4 + e;
      int kk = (p & ~31) | ((((p >> 3) & 3) ^ P) << 3) | (p & 7);
      float v = T[kk][n];
      __bf16 h = (__bf16)v;
      hv[e] = h;
      if constexpr (SPLIT) lv[e] = (__bf16)(v - (float)h);
    }
    *(bf16x4*)&Th[(size_t)nn * K + k0 + p4] = hv;
    if constexpr (SPLIT) *(bf16x4*)&Tl[(size_t)nn * K + k0 + p4] = lv;
  }
}

// ---------------- m97-style bf16 MFMA GEMM: A[M][K], B^T[Npad][K] planes, 128x128 tile, BK=32 ----------------
template <bool SPLIT>
__global__ __launch_bounds__(256) void k_gemm2(const __bf16* __restrict__ Ah,
                                               const __bf16* __restrict__ Al,
                                               const __bf16* __restrict__ Bh,
                                               const __bf16* __restrict__ Bl,
                                               float* __restrict__ C,
                                               int M, int N, int K, int ks, int nst) {
  __shared__ __bf16 lds[(SPLIT ? 4 : 2) * 4096];
  __bf16* const AsH = lds;
  __bf16* const BsH = lds + (SPLIT ? 2 : 1) * 4096;
  __bf16* const AsL = SPLIT ? (lds + 4096) : nullptr;
  __bf16* const BsL = SPLIT ? (lds + 3 * 4096) : nullptr;

  const int tid = threadIdx.x;
  const int bn = blockIdx.x, bm = blockIdx.y, z = blockIdx.z;
  const int m0 = bm * 128, n0 = bn * 128;
  const int s0 = (int)(((long long)z * nst) / ks);
  const int s1 = (int)(((long long)(z + 1) * nst) / ks);
  float* __restrict__ Cp = C + (size_t)z * M * N;

  const int lane = tid & 63, wid = tid >> 6;
  const int wr = wid >> 1, wc = wid & 1;
  const int l16 = lane & 15, kl = lane >> 4;

  const int srow = tid >> 2;
  const int schunk = (tid & 3) * 8;
  const size_t aB0 = (size_t)(m0 + srow) * K + schunk;
  const size_t aB1 = aB0 + (size_t)64 * K;
  const size_t bB0 = (size_t)(n0 + srow) * K + schunk;
  const size_t bB1 = bB0 + (size_t)64 * K;
  __bf16* const lA0 = AsH + tid * 8;
  __bf16* const lA1 = AsH + (tid + 256) * 8;
  __bf16* const lB0 = BsH + tid * 8;
  __bf16* const lB1 = BsH + (tid + 256) * 8;

  int aoff[4], boff[4];
#pragma unroll
  for (int mi = 0; mi < 4; mi++) {
    int r = wr * 64 + mi * 16 + l16;
    aoff[mi] = r * 64 + ((kl ^ ((r >> 1) & 3)) << 4);
  }
#pragma unroll
  for (int ni = 0; ni < 4; ni++) {
    int r = wc * 64 + ni * 16 + l16;
    boff[ni] = r * 64 + ((kl ^ ((r >> 1) & 3)) << 4);
  }

  f32x4 acc[4][4];
#pragma unroll
  for (int mi = 0; mi < 4; mi++)
#pragma unroll
    for (int ni = 0; ni < 4; ni++) acc[mi][ni] = f32x4{0.f, 0.f, 0.f, 0.f};

  for (int s = s0; s < s1; ++s) {
    const int k0 = s << 5;
    __syncthreads();
    gl16(Ah + aB0 + k0, lA0);
    gl16(Ah + aB1 + k0, lA1);
    gl16(Bh + bB0 + k0, lB0);
    gl16(Bh + bB1 + k0, lB1);
    if constexpr (SPLIT) {
      gl16(Al + aB0 + k0, AsL + tid * 8);
      gl16(Al + aB1 + k0, AsL + (tid + 256) * 8);
      gl16(Bl + bB0 + k0, BsL + tid * 8);
      gl16(Bl + bB1 + k0, BsL + (tid + 256) * 8);
    }
    __syncthreads();
    bf16x8 ah[4], bh[4];
#pragma unroll
    for (int mi = 0; mi < 4; mi++) ah[mi] = *(const bf16x8*)((const char*)AsH + aoff[mi]);
#pragma unroll
    for (int ni = 0; ni < 4; ni++) bh[ni] = *(const bf16x8*)((const char*)BsH + boff[ni]);
#pragma unroll
    for (int mi = 0; mi < 4; mi++)
#pragma unroll
      for (int ni = 0; ni < 4; ni++)
        acc[mi][ni] = __builtin_amdgcn_mfma_f32_16x16x32_bf16(ah[mi], bh[ni], acc[mi][ni], 0, 0, 0);
    if constexpr (SPLIT) {
      bf16x8 al[4], bl[4];
#pragma unroll
      for (int mi = 0; mi < 4; mi++) al[mi] = *(const bf16x8*)((const char*)AsL + aoff[mi]);
#pragma unroll
      for (int ni = 0; ni < 4; ni++) bl[ni] = *(const bf16x8*)((const char*)BsL + boff[ni]);
#pragma unroll
      for (int mi = 0; mi < 4; mi++)
#pragma unroll
        for (int ni = 0; ni < 4; ni++) {
          acc[mi][ni] = __builtin_amdgcn_mfma_f32_16x16x32_bf16(ah[mi], bl[ni], acc[mi][ni], 0, 0, 0);
          acc[mi][ni] = __builtin_amdgcn_mfma_f32_16x16x32_bf16(al[mi], bh[ni], acc[mi][ni], 0, 0, 0);
        }
    }
  }
#pragma unroll
  for (int mi = 0; mi < 4; mi++)
#pragma unroll
    for (int ni = 0; ni < 4; ni++)
#pragma unroll
      for (int r = 0; r < 4; r++) {
        int row = m0 + wr * 64 + mi * 16 + kl * 4 + r;
        int col = n0 + wc * 64 + ni * 16 + l16;
        if (col < N) Cp[(size_t)row * N + col] = acc[mi][ni][r];
      }
}

// ---------------- partial reduce (+ optional residual) ----------------
template <bool RES>
__global__ void k_reduce(const float* __restrict__ Pp, int np, int n4,
                         const float* __restrict__ res, float* __restrict__ out) {
  int i = blockIdx.x * 256 + threadIdx.x;
  int stride = gridDim.x * 256;
  for (; i < n4; i += stride) {
    float4 a = ((const float4*)Pp)[i];
    for (int z = 1; z < np; z++) {
      float4 b = ((const float4*)Pp)[(size_t)z * n4 + i];
      a.x += b.x; a.y += b.y; a.z += b.z; a.w += b.w;
    }
    if constexpr (RES) {
      float4 r0 = ((const float4*)res)[i];
      a.x += r0.x; a.y += r0.y; a.z += r0.z; a.w += r0.w;
    }
    ((float4*)out)[i] = a;
  }
}

// ---------------- gather slot activations -> swizzled bf16 ----------------
__global__ __launch_bounds__(256) void k_gatherA(const float* __restrict__ xm,
                                                 const int* __restrict__ perm,
                                                 __bf16* __restrict__ Aslots) {
  int s = blockIdx.x, tid = threadIdx.x;
  int t = perm[s];
  int P = (s >> 1) & 3;
  const float* src = xm + (size_t)t * D_MODEL;
  __bf16* dst = Aslots + (size_t)s * D_MODEL;
  for (int i = tid; i < D_MODEL / 4; i += 256) {
    float4 v = ((const float4*)src)[i];
    int p = swz_p(i * 4, P);
    bf16x4 h;
    h[0] = (__bf16)v.x; h[1] = (__bf16)v.y; h[2] = (__bf16)v.z; h[3] = (__bf16)v.w;
    *(bf16x4*)&dst[p] = h;
  }
}

// ---------------- routed expert GEMM: A bf16 slots (swizzled), B f32 [K][N], split-K ----------------
// grid (bnTiles, KS, NEXP); C partial planes of [NSLOTP][N]
template <int KS>
__global__ __launch_bounds__(256) void k_gemmE2(const __bf16* __restrict__ Aall,
                                                const float* __restrict__ Bg,
                                                float* __restrict__ Cp,
                                                const int* __restrict__ expOff,
                                                const int* __restrict__ expCnt,
                                                int N, int K, long long strideB) {
  __shared__ __bf16 Asl[2][128 * 32];
  __shared__ __bf16 Bsl[2][128][40];
  const int tid = threadIdx.x;
  const int bn = blockIdx.x, ks = blockIdx.y, e = blockIdx.z;
  const int cnt = expCnt[e], base = expOff[e];
  if (cnt == 0) return;
  const float* Bp = Bg + (long long)e * strideB;
  const int n0 = bn * 128;
  const int kChunk = K / KS, kBeg = ks * kChunk, nIter = kChunk / 32;
  float* __restrict__ Cpl = Cp + (size_t)ks * NSLOTP * N;
  const int lane = tid & 63, wid = tid >> 6;
  const int wr = wid >> 1, wc = wid & 1;
  const int l16 = lane & 15, kl = lane >> 4;
  const int kb = tid >> 5, cb = tid & 31;        // B staging: 4x4 block (kb*4+j, cb*4+e)
  const int arow = tid >> 2, achk = (tid & 3) * 8;  // A staging
  const bool bok = (n0 + cb * 4) < N;

  int boffs[4];
#pragma unroll
  for (int ni = 0; ni < 4; ni++) boffs[ni] = (wc * 64 + ni * 16 + l16) * 40 + kl * 8;  // elements

  for (int bm = 0; bm * 128 < cnt; ++bm) {
    const int rbase = base + bm * 128;
    int aoff[4];
#pragma unroll
    for (int mi = 0; mi < 4; mi++) {
      int r = wr * 64 + mi * 16 + l16;
      int P = ((rbase + r) >> 1) & 3;
      aoff[mi] = r * 64 + ((kl ^ P) << 4);  // bytes
    }
    f32x4 acc[4][4];
#pragma unroll
    for (int mi = 0; mi < 4; mi++)
#pragma unroll
      for (int ni = 0; ni < 4; ni++) acc[mi][ni] = f32x4{0.f, 0.f, 0.f, 0.f};

    const size_t aBase = (size_t)(rbase + arow) * K + achk + kBeg;
    const size_t aBase2 = aBase + (size_t)64 * K;

    // prologue: stage kt=0
    gl16(Aall + aBase, &Asl[0][tid * 8]);
    gl16(Aall + aBase2, &Asl[0][(tid + 256) * 8]);
    {
      const float* src = Bp + (size_t)(kBeg + kb * 4) * N + n0 + cb * 4;
      f32x4 bv[4];
#pragma unroll
      for (int j = 0; j < 4; j++)
        bv[j] = bok ? *(const f32x4*)(src + (size_t)j * N) : f32x4{0.f, 0.f, 0.f, 0.f};
#pragma unroll
      for (int e4 = 0; e4 < 4; e4++) {
        bf16x4 h;
        h[0] = (__bf16)bv[0][e4]; h[1] = (__bf16)bv[1][e4];
        h[2] = (__bf16)bv[2][e4]; h[3] = (__bf16)bv[3][e4];
        *(bf16x4*)&Bsl[0][cb * 4 + e4][kb * 4] = h;
      }
    }
    __syncthreads();
    int cur = 0;
    for (int kt = 0; kt < nIter; ++kt) {
      const bool more = (kt + 1 < nIter);
      f32x4 nv[4];
      if (more) {
        const int kOff = (kt + 1) * 32;
        gl16(Aall + aBase + kOff, &Asl[cur ^ 1][tid * 8]);
        gl16(Aall + aBase2 + kOff, &Asl[cur ^ 1][(tid + 256) * 8]);
        const float* src = Bp + (size_t)(kBeg + kOff + kb * 4) * N + n0 + cb * 4;
#pragma unroll
        for (int j = 0; j < 4; j++)
          nv[j] = bok ? *(const f32x4*)(src + (size_t)j * N) : f32x4{0.f, 0.f, 0.f, 0.f};
      }
      bf16x8 ah[4], bh[4];
#pragma unroll
      for (int mi = 0; mi < 4; mi++) ah[mi] = *(const bf16x8*)((const char*)&Asl[cur][0] + aoff[mi]);
#pragma unroll
      for (int ni = 0; ni < 4; ni++) bh[ni] = *(const bf16x8*)&Bsl[cur][0][boffs[ni]];
#pragma unroll
      for (int mi = 0; mi < 4; mi++)
#pragma unroll
        for (int ni = 0; ni < 4; ni++)
          acc[mi][ni] = __builtin_amdgcn_mfma_f32_16x16x32_bf16(ah[mi], bh[ni], acc[mi][ni], 0, 0, 0);
      if (more) {
#pragma unroll
        for (int e4 = 0; e4 < 4; e4++) {
          bf16x4 h;
          h[0] = (__bf16)nv[0][e4]; h[1] = (__bf16)nv[1][e4];
          h[2] = (__bf16)nv[2][e4]; h[3] = (__bf16)nv[3][e4];
          *(bf16x4*)&Bsl[cur ^ 1][cb * 4 + e4][kb * 4] = h;
        }
      }
      __syncthreads();
      cur ^= 1;
    }
#pragma unroll
    for (int mi = 0; mi < 4; mi++)
#pragma unroll
      for (int ni = 0; ni < 4; ni++)
#pragma unroll
        for (int r = 0; r < 4; r++) {
          int rl = bm * 128 + wr * 64 + mi * 16 + kl * 4 + r;
          int col = n0 + wc * 64 + ni * 16 + l16;
          if (rl < cnt && col < N) Cpl[(size_t)(base + rl) * N + col] = acc[mi][ni][r];
        }
  }
}

// ---------------- routed: reduce gate/up partials + silu-mul + scale -> swizzled bf16 ----------------
__global__ __launch_bounds__(256) void k_silumulE(const float* __restrict__ gP,
                                                  const float* __restrict__ uP,
                                                  const float* __restrict__ slotw,
                                                  __bf16* __restrict__ outp) {
  int s = blockIdx.x, tid = threadIdx.x;
  float w = slotw[s];
  int P = (s >> 1) & 3;
  const size_t PL = (size_t)NSLOTP * M_INTER;
  for (int i = tid; i < M_INTER / 4; i += 256) {
    f32x4 g = f32x4{0.f, 0.f, 0.f, 0.f}, u = f32x4{0.f, 0.f, 0.f, 0.f};
#pragma unroll
    for (int z = 0; z < 4; z++) {
      g += *(const f32x4*)&gP[z * PL + (size_t)s * M_INTER + i * 4];
      u += *(const f32x4*)&uP[z * PL + (size_t)s * M_INTER + i * 4];
    }
    int p = swz_p(i * 4, P);
    bf16x4 h;
    h[0] = (__bf16)(siluf(g[0]) * u[0] * w);
    h[1] = (__bf16)(siluf(g[1]) * u[1] * w);
    h[2] = (__bf16)(siluf(g[2]) * u[2] * w);
    h[3] = (__bf16)(siluf(g[3]) * u[3] * w);
    *(bf16x4*)&outp[(size_t)s * M_INTER + p] = h;
  }
}

// ---------------- dt softplus ----------------
__global__ void k_dt(const float* __restrict__ zx, const float* __restrict__ dt_bias,
                     const float* __restrict__ A_log, float* __restrict__ dtp,
                     float* __restrict__ dtA) {
  int t = blockIdx.x, h = threadIdx.x;
  if (h < HEADS) {
    float v = zx[(size_t)t * D_INPROJ + 10496 + h] + dt_bias[h];
    float sp = fmaxf(v, 0.f) + log1pf(expf(-fabsf(v)));
    dtp[t * HEADS + h] = sp;
    dtA[t * HEADS + h] = sp * (-expf(A_log[h]));
  }
}

// ---------------- causal depthwise conv + SiLU ----------------
__global__ void k_conv(const float* __restrict__ zx, const float* __restrict__ cw,
                       const float* __restrict__ cb, float* __restrict__ xBC) {
  int cidx = blockIdx.x * 256 + threadIdx.x;
  int t = blockIdx.y;
  if (cidx < CONV_DIM) {
    float acc = cb[cidx];
#pragma unroll
    for (int j = 0; j < 4; j++) {
      int tt = t - 3 + j;
      if (tt >= 0) acc += zx[(size_t)tt * D_INPROJ + D_INNER + cidx] * cw[cidx * 4 + j];
    }
    xBC[(size_t)t * CONV_DIM + cidx] = siluf(acc);
  }
}

// ---------------- scan: intra-chunk ----------------
__global__ __launch_bounds__(256) void k_scan_intra(
    const float* __restrict__ xBC, const float* __restrict__ dtp,
    const float* __restrict__ dtA, float* __restrict__ y, float* __restrict__ S,
    float* __restrict__ cumA, float* __restrict__ Atot) {
  __shared__ float Bs[64][132];
  __shared__ float Cs[64][132];
  __shared__ float Xs[64][68];
  __shared__ float Gs[64][65];
  __shared__ float da_s[64], a_s[64], dt_sh[64], w_sh[64];
  int c = blockIdx.x, h = blockIdx.y, tid = threadIdx.x;
  int t0 = c * QCHUNK;
#pragma unroll
  for (int i = 0; i < 8; i++) {
    int id = tid + 256 * i;
    int r = id >> 5, c4 = (id & 31) * 4;
    *(float4*)&Bs[r][c4] = *(const float4*)&xBC[(size_t)(t0 + r) * CONV_DIM + D_INNER + c4];
    *(float4*)&Cs[r][c4] = *(const float4*)&xBC[(size_t)(t0 + r) * CONV_DIM + D_INNER + N_STATE + c4];
  }
#pragma unroll
  for (int i = 0; i < 4; i++) {
    int id = tid + 256 * i;
    int r = id >> 4, p4 = (id & 15) * 4;
    *(float4*)&Xs[r][p4] = *(const float4*)&xBC[(size_t)(t0 + r) * CONV_DIM + h * P_HEAD + p4];
  }
  if (tid < 64) {
    da_s[tid] = dtA[(size_t)(t0 + tid) * HEADS + h];
    dt_sh[tid] = dtp[(size_t)(t0 + tid) * HEADS + h];
  }
  __syncthreads();
  if (tid < 64) {
    float a = 0.f;
    for (int i = 0; i <= tid; i++) a += da_s[i];
    a_s[tid] = a;
    cumA[((size_t)c * HEADS + h) * 64 + tid] = a;
  }
  __syncthreads();
  if (tid < 64) {
    w_sh[tid] = __expf(a_s[63] - a_s[tid]) * dt_sh[tid];
    if (tid == 0) Atot[c * HEADS + h] = a_s[63];
  }
  __syncthreads();
  {
    int tq = tid >> 4, sq = tid & 15;
    float gacc[4][4];
#pragma unroll
    for (int j = 0; j < 4; j++)
#pragma unroll
      for (int jj = 0; jj < 4; jj++) gacc[j][jj] = 0.f;
    for (int n4 = 0; n4 < 128; n4 += 4) {
      float4 cv[4], bv[4];
#pragma unroll
      for (int j = 0; j < 4; j++) cv[j] = *(const float4*)&Cs[tq * 4 + j][n4];
#pragma unroll
      for (int j = 0; j < 4; j++) bv[j] = *(const float4*)&Bs[sq * 4 + j][n4];
#pragma unroll
      for (int j = 0; j < 4; j++)
#pragma unroll
        for (int jj = 0; jj < 4; jj++)
          gacc[j][jj] += cv[j].x * bv[jj].x + cv[j].y * bv[jj].y + cv[j].z * bv[jj].z + cv[j].w * bv[jj].w;
    }
#pragma unroll
    for (int j = 0; j < 4; j++)
#pragma unroll
      for (int jj = 0; jj < 4; jj++) {
        int t = tq * 4 + j, s = sq * 4 + jj;
        float arg = fminf(a_s[t] - a_s[s], 0.f);
        Gs[t][s] = (s <= t) ? gacc[j][jj] * __expf(arg) * dt_sh[s] : 0.f;
      }
  }
  __syncthreads();
  {
    int tq = tid >> 4, pq = tid & 15;
    float4 acc[4];
#pragma unroll
    for (int j = 0; j < 4; j++) acc[j] = float4{0.f, 0.f, 0.f, 0.f};
    for (int s = 0; s < 64; s++) {
      float4 xv = *(const float4*)&Xs[s][pq * 4];
#pragma unroll
      for (int j = 0; j < 4; j++) {
        float g = Gs[tq * 4 + j][s];
        acc[j].x += g * xv.x; acc[j].y += g * xv.y; acc[j].z += g * xv.z; acc[j].w += g * xv.w;
      }
    }
#pragma unroll
    for (int j = 0; j < 4; j++) {
      int t = tq * 4 + j;
      *(float4*)&y[(size_t)(t0 + t) * D_INNER + h * P_HEAD + pq * 4] = acc[j];
    }
  }
  {
    int p2 = tid >> 5, n4 = (tid & 31) * 4;
    float4 acc[8];
#pragma unroll
    for (int j = 0; j < 8; j++) acc[j] = float4{0.f, 0.f, 0.f, 0.f};
    for (int s = 0; s < 64; s++) {
      float4 bv = *(const float4*)&Bs[s][n4];
#pragma unroll
      for (int j = 0; j < 8; j++) {
        float xw = Xs[s][p2 * 8 + j] * w_sh[s];
        acc[j].x += xw * bv.x; acc[j].y += xw * bv.y; acc[j].z += xw * bv.z; acc[j].w += xw * bv.w;
      }
    }
    size_t bb = ((size_t)(c * HEADS + h) * 64) * 128;
#pragma unroll
    for (int j = 0; j < 8; j++)
      *(float4*)&S[bb + (size_t)(p2 * 8 + j) * 128 + n4] = acc[j];
  }
}

// ---------------- scan: inter-chunk state recurrence ----------------
__global__ void k_scan_state(float* __restrict__ S, const float* __restrict__ Atot) {
  int gid = blockIdx.x * 256 + threadIdx.x;
  int h = gid >> 13;
  int rem = gid & 8191;
  float run = 0.f;
#pragma unroll
  for (int c = 0; c < NCHUNK; c++) {
    size_t idx = ((size_t)(c * HEADS + h) << 13) + rem;
    float s = S[idx];
    S[idx] = run;
    run = run * __expf(Atot[c * HEADS + h]) + s;
  }
}

// ---------------- scan: inter-chunk contribution + D*x ----------------
__global__ __launch_bounds__(256) void k_scan_inter(
    const float* __restrict__ xBC, const float* __restrict__ Hin,
    const float* __restrict__ cumA, const float* __restrict__ Dv,
    float* __restrict__ y) {
  __shared__ float Hs[64][132];
  __shared__ float Cs[64][132];
  __shared__ float a_l[64];
  int c = blockIdx.x, h = blockIdx.y, tid = threadIdx.x;
  int t0 = c * QCHUNK;
#pragma unroll
  for (int i = 0; i < 8; i++) {
    int id = tid + 256 * i;
    int r = id >> 5, n4 = (id & 31) * 4;
    *(float4*)&Hs[r][n4] = *(const float4*)&Hin[(((size_t)(c * HEADS + h) * 64 + r) << 7) + n4];
    *(float4*)&Cs[r][n4] = *(const float4*)&xBC[(size_t)(t0 + r) * CONV_DIM + D_INNER + N_STATE + n4];
  }
  if (tid < 64) a_l[tid] = cumA[((size_t)c * HEADS + h) * 64 + tid];
  __syncthreads();
  float Dh = Dv[h];
  int tq = tid >> 4, pq = tid & 15;
  float4 acc[4];
#pragma unroll
  for (int j = 0; j < 4; j++) acc[j] = float4{0.f, 0.f, 0.f, 0.f};
  for (int n4 = 0; n4 < 128; n4 += 4) {
    float4 hv[4], cv[4];
#pragma unroll
    for (int jj = 0; jj < 4; jj++) hv[jj] = *(const float4*)&Hs[pq * 4 + jj][n4];
#pragma unroll
    for (int j = 0; j < 4; j++) cv[j] = *(const float4*)&Cs[tq * 4 + j][n4];
#pragma unroll
    for (int j = 0; j < 4; j++) {
      acc[j].x += cv[j].x * hv[0].x + cv[j].y * hv[0].y + cv[j].z * hv[0].z + cv[j].w * hv[0].w;
      acc[j].y += cv[j].x * hv[1].x + cv[j].y * hv[1].y + cv[j].z * hv[1].z + cv[j].w * hv[1].w;
      acc[j].z += cv[j].x * hv[2].x + cv[j].y * hv[2].y + cv[j].z * hv[2].z + cv[j].w * hv[2].w;
      acc[j].w += cv[j].x * hv[3].x + cv[j].y * hv[3].y + cv[j].z * hv[3].z + cv[j].w * hv[3].w;
    }
  }
#pragma unroll
  for (int j = 0; j < 4; j++) {
    int t = tq * 4 + j;
    float e = __expf(a_l[t]);
    float4 xv = *(const float4*)&xBC[(size_t)(t0 + t) * CONV_DIM + h * P_HEAD + pq * 4];
    size_t yoff = (size_t)(t0 + t) * D_INNER + h * P_HEAD + pq * 4;
    float4 yv = *(float4*)&y[yoff];
    yv.x += e * acc[j].x + Dh * xv.x;
    yv.y += e * acc[j].y + Dh * xv.y;
    yv.z += e * acc[j].z + Dh * xv.z;
    yv.w += e * acc[j].w + Dh * xv.w;
    *(float4*)&y[yoff] = yv;
  }
}

// ---------------- gated RMSNorm -> swizzled bf16 planes ----------------
__global__ __launch_bounds__(256) void k_gatednorm_p(const float* __restrict__ y,
                                                     const float* __restrict__ zx,
                                                     const float* __restrict__ w,
                                                     __bf16* __restrict__ ph,
                                                     __bf16* __restrict__ pl) {
  __shared__ float vbuf[D_INNER];
  __shared__ float red[4];
  int t = blockIdx.x, tid = threadIdx.x;
  float ss = 0.f;
  for (int i = tid; i < D_INNER / 4; i += 256) {
    float4 yv = *(const float4*)&y[(size_t)t * D_INNER + i * 4];
    float4 zv = *(const float4*)&zx[(size_t)t * D_INPROJ + i * 4];
    float4 v;
    v.x = yv.x * siluf(zv.x); v.y = yv.y * siluf(zv.y);
    v.z = yv.z * siluf(zv.z); v.w = yv.w * siluf(zv.w);
    *(float4*)&vbuf[i * 4] = v;
    ss += v.x * v.x + v.y * v.y + v.z * v.z + v.w * v.w;
  }
  float tot = block_sum256(ss, red);
  float r = rsqrtf(tot / (float)D_INNER + 1e-6f);
  int P = (t >> 1) & 3;
  for (int i = tid; i < D_INNER / 4; i += 256) {
    float4 v = *(const float4*)&vbuf[i * 4];
    float4 wv = *(const float4*)&w[i * 4];
    float4 o;
    o.x = wv.x * v.x * r; o.y = wv.y * v.y * r; o.z = wv.z * v.z * r; o.w = wv.w * v.w * r;
    int p = swz_p(i * 4, P);
    bf16x4 hv;
    hv[0] = (__bf16)o.x; hv[1] = (__bf16)o.y; hv[2] = (__bf16)o.z; hv[3] = (__bf16)o.w;
    *(bf16x4*)&ph[(size_t)t * D_INNER + p] = hv;
    bf16x4 lv;
    lv[0] = (__bf16)(o.x - (float)hv[0]); lv[1] = (__bf16)(o.y - (float)hv[1]);
    lv[2] = (__bf16)(o.z - (float)hv[2]); lv[3] = (__bf16)(o.w - (float)hv[3]);
    *(bf16x4*)&pl[(size_t)t * D_INNER + p] = lv;
  }
}

// ---------------- router ----------------
__global__ void k_zero(int* counts, int* cursor) {
  int i = threadIdx.x;
  if (i < NEXP) { counts[i] = 0; cursor[i] = 0; }
}

__global__ __launch_bounds__(256) void k_router(const float* __restrict__ xm,
                                                const float* __restrict__ Wr,
                                                int* __restrict__ top_i,
                                                float* __restrict__ top_v,
                                                int* __restrict__ counts) {
  __shared__ float part[16][17];
  __shared__ float lg[16];
  int t = blockIdx.x, tid = threadIdx.x;
  int e = tid & 15, seg = tid >> 4;
  const float* xr = xm + (size_t)t * D_MODEL;
  float s = 0.f;
  for (int i = 0; i < 160; i++) {
    int k = seg * 160 + i;
    s += xr[k] * Wr[(size_t)k * NEXP + e];
  }
  part[seg][e] = s;
  __syncthreads();
  if (tid < 16) {
    float l = 0.f;
    for (int g = 0; g < 16; g++) l += part[g][tid];
    lg[tid] = l;
  }
  __syncthreads();
  if (tid == 0) {
    float mx = lg[0];
    for (int i = 1; i < 16; i++) mx = fmaxf(mx, lg[i]);
    float pe[16];
    for (int i = 0; i < 16; i++) pe[i] = expf(lg[i] - mx);
    int i0 = 0; float v0 = pe[0];
    for (int i = 1; i < 16; i++) if (pe[i] > v0) { v0 = pe[i]; i0 = i; }
    int i1 = -1; float v1 = -1.f;
    for (int i = 0; i < 16; i++) if (i != i0 && pe[i] > v1) { v1 = pe[i]; i1 = i; }
    float inv = 1.f / (v0 + v1);
    top_i[t * 2] = i0; top_i[t * 2 + 1] = i1;
    top_v[t * 2] = v0 * inv; top_v[t * 2 + 1] = v1 * inv;
    atomicAdd(&counts[i0], 1);
    atomicAdd(&counts[i1], 1);
  }
}

__global__ void k_offsets(const int* counts, int* offs, int* cursor) {
  if (threadIdx.x == 0) {
    int s = 0;
    for (int e = 0; e < NEXP; e++) { offs[e] = s; cursor[e] = s; s += counts[e]; }
  }
}

__global__ void k_scatter(const int* __restrict__ top_i, const float* __restrict__ top_v,
                          int* __restrict__ cursor, int* __restrict__ perm,
                          int* __restrict__ slotOf, float* __restrict__ slotw) {
  int t = blockIdx.x * 256 + threadIdx.x;
  if (t < SEQ) {
    for (int k = 0; k < 2; k++) {
      int e = top_i[t * 2 + k];
      int pos = atomicAdd(&cursor[e], 1);
      perm[pos] = t;
      slotOf[t * 2 + k] = pos;
      slotw[pos] = top_v[t * 2 + k];
    }
  }
}

// ---------------- silu-mul: shared -> swizzled bf16 plane ----------------
__global__ void k_silumul_sh(const float* __restrict__ g, const float* __restrict__ u,
                             __bf16* __restrict__ outp) {
  int m = blockIdx.x, tid = threadIdx.x;
  int P = (m >> 1) & 3;
  for (int i = tid; i < MS_INTER / 4; i += 256) {
    float4 gv = *(const float4*)&g[(size_t)m * MS_INTER + i * 4];
    float4 uv = *(const float4*)&u[(size_t)m * MS_INTER + i * 4];
    float4 o;
    o.x = siluf(gv.x) * uv.x; o.y = siluf(gv.y) * uv.y;
    o.z = siluf(gv.z) * uv.z; o.w = siluf(gv.w) * uv.w;
    int p = swz_p(i * 4, P);
    bf16x4 hv;
    hv[0] = (__bf16)o.x; hv[1] = (__bf16)o.y; hv[2] = (__bf16)o.z; hv[3] = (__bf16)o.w;
    *(bf16x4*)&outp[(size_t)m * MS_INTER + p] = hv;
  }
}

// ---------------- final combine (3 down-partial planes) ----------------
__global__ void k_final2(const float* __restrict__ hidden, const float* __restrict__ sh,
                         const float* __restrict__ dsP, const int* __restrict__ slotOf,
                         float* __restrict__ out) {
  int t = blockIdx.y;
  int d4 = (blockIdx.x * 256 + threadIdx.x) * 4;
  if (d4 < D_MODEL) {
    int s0 = slotOf[t * 2], s1 = slotOf[t * 2 + 1];
    f32x4 a = *(const f32x4*)&hidden[(size_t)t * D_MODEL + d4];
    f32x4 b = *(const f32x4*)&sh[(size_t)t * D_MODEL + d4];
    f32x4 acc = a + b;
    const size_t PL = (size_t)NSLOTP * D_MODEL;
#pragma unroll
    for (int z = 0; z < 3; z++) {
      acc += *(const f32x4*)&dsP[z * PL + (size_t)s0 * D_MODEL + d4];
      acc += *(const f32x4*)&dsP[z * PL + (size_t)s1 * D_MODEL + d4];
    }
    *(f32x4*)&out[(size_t)t * D_MODEL + d4] = acc;
  }
}

// ---------------- launch ----------------
extern "C" void kernel_launch(void* const* d_in, const int* in_sizes, int n_in,
                              void* d_out, int out_size, void* d_ws, size_t ws_size,
                              hipStream_t stream) {
  const float* hs = (const float*)d_in[0];
  const float* w_in = (const float*)d_in[1];
  const float* conv_w = (const float*)d_in[2];
  const float* conv_b = (const float*)d_in[3];
  const float* dt_bias = (const float*)d_in[4];
  const float* A_log = (const float*)d_in[5];
  const float* Dv = (const float*)d_in[6];
  const float* mnw = (const float*)d_in[7];
  const float* w_out = (const float*)d_in[8];
  const float* ln1 = (const float*)d_in[9];
  const float* ln2 = (const float*)d_in[10];
  const float* router_w = (const float*)d_in[11];
  const float* we_gate = (const float*)d_in[12];
  const float* we_up = (const float*)d_in[13];
  const float* we_down = (const float*)d_in[14];
  const float* ws_gate = (const float*)d_in[15];
  const float* ws_up = (const float*)d_in[16];
  const float* ws_down = (const float*)d_in[17];

  char* base = (char*)d_ws;
  size_t off = 0;
  auto A = [&](size_t bytes) -> void* {
    void* p = base + off;
    off += (bytes + 255) & ~(size_t)255;
    return p;
  };
  float* zx = (float*)A((size_t)SEQ * D_INPROJ * 4);
  float* xbc = (float*)A((size_t)SEQ * CONV_DIM * 4);
  float* xmf = (float*)A((size_t)SEQ * D_MODEL * 4);
  float* dtp = (float*)A((size_t)SEQ * HEADS * 4);
  float* dtA = (float*)A((size_t)SEQ * HEADS * 4);
  float* yf = (float*)A((size_t)SEQ * D_INNER * 4);
  float* cumA = (float*)A((size_t)NCHUNK * HEADS * 64 * 4);
  float* Atot = (float*)A((size_t)NCHUNK * HEADS * 4);
  float* Sbuf = (float*)A((size_t)NCHUNK * HEADS * 64 * 128 * 4);
  float* hidden = (float*)A((size_t)SEQ * D_MODEL * 4);
  float* shout = (float*)A((size_t)SEQ * D_MODEL * 4);
  float* top_v = (float*)A(8192);
  float* slotw = (float*)A(8192);
  int* top_i = (int*)A(8192);
  int* counts = (int*)A(64);
  int* offs = (int*)A(64);
  int* cursor = (int*)A(64);
  int* perm = (int*)A(8192);
  int* slotOf = (int*)A(8192);
  __bf16* xp_h = (__bf16*)A((size_t)SEQ * D_MODEL * 2);
  __bf16* xp_l = (__bf16*)A((size_t)SEQ * D_MODEL * 2);
  __bf16* ybp_h = (__bf16*)A((size_t)SEQ * D_INNER * 2);
  __bf16* ybp_l = (__bf16*)A((size_t)SEQ * D_INNER * 2);
  __bf16* gbuf_bh = (__bf16*)A((size_t)SEQ * MS_INTER * 2);
  char* REG = (char*)A((size_t)146000000);

  // Phase M aliases
  __bf16* winT_h = (__bf16*)REG;                       // [10624][2560]
  __bf16* winT_l = (__bf16*)(REG + 54394880);
  __bf16* woutT_h = (__bf16*)REG;                      // [2560][5120]
  __bf16* woutT_l = (__bf16*)(REG + 26214400);
  float* partials = (float*)(REG + 60000000);          // up to 4x1024x2560 f32
  // Phase S aliases
  __bf16* gateT = (__bf16*)REG;                        // [1792][2560]
  __bf16* upT = (__bf16*)(REG + 9175040);
  __bf16* downT = (__bf16*)(REG + 18350080);           // [2560][1728]
  float* gbufF = (float*)(REG + 30000000);             // [1024][1728]
  float* ubufF = (float*)(REG + 38000000);
  // Phase R aliases
  __bf16* Aslots = (__bf16*)REG;                       // [2176][2560]
  __bf16* gsl = (__bf16*)(REG + 12000000);             // [2176][864]
  float* gateP = (float*)(REG + 16000000);             // 4x[2176][864]
  float* upP = (float*)(REG + 47000000);
  float* dslotsP = (float*)(REG + 78000000);           // 3x[2176][2560]

  // ---- Mamba sub-block ----
  k_rmsnorm_p<<<SEQ, 256, 0, stream>>>(hs, ln1, nullptr, xp_h, xp_l, D_MODEL);
  k_transW<true><<<dim3(166, 40), 256, 0, stream>>>(w_in, D_MODEL, D_INPROJ, winT_h, winT_l);
  k_gemm2<true><<<dim3(83, 8, 1), 256, 0, stream>>>(xp_h, xp_l, winT_h, winT_l, zx,
                                                    SEQ, D_INPROJ, D_MODEL, 1, 80);
  k_dt<<<SEQ, 128, 0, stream>>>(zx, dt_bias, A_log, dtp, dtA);
  k_conv<<<dim3(21, SEQ), 256, 0, stream>>>(zx, conv_w, conv_b, xbc);
  k_scan_intra<<<dim3(NCHUNK, HEADS), 256, 0, stream>>>(xbc, dtp, dtA, yf, Sbuf, cumA, Atot);
  k_scan_state<<<2560, 256, 0, stream>>>(Sbuf, Atot);
  k_scan_inter<<<dim3(NCHUNK, HEADS), 256, 0, stream>>>(xbc, Sbuf, cumA, Dv, yf);
  k_gatednorm_p<<<SEQ, 256, 0, stream>>>(yf, zx, mnw, ybp_h, ybp_l);
  k_transW<true><<<dim3(40, 80), 256, 0, stream>>>(w_out, D_INNER, D_MODEL, woutT_h, woutT_l);
  k_gemm2<true><<<dim3(20, 8, 4), 256, 0, stream>>>(ybp_h, ybp_l, woutT_h, woutT_l, partials,
                                                    SEQ, D_MODEL, D_INNER, 4, 160);
  k_reduce<true><<<2048, 256, 0, stream>>>(partials, 4, SEQ * D_MODEL / 4, hs, hidden);

  // ---- MoE sub-block ----
  k_rmsnorm_p<<<SEQ, 256, 0, stream>>>(hidden, ln2, xmf, xp_h, nullptr, D_MODEL);
  k_zero<<<1, 64, 0, stream>>>(counts, cursor);
  k_router<<<SEQ, 256, 0, stream>>>(xmf, router_w, top_i, top_v, counts);
  k_offsets<<<1, 32, 0, stream>>>(counts, offs, cursor);
  k_scatter<<<4, 256, 0, stream>>>(top_i, top_v, cursor, perm, slotOf, slotw);

  // shared experts
  k_transW<false><<<dim3(28, 40), 256, 0, stream>>>(ws_gate, D_MODEL, MS_INTER, gateT, nullptr);
  k_gemm2<false><<<dim3(14, 8, 4), 256, 0, stream>>>(xp_h, nullptr, gateT, nullptr, partials,
                                                     SEQ, MS_INTER, D_MODEL, 4, 80);
  k_reduce<false><<<2048, 256, 0, stream>>>(partials, 4, SEQ * MS_INTER / 4, nullptr, gbufF);
  k_transW<false><<<dim3(28, 40), 256, 0, stream>>>(ws_up, D_MODEL, MS_INTER, upT, nullptr);
  k_gemm2<false><<<dim3(14, 8, 4), 256, 0, stream>>>(xp_h, nullptr, upT, nullptr, partials,
                                                     SEQ, MS_INTER, D_MODEL, 4, 80);
  k_reduce<false><<<2048, 256, 0, stream>>>(partials, 4, SEQ * MS_INTER / 4, nullptr, ubufF);
  k_silumul_sh<<<SEQ, 256, 0, stream>>>(gbufF, ubufF, gbuf_bh);
  k_transW<false><<<dim3(40, 27), 256, 0, stream>>>(ws_down, MS_INTER, D_MODEL, downT, nullptr);
  k_gemm2<false><<<dim3(20, 8, 4), 256, 0, stream>>>(gbuf_bh, nullptr, downT, nullptr, partials,
                                                     SEQ, D_MODEL, MS_INTER, 4, 54);
  k_reduce<false><<<2048, 256, 0, stream>>>(partials, 4, SEQ * D_MODEL / 4, nullptr, shout);

  // routed experts
  k_gatherA<<<NSLOT, 256, 0, stream>>>(xmf, perm, Aslots);
  k_gemmE2<4><<<dim3(7, 4, NEXP), 256, 0, stream>>>(Aslots, we_gate, gateP, offs, counts,
                                                    M_INTER, D_MODEL, (long long)D_MODEL * M_INTER);
  k_gemmE2<4><<<dim3(7, 4, NEXP), 256, 0, stream>>>(Aslots, we_up, upP, offs, counts,
                                                    M_INTER, D_MODEL, (long long)D_MODEL * M_INTER);
  k_silumulE<<<NSLOT, 256, 0, stream>>>(gateP, upP, slotw, gsl);
  k_gemmE2<3><<<dim3(20, 3, NEXP), 256, 0, stream>>>(gsl, we_down, dslotsP, offs, counts,
                                                     D_MODEL, M_INTER, (long long)M_INTER * D_MODEL);

  k_final2<<<dim3(3, SEQ), 256, 0, stream>>>(hidden, shout, dslotsP, slotOf, (float*)d_out);
}

// Round 5
// 977.454 us; speedup vs baseline: 2.7660x; 1.0396x over previous
//
#include <hip/hip_runtime.h>

// ---------------- types ----------------
typedef __attribute__((ext_vector_type(4))) float f32x4;
typedef __attribute__((ext_vector_type(8))) __bf16 bf16x8;
typedef __attribute__((ext_vector_type(4))) __bf16 bf16x4;

#define D_MODEL 2560
#define D_INNER 5120
#define N_STATE 128
#define HEADS 80
#define P_HEAD 64
#define CONV_DIM 5376
#define D_INPROJ 10576
#define SEQ 1024
#define NCHUNK 16
#define QCHUNK 64
#define NEXP 16
#define M_INTER 864
#define MS_INTER 1728
#define NSLOT 2048
#define NSLOTP 2176   // padded slot rows

__device__ __forceinline__ float siluf(float x) { return x / (1.f + __expf(-x)); }

// swizzled chunk position: within each 32-elem K-group, 16B chunk c stored at c ^ P
__device__ __forceinline__ int swz_p(int k4, int P) {
  return (k4 & ~31) | ((((k4 >> 3) & 3) ^ P) << 3) | (k4 & 7);
}

__device__ __forceinline__ void gl16(const __bf16* g, __bf16* l) {
  __builtin_amdgcn_global_load_lds((const __attribute__((address_space(1))) unsigned int*)g,
                                   (__attribute__((address_space(3))) unsigned int*)l, 16, 0, 0);
}

__device__ __forceinline__ float block_sum256(float v, float* red) {
#pragma unroll
  for (int m = 32; m > 0; m >>= 1) v += __shfl_xor(v, m, 64);
  int w = threadIdx.x >> 6;
  if ((threadIdx.x & 63) == 0) red[w] = v;
  __syncthreads();
  return red[0] + red[1] + red[2] + red[3];
}

// ---------------- RMSNorm -> f32 (optional) + swizzled bf16 planes ----------------
__global__ __launch_bounds__(256) void k_rmsnorm_p(const float* __restrict__ in,
                                                   const float* __restrict__ w,
                                                   float* __restrict__ f32out,
                                                   __bf16* __restrict__ ph,
                                                   __bf16* __restrict__ pl, int D) {
  __shared__ float red[4];
  int t = blockIdx.x, tid = threadIdx.x;
  const float* x = in + (size_t)t * D;
  int nd4 = D >> 2;
  float ss = 0.f;
  for (int i = tid; i < nd4; i += 256) {
    float4 v = ((const float4*)x)[i];
    ss += v.x * v.x + v.y * v.y + v.z * v.z + v.w * v.w;
  }
  float tot = block_sum256(ss, red);
  float r = rsqrtf(tot / (float)D + 1e-6f);
  int P = (t >> 1) & 3;
  for (int i = tid; i < nd4; i += 256) {
    float4 v = ((const float4*)x)[i];
    float4 wv = ((const float4*)w)[i];
    float4 o;
    o.x = wv.x * v.x * r; o.y = wv.y * v.y * r; o.z = wv.z * v.z * r; o.w = wv.w * v.w * r;
    if (f32out) ((float4*)(f32out + (size_t)t * D))[i] = o;
    int p = swz_p(i * 4, P);
    bf16x4 hv;
    hv[0] = (__bf16)o.x; hv[1] = (__bf16)o.y; hv[2] = (__bf16)o.z; hv[3] = (__bf16)o.w;
    *(bf16x4*)&ph[(size_t)t * D + p] = hv;
    if (pl) {
      bf16x4 lv;
      lv[0] = (__bf16)(o.x - (float)hv[0]); lv[1] = (__bf16)(o.y - (float)hv[1]);
      lv[2] = (__bf16)(o.z - (float)hv[2]); lv[3] = (__bf16)(o.w - (float)hv[3]);
      *(bf16x4*)&pl[(size_t)t * D + p] = lv;
    }
  }
}

// ---------------- weight transpose+convert: f32 [K][N] -> bf16 [Npad][K] (swizzled) ----------------
template <bool SPLIT>
__global__ __launch_bounds__(256) void k_transW(const float* __restrict__ W, int K, int N,
                                                __bf16* __restrict__ Th, __bf16* __restrict__ Tl) {
  __shared__ float T[64][65];
  const int n0 = blockIdx.x * 64, k0 = blockIdx.y * 64, tid = threadIdx.x;
#pragma unroll
  for (int i = 0; i < 16; i++) {
    int idx = tid + i * 256;
    int k = idx >> 6, n = idx & 63;
    float v = 0.f;
    if (n0 + n < N) v = W[(size_t)(k0 + k) * N + n0 + n];
    T[k][n] = v;
  }
  __syncthreads();
#pragma unroll
  for (int i = 0; i < 4; i++) {
    int idx = tid + i * 256;
    int n = idx >> 4, p4 = (idx & 15) * 4;
    int nn = n0 + n;
    int P = (nn >> 1) & 3;
    bf16x4 hv, lv;
#pragma unroll
    for (int e = 0; e < 4; e++) {
      int p = p4 + e;
      int kk = (p & ~31) | ((((p >> 3) & 3) ^ P) << 3) | (p & 7);
      float v = T[kk][n];
      __bf16 h = (__bf16)v;
      hv[e] = h;
      if constexpr (SPLIT) lv[e] = (__bf16)(v - (float)h);
    }
    *(bf16x4*)&Th[(size_t)nn * K + k0 + p4] = hv;
    if constexpr (SPLIT) *(bf16x4*)&Tl[(size_t)nn * K + k0 + p4] = lv;
  }
}

// ---------------- pipelined bf16 MFMA GEMM: A[M][K], B^T[Npad][K] planes, 128x128, BK=32, dbuf ----------------
// grid: (bmTiles, bnTiles, KS)  — bm fastest for B-panel L2/L3 reuse
template <bool SPLIT>
__global__ __launch_bounds__(256) void k_gemm2(const __bf16* __restrict__ Ah,
                                               const __bf16* __restrict__ Al,
                                               const __bf16* __restrict__ Bh,
                                               const __bf16* __restrict__ Bl,
                                               float* __restrict__ C,
                                               int M, int N, int K, int ks, int nst) {
  constexpr int NP = SPLIT ? 4 : 2;
  __shared__ __bf16 lds[2 * NP * 4096];
  const int tid = threadIdx.x;
  const int bm = blockIdx.x, bn = blockIdx.y, z = blockIdx.z;
  const int m0 = bm * 128, n0 = bn * 128;
  const int s0 = (int)(((long long)z * nst) / ks);
  const int s1 = (int)(((long long)(z + 1) * nst) / ks);
  float* __restrict__ Cp = C + (size_t)z * M * N;

  const int lane = tid & 63, wid = tid >> 6;
  const int wr = wid >> 1, wc = wid & 1;
  const int l16 = lane & 15, kl = lane >> 4;

  const int srow = tid >> 2;
  const int schunk = (tid & 3) * 8;
  const size_t aB0 = (size_t)(m0 + srow) * K + schunk;
  const size_t aB1 = aB0 + (size_t)64 * K;
  const size_t bB0 = (size_t)(n0 + srow) * K + schunk;
  const size_t bB1 = bB0 + (size_t)64 * K;

  int aoff[4], boff[4];
#pragma unroll
  for (int mi = 0; mi < 4; mi++) {
    int r = wr * 64 + mi * 16 + l16;
    aoff[mi] = r * 64 + ((kl ^ ((r >> 1) & 3)) << 4);   // bytes within plane
  }
#pragma unroll
  for (int ni = 0; ni < 4; ni++) {
    int r = wc * 64 + ni * 16 + l16;
    boff[ni] = r * 64 + ((kl ^ ((r >> 1) & 3)) << 4);
  }

  f32x4 acc[4][4];
#pragma unroll
  for (int mi = 0; mi < 4; mi++)
#pragma unroll
    for (int ni = 0; ni < 4; ni++) acc[mi][ni] = f32x4{0.f, 0.f, 0.f, 0.f};

  auto STAGE = [&](int b, int kk) {
    __bf16* L = lds + (size_t)b * NP * 4096;
    gl16(Ah + aB0 + kk, L + tid * 8);
    gl16(Ah + aB1 + kk, L + (tid + 256) * 8);
    gl16(Bh + bB0 + kk, L + (SPLIT ? 2 : 1) * 4096 + tid * 8);
    gl16(Bh + bB1 + kk, L + (SPLIT ? 2 : 1) * 4096 + (tid + 256) * 8);
    if constexpr (SPLIT) {
      gl16(Al + aB0 + kk, L + 4096 + tid * 8);
      gl16(Al + aB1 + kk, L + 4096 + (tid + 256) * 8);
      gl16(Bl + bB0 + kk, L + 3 * 4096 + tid * 8);
      gl16(Bl + bB1 + kk, L + 3 * 4096 + (tid + 256) * 8);
    }
  };

  STAGE(0, s0 << 5);
  __syncthreads();                 // compiler drains vmcnt(0) before barrier
  int cur = 0;
  for (int s = s0; s < s1; ++s) {
    if (s + 1 < s1) STAGE(cur ^ 1, (s + 1) << 5);   // loads fly during MFMA below
    const __bf16* L = lds + (size_t)cur * NP * 4096;
    const char* AsH = (const char*)L;
    const char* BsH = (const char*)(L + (SPLIT ? 2 : 1) * 4096);
    bf16x8 ah[4], bh[4];
#pragma unroll
    for (int mi = 0; mi < 4; mi++) ah[mi] = *(const bf16x8*)(AsH + aoff[mi]);
#pragma unroll
    for (int ni = 0; ni < 4; ni++) bh[ni] = *(const bf16x8*)(BsH + boff[ni]);
#pragma unroll
    for (int mi = 0; mi < 4; mi++)
#pragma unroll
      for (int ni = 0; ni < 4; ni++)
        acc[mi][ni] = __builtin_amdgcn_mfma_f32_16x16x32_bf16(ah[mi], bh[ni], acc[mi][ni], 0, 0, 0);
    if constexpr (SPLIT) {
      const char* AsL = (const char*)(L + 4096);
      const char* BsL = (const char*)(L + 3 * 4096);
      bf16x8 al[4], bl[4];
#pragma unroll
      for (int mi = 0; mi < 4; mi++) al[mi] = *(const bf16x8*)(AsL + aoff[mi]);
#pragma unroll
      for (int ni = 0; ni < 4; ni++) bl[ni] = *(const bf16x8*)(BsL + boff[ni]);
#pragma unroll
      for (int mi = 0; mi < 4; mi++)
#pragma unroll
        for (int ni = 0; ni < 4; ni++) {
          acc[mi][ni] = __builtin_amdgcn_mfma_f32_16x16x32_bf16(ah[mi], bl[ni], acc[mi][ni], 0, 0, 0);
          acc[mi][ni] = __builtin_amdgcn_mfma_f32_16x16x32_bf16(al[mi], bh[ni], acc[mi][ni], 0, 0, 0);
        }
    }
    __syncthreads();               // drains this iter's STAGE + orders buffer reuse
    cur ^= 1;
  }
#pragma unroll
  for (int mi = 0; mi < 4; mi++)
#pragma unroll
    for (int ni = 0; ni < 4; ni++)
#pragma unroll
      for (int r = 0; r < 4; r++) {
        int row = m0 + wr * 64 + mi * 16 + kl * 4 + r;
        int col = n0 + wc * 64 + ni * 16 + l16;
        if (col < N) Cp[(size_t)row * N + col] = acc[mi][ni][r];
      }
}

// ---------------- partial reduce (+ optional residual) ----------------
template <bool RES>
__global__ void k_reduce(const float* __restrict__ Pp, int np, int n4,
                         const float* __restrict__ res, float* __restrict__ out) {
  int i = blockIdx.x * 256 + threadIdx.x;
  int stride = gridDim.x * 256;
  for (; i < n4; i += stride) {
    float4 a = ((const float4*)Pp)[i];
    for (int z = 1; z < np; z++) {
      float4 b = ((const float4*)Pp)[(size_t)z * n4 + i];
      a.x += b.x; a.y += b.y; a.z += b.z; a.w += b.w;
    }
    if constexpr (RES) {
      float4 r0 = ((const float4*)res)[i];
      a.x += r0.x; a.y += r0.y; a.z += r0.z; a.w += r0.w;
    }
    ((float4*)out)[i] = a;
  }
}

// ---------------- gather slot activations -> swizzled bf16 ----------------
__global__ __launch_bounds__(256) void k_gatherA(const float* __restrict__ xm,
                                                 const int* __restrict__ perm,
                                                 __bf16* __restrict__ Aslots) {
  int s = blockIdx.x, tid = threadIdx.x;
  int t = perm[s];
  int P = (s >> 1) & 3;
  const float* src = xm + (size_t)t * D_MODEL;
  __bf16* dst = Aslots + (size_t)s * D_MODEL;
  for (int i = tid; i < D_MODEL / 4; i += 256) {
    float4 v = ((const float4*)src)[i];
    int p = swz_p(i * 4, P);
    bf16x4 h;
    h[0] = (__bf16)v.x; h[1] = (__bf16)v.y; h[2] = (__bf16)v.z; h[3] = (__bf16)v.w;
    *(bf16x4*)&dst[p] = h;
  }
}

// ---------------- routed expert GEMM: A bf16 slots (swizzled), B f32 [K][N], split-K ----------------
template <int KS>
__global__ __launch_bounds__(256) void k_gemmE2(const __bf16* __restrict__ Aall,
                                                const float* __restrict__ Bg,
                                                float* __restrict__ Cp,
                                                const int* __restrict__ expOff,
                                                const int* __restrict__ expCnt,
                                                int N, int K, long long strideB) {
  __shared__ __bf16 Asl[2][128 * 32];
  __shared__ __bf16 Bsl[2][128][40];
  const int tid = threadIdx.x;
  const int bn = blockIdx.x, ks = blockIdx.y, e = blockIdx.z;
  const int cnt = expCnt[e], base = expOff[e];
  if (cnt == 0) return;
  const float* Bp = Bg + (long long)e * strideB;
  const int n0 = bn * 128;
  const int kChunk = K / KS, kBeg = ks * kChunk, nIter = kChunk / 32;
  float* __restrict__ Cpl = Cp + (size_t)ks * NSLOTP * N;
  const int lane = tid & 63, wid = tid >> 6;
  const int wr = wid >> 1, wc = wid & 1;
  const int l16 = lane & 15, kl = lane >> 4;
  const int kb = tid >> 5, cb = tid & 31;
  const int arow = tid >> 2, achk = (tid & 3) * 8;
  const bool bok = (n0 + cb * 4) < N;

  int boffs[4];
#pragma unroll
  for (int ni = 0; ni < 4; ni++) boffs[ni] = (wc * 64 + ni * 16 + l16) * 40 + kl * 8;

  for (int bm = 0; bm * 128 < cnt; ++bm) {
    const int rbase = base + bm * 128;
    int aoff[4];
#pragma unroll
    for (int mi = 0; mi < 4; mi++) {
      int r = wr * 64 + mi * 16 + l16;
      int P = ((rbase + r) >> 1) & 3;
      aoff[mi] = r * 64 + ((kl ^ P) << 4);
    }
    f32x4 acc[4][4];
#pragma unroll
    for (int mi = 0; mi < 4; mi++)
#pragma unroll
      for (int ni = 0; ni < 4; ni++) acc[mi][ni] = f32x4{0.f, 0.f, 0.f, 0.f};

    const size_t aBase = (size_t)(rbase + arow) * K + achk + kBeg;
    const size_t aBase2 = aBase + (size_t)64 * K;

    gl16(Aall + aBase, &Asl[0][tid * 8]);
    gl16(Aall + aBase2, &Asl[0][(tid + 256) * 8]);
    {
      const float* src = Bp + (size_t)(kBeg + kb * 4) * N + n0 + cb * 4;
      f32x4 bv[4];
#pragma unroll
      for (int j = 0; j < 4; j++)
        bv[j] = bok ? *(const f32x4*)(src + (size_t)j * N) : f32x4{0.f, 0.f, 0.f, 0.f};
#pragma unroll
      for (int e4 = 0; e4 < 4; e4++) {
        bf16x4 h;
        h[0] = (__bf16)bv[0][e4]; h[1] = (__bf16)bv[1][e4];
        h[2] = (__bf16)bv[2][e4]; h[3] = (__bf16)bv[3][e4];
        *(bf16x4*)&Bsl[0][cb * 4 + e4][kb * 4] = h;
      }
    }
    __syncthreads();
    int cur = 0;
    for (int kt = 0; kt < nIter; ++kt) {
      const bool more = (kt + 1 < nIter);
      f32x4 nv[4];
      if (more) {
        const int kOff = (kt + 1) * 32;
        gl16(Aall + aBase + kOff, &Asl[cur ^ 1][tid * 8]);
        gl16(Aall + aBase2 + kOff, &Asl[cur ^ 1][(tid + 256) * 8]);
        const float* src = Bp + (size_t)(kBeg + kOff + kb * 4) * N + n0 + cb * 4;
#pragma unroll
        for (int j = 0; j < 4; j++)
          nv[j] = bok ? *(const f32x4*)(src + (size_t)j * N) : f32x4{0.f, 0.f, 0.f, 0.f};
      }
      bf16x8 ah[4], bh[4];
#pragma unroll
      for (int mi = 0; mi < 4; mi++) ah[mi] = *(const bf16x8*)((const char*)&Asl[cur][0] + aoff[mi]);
#pragma unroll
      for (int ni = 0; ni < 4; ni++) bh[ni] = *(const bf16x8*)&Bsl[cur][0][boffs[ni]];
#pragma unroll
      for (int mi = 0; mi < 4; mi++)
#pragma unroll
        for (int ni = 0; ni < 4; ni++)
          acc[mi][ni] = __builtin_amdgcn_mfma_f32_16x16x32_bf16(ah[mi], bh[ni], acc[mi][ni], 0, 0, 0);
      if (more) {
#pragma unroll
        for (int e4 = 0; e4 < 4; e4++) {
          bf16x4 h;
          h[0] = (__bf16)nv[0][e4]; h[1] = (__bf16)nv[1][e4];
          h[2] = (__bf16)nv[2][e4]; h[3] = (__bf16)nv[3][e4];
          *(bf16x4*)&Bsl[cur ^ 1][cb * 4 + e4][kb * 4] = h;
        }
      }
      __syncthreads();
      cur ^= 1;
    }
#pragma unroll
    for (int mi = 0; mi < 4; mi++)
#pragma unroll
      for (int ni = 0; ni < 4; ni++)
#pragma unroll
        for (int r = 0; r < 4; r++) {
          int rl = bm * 128 + wr * 64 + mi * 16 + kl * 4 + r;
          int col = n0 + wc * 64 + ni * 16 + l16;
          if (rl < cnt && col < N) Cpl[(size_t)(base + rl) * N + col] = acc[mi][ni][r];
        }
  }
}

// ---------------- routed: reduce gate/up partials + silu-mul + scale -> swizzled bf16 ----------------
__global__ __launch_bounds__(256) void k_silumulE(const float* __restrict__ gP,
                                                  const float* __restrict__ uP,
                                                  const float* __restrict__ slotw,
                                                  __bf16* __restrict__ outp) {
  int s = blockIdx.x, tid = threadIdx.x;
  float w = slotw[s];
  int P = (s >> 1) & 3;
  const size_t PL = (size_t)NSLOTP * M_INTER;
  for (int i = tid; i < M_INTER / 4; i += 256) {
    f32x4 g = f32x4{0.f, 0.f, 0.f, 0.f}, u = f32x4{0.f, 0.f, 0.f, 0.f};
#pragma unroll
    for (int z = 0; z < 4; z++) {
      g += *(const f32x4*)&gP[z * PL + (size_t)s * M_INTER + i * 4];
      u += *(const f32x4*)&uP[z * PL + (size_t)s * M_INTER + i * 4];
    }
    int p = swz_p(i * 4, P);
    bf16x4 h;
    h[0] = (__bf16)(siluf(g[0]) * u[0] * w);
    h[1] = (__bf16)(siluf(g[1]) * u[1] * w);
    h[2] = (__bf16)(siluf(g[2]) * u[2] * w);
    h[3] = (__bf16)(siluf(g[3]) * u[3] * w);
    *(bf16x4*)&outp[(size_t)s * M_INTER + p] = h;
  }
}

// ---------------- shared: reduce combined gate|up partials + silu-mul -> swizzled bf16 ----------------
__global__ __launch_bounds__(256) void k_silumul_sh2(const float* __restrict__ P4,
                                                     __bf16* __restrict__ outp) {
  int t = blockIdx.x, tid = threadIdx.x;
  int P = (t >> 1) & 3;
  const size_t PL = (size_t)SEQ * 3456;
  for (int i = tid; i < MS_INTER / 4; i += 256) {
    f32x4 g = f32x4{0.f, 0.f, 0.f, 0.f}, u = f32x4{0.f, 0.f, 0.f, 0.f};
#pragma unroll
    for (int z = 0; z < 4; z++) {
      g += *(const f32x4*)&P4[z * PL + (size_t)t * 3456 + i * 4];
      u += *(const f32x4*)&P4[z * PL + (size_t)t * 3456 + 1728 + i * 4];
    }
    int p = swz_p(i * 4, P);
    bf16x4 h;
    h[0] = (__bf16)(siluf(g[0]) * u[0]);
    h[1] = (__bf16)(siluf(g[1]) * u[1]);
    h[2] = (__bf16)(siluf(g[2]) * u[2]);
    h[3] = (__bf16)(siluf(g[3]) * u[3]);
    *(bf16x4*)&outp[(size_t)t * MS_INTER + p] = h;
  }
}

// ---------------- dt softplus ----------------
__global__ void k_dt(const float* __restrict__ zx, const float* __restrict__ dt_bias,
                     const float* __restrict__ A_log, float* __restrict__ dtp,
                     float* __restrict__ dtA) {
  int t = blockIdx.x, h = threadIdx.x;
  if (h < HEADS) {
    float v = zx[(size_t)t * D_INPROJ + 10496 + h] + dt_bias[h];
    float sp = fmaxf(v, 0.f) + log1pf(expf(-fabsf(v)));
    dtp[t * HEADS + h] = sp;
    dtA[t * HEADS + h] = sp * (-expf(A_log[h]));
  }
}

// ---------------- causal depthwise conv + SiLU ----------------
__global__ void k_conv(const float* __restrict__ zx, const float* __restrict__ cw,
                       const float* __restrict__ cb, float* __restrict__ xBC) {
  int cidx = blockIdx.x * 256 + threadIdx.x;
  int t = blockIdx.y;
  if (cidx < CONV_DIM) {
    float acc = cb[cidx];
#pragma unroll
    for (int j = 0; j < 4; j++) {
      int tt = t - 3 + j;
      if (tt >= 0) acc += zx[(size_t)tt * D_INPROJ + D_INNER + cidx] * cw[cidx * 4 + j];
    }
    xBC[(size_t)t * CONV_DIM + cidx] = siluf(acc);
  }
}

// ---------------- scan: intra-chunk ----------------
__global__ __launch_bounds__(256) void k_scan_intra(
    const float* __restrict__ xBC, const float* __restrict__ dtp,
    const float* __restrict__ dtA, float* __restrict__ y, float* __restrict__ S,
    float* __restrict__ cumA, float* __restrict__ Atot) {
  __shared__ float Bs[64][132];
  __shared__ float Cs[64][132];
  __shared__ float Xs[64][68];
  __shared__ float Gs[64][65];
  __shared__ float da_s[64], a_s[64], dt_sh[64], w_sh[64];
  int c = blockIdx.x, h = blockIdx.y, tid = threadIdx.x;
  int t0 = c * QCHUNK;
#pragma unroll
  for (int i = 0; i < 8; i++) {
    int id = tid + 256 * i;
    int r = id >> 5, c4 = (id & 31) * 4;
    *(float4*)&Bs[r][c4] = *(const float4*)&xBC[(size_t)(t0 + r) * CONV_DIM + D_INNER + c4];
    *(float4*)&Cs[r][c4] = *(const float4*)&xBC[(size_t)(t0 + r) * CONV_DIM + D_INNER + N_STATE + c4];
  }
#pragma unroll
  for (int i = 0; i < 4; i++) {
    int id = tid + 256 * i;
    int r = id >> 4, p4 = (id & 15) * 4;
    *(float4*)&Xs[r][p4] = *(const float4*)&xBC[(size_t)(t0 + r) * CONV_DIM + h * P_HEAD + p4];
  }
  if (tid < 64) {
    da_s[tid] = dtA[(size_t)(t0 + tid) * HEADS + h];
    dt_sh[tid] = dtp[(size_t)(t0 + tid) * HEADS + h];
  }
  __syncthreads();
  if (tid < 64) {
    float a = 0.f;
    for (int i = 0; i <= tid; i++) a += da_s[i];
    a_s[tid] = a;
    cumA[((size_t)c * HEADS + h) * 64 + tid] = a;
  }
  __syncthreads();
  if (tid < 64) {
    w_sh[tid] = __expf(a_s[63] - a_s[tid]) * dt_sh[tid];
    if (tid == 0) Atot[c * HEADS + h] = a_s[63];
  }
  __syncthreads();
  {
    int tq = tid >> 4, sq = tid & 15;
    float gacc[4][4];
#pragma unroll
    for (int j = 0; j < 4; j++)
#pragma unroll
      for (int jj = 0; jj < 4; jj++) gacc[j][jj] = 0.f;
    for (int n4 = 0; n4 < 128; n4 += 4) {
      float4 cv[4], bv[4];
#pragma unroll
      for (int j = 0; j < 4; j++) cv[j] = *(const float4*)&Cs[tq * 4 + j][n4];
#pragma unroll
      for (int j = 0; j < 4; j++) bv[j] = *(const float4*)&Bs[sq * 4 + j][n4];
#pragma unroll
      for (int j = 0; j < 4; j++)
#pragma unroll
        for (int jj = 0; jj < 4; jj++)
          gacc[j][jj] += cv[j].x * bv[jj].x + cv[j].y * bv[jj].y + cv[j].z * bv[jj].z + cv[j].w * bv[jj].w;
    }
#pragma unroll
    for (int j = 0; j < 4; j++)
#pragma unroll
      for (int jj = 0; jj < 4; jj++) {
        int t = tq * 4 + j, s = sq * 4 + jj;
        float arg = fminf(a_s[t] - a_s[s], 0.f);
        Gs[t][s] = (s <= t) ? gacc[j][jj] * __expf(arg) * dt_sh[s] : 0.f;
      }
  }
  __syncthreads();
  {
    int tq = tid >> 4, pq = tid & 15;
    float4 acc[4];
#pragma unroll
    for (int j = 0; j < 4; j++) acc[j] = float4{0.f, 0.f, 0.f, 0.f};
    for (int s = 0; s < 64; s++) {
      float4 xv = *(const float4*)&Xs[s][pq * 4];
#pragma unroll
      for (int j = 0; j < 4; j++) {
        float g = Gs[tq * 4 + j][s];
        acc[j].x += g * xv.x; acc[j].y += g * xv.y; acc[j].z += g * xv.z; acc[j].w += g * xv.w;
      }
    }
#pragma unroll
    for (int j = 0; j < 4; j++) {
      int t = tq * 4 + j;
      *(float4*)&y[(size_t)(t0 + t) * D_INNER + h * P_HEAD + pq * 4] = acc[j];
    }
  }
  {
    int p2 = tid >> 5, n4 = (tid & 31) * 4;
    float4 acc[8];
#pragma unroll
    for (int j = 0; j < 8; j++) acc[j] = float4{0.f, 0.f, 0.f, 0.f};
    for (int s = 0; s < 64; s++) {
      float4 bv = *(const float4*)&Bs[s][n4];
#pragma unroll
      for (int j = 0; j < 8; j++) {
        float xw = Xs[s][p2 * 8 + j] * w_sh[s];
        acc[j].x += xw * bv.x; acc[j].y += xw * bv.y; acc[j].z += xw * bv.z; acc[j].w += xw * bv.w;
      }
    }
    size_t bb = ((size_t)(c * HEADS + h) * 64) * 128;
#pragma unroll
    for (int j = 0; j < 8; j++)
      *(float4*)&S[bb + (size_t)(p2 * 8 + j) * 128 + n4] = acc[j];
  }
}

// ---------------- scan: inter-chunk state recurrence ----------------
__global__ void k_scan_state(float* __restrict__ S, const float* __restrict__ Atot) {
  int gid = blockIdx.x * 256 + threadIdx.x;
  int h = gid >> 13;
  int rem = gid & 8191;
  float run = 0.f;
#pragma unroll
  for (int c = 0; c < NCHUNK; c++) {
    size_t idx = ((size_t)(c * HEADS + h) << 13) + rem;
    float s = S[idx];
    S[idx] = run;
    run = run * __expf(Atot[c * HEADS + h]) + s;
  }
}

// ---------------- scan: inter-chunk contribution + D*x ----------------
__global__ __launch_bounds__(256) void k_scan_inter(
    const float* __restrict__ xBC, const float* __restrict__ Hin,
    const float* __restrict__ cumA, const float* __restrict__ Dv,
    float* __restrict__ y) {
  __shared__ float Hs[64][132];
  __shared__ float Cs[64][132];
  __shared__ float a_l[64];
  int c = blockIdx.x, h = blockIdx.y, tid = threadIdx.x;
  int t0 = c * QCHUNK;
#pragma unroll
  for (int i = 0; i < 8; i++) {
    int id = tid + 256 * i;
    int r = id >> 5, n4 = (id & 31) * 4;
    *(float4*)&Hs[r][n4] = *(const float4*)&Hin[(((size_t)(c * HEADS + h) * 64 + r) << 7) + n4];
    *(float4*)&Cs[r][n4] = *(const float4*)&xBC[(size_t)(t0 + r) * CONV_DIM + D_INNER + N_STATE + n4];
  }
  if (tid < 64) a_l[tid] = cumA[((size_t)c * HEADS + h) * 64 + tid];
  __syncthreads();
  float Dh = Dv[h];
  int tq = tid >> 4, pq = tid & 15;
  float4 acc[4];
#pragma unroll
  for (int j = 0; j < 4; j++) acc[j] = float4{0.f, 0.f, 0.f, 0.f};
  for (int n4 = 0; n4 < 128; n4 += 4) {
    float4 hv[4], cv[4];
#pragma unroll
    for (int jj = 0; jj < 4; jj++) hv[jj] = *(const float4*)&Hs[pq * 4 + jj][n4];
#pragma unroll
    for (int j = 0; j < 4; j++) cv[j] = *(const float4*)&Cs[tq * 4 + j][n4];
#pragma unroll
    for (int j = 0; j < 4; j++) {
      acc[j].x += cv[j].x * hv[0].x + cv[j].y * hv[0].y + cv[j].z * hv[0].z + cv[j].w * hv[0].w;
      acc[j].y += cv[j].x * hv[1].x + cv[j].y * hv[1].y + cv[j].z * hv[1].z + cv[j].w * hv[1].w;
      acc[j].z += cv[j].x * hv[2].x + cv[j].y * hv[2].y + cv[j].z * hv[2].z + cv[j].w * hv[2].w;
      acc[j].w += cv[j].x * hv[3].x + cv[j].y * hv[3].y + cv[j].z * hv[3].z + cv[j].w * hv[3].w;
    }
  }
#pragma unroll
  for (int j = 0; j < 4; j++) {
    int t = tq * 4 + j;
    float e = __expf(a_l[t]);
    float4 xv = *(const float4*)&xBC[(size_t)(t0 + t) * CONV_DIM + h * P_HEAD + pq * 4];
    size_t yoff = (size_t)(t0 + t) * D_INNER + h * P_HEAD + pq * 4;
    float4 yv = *(float4*)&y[yoff];
    yv.x += e * acc[j].x + Dh * xv.x;
    yv.y += e * acc[j].y + Dh * xv.y;
    yv.z += e * acc[j].z + Dh * xv.z;
    yv.w += e * acc[j].w + Dh * xv.w;
    *(float4*)&y[yoff] = yv;
  }
}

// ---------------- gated RMSNorm -> swizzled bf16 planes ----------------
__global__ __launch_bounds__(256) void k_gatednorm_p(const float* __restrict__ y,
                                                     const float* __restrict__ zx,
                                                     const float* __restrict__ w,
                                                     __bf16* __restrict__ ph,
                                                     __bf16* __restrict__ pl) {
  __shared__ float vbuf[D_INNER];
  __shared__ float red[4];
  int t = blockIdx.x, tid = threadIdx.x;
  float ss = 0.f;
  for (int i = tid; i < D_INNER / 4; i += 256) {
    float4 yv = *(const float4*)&y[(size_t)t * D_INNER + i * 4];
    float4 zv = *(const float4*)&zx[(size_t)t * D_INPROJ + i * 4];
    float4 v;
    v.x = yv.x * siluf(zv.x); v.y = yv.y * siluf(zv.y);
    v.z = yv.z * siluf(zv.z); v.w = yv.w * siluf(zv.w);
    *(float4*)&vbuf[i * 4] = v;
    ss += v.x * v.x + v.y * v.y + v.z * v.z + v.w * v.w;
  }
  float tot = block_sum256(ss, red);
  float r = rsqrtf(tot / (float)D_INNER + 1e-6f);
  int P = (t >> 1) & 3;
  for (int i = tid; i < D_INNER / 4; i += 256) {
    float4 v = *(const float4*)&vbuf[i * 4];
    float4 wv = *(const float4*)&w[i * 4];
    float4 o;
    o.x = wv.x * v.x * r; o.y = wv.y * v.y * r; o.z = wv.z * v.z * r; o.w = wv.w * v.w * r;
    int p = swz_p(i * 4, P);
    bf16x4 hv;
    hv[0] = (__bf16)o.x; hv[1] = (__bf16)o.y; hv[2] = (__bf16)o.z; hv[3] = (__bf16)o.w;
    *(bf16x4*)&ph[(size_t)t * D_INNER + p] = hv;
    bf16x4 lv;
    lv[0] = (__bf16)(o.x - (float)hv[0]); lv[1] = (__bf16)(o.y - (float)hv[1]);
    lv[2] = (__bf16)(o.z - (float)hv[2]); lv[3] = (__bf16)(o.w - (float)hv[3]);
    *(bf16x4*)&pl[(size_t)t * D_INNER + p] = lv;
  }
}

// ---------------- router ----------------
__global__ void k_zero(int* counts, int* cursor) {
  int i = threadIdx.x;
  if (i < NEXP) { counts[i] = 0; cursor[i] = 0; }
}

__global__ __launch_bounds__(256) void k_router(const float* __restrict__ xm,
                                                const float* __restrict__ Wr,
                                                int* __restrict__ top_i,
                                                float* __restrict__ top_v,
                                                int* __restrict__ counts) {
  __shared__ float part[16][17];
  __shared__ float lg[16];
  int t = blockIdx.x, tid = threadIdx.x;
  int e = tid & 15, seg = tid >> 4;
  const float* xr = xm + (size_t)t * D_MODEL;
  float s = 0.f;
  for (int i = 0; i < 160; i++) {
    int k = seg * 160 + i;
    s += xr[k] * Wr[(size_t)k * NEXP + e];
  }
  part[seg][e] = s;
  __syncthreads();
  if (tid < 16) {
    float l = 0.f;
    for (int g = 0; g < 16; g++) l += part[g][tid];
    lg[tid] = l;
  }
  __syncthreads();
  if (tid == 0) {
    float mx = lg[0];
    for (int i = 1; i < 16; i++) mx = fmaxf(mx, lg[i]);
    float pe[16];
    for (int i = 0; i < 16; i++) pe[i] = expf(lg[i] - mx);
    int i0 = 0; float v0 = pe[0];
    for (int i = 1; i < 16; i++) if (pe[i] > v0) { v0 = pe[i]; i0 = i; }
    int i1 = -1; float v1 = -1.f;
    for (int i = 0; i < 16; i++) if (i != i0 && pe[i] > v1) { v1 = pe[i]; i1 = i; }
    float inv = 1.f / (v0 + v1);
    top_i[t * 2] = i0; top_i[t * 2 + 1] = i1;
    top_v[t * 2] = v0 * inv; top_v[t * 2 + 1] = v1 * inv;
    atomicAdd(&counts[i0], 1);
    atomicAdd(&counts[i1], 1);
  }
}

__global__ void k_offsets(const int* counts, int* offs, int* cursor) {
  if (threadIdx.x == 0) {
    int s = 0;
    for (int e = 0; e < NEXP; e++) { offs[e] = s; cursor[e] = s; s += counts[e]; }
  }
}

__global__ void k_scatter(const int* __restrict__ top_i, const float* __restrict__ top_v,
                          int* __restrict__ cursor, int* __restrict__ perm,
                          int* __restrict__ slotOf, float* __restrict__ slotw) {
  int t = blockIdx.x * 256 + threadIdx.x;
  if (t < SEQ) {
    for (int k = 0; k < 2; k++) {
      int e = top_i[t * 2 + k];
      int pos = atomicAdd(&cursor[e], 1);
      perm[pos] = t;
      slotOf[t * 2 + k] = pos;
      slotw[pos] = top_v[t * 2 + k];
    }
  }
}

// ---------------- final combine (3 down-partial planes) ----------------
__global__ void k_final2(const float* __restrict__ hidden, const float* __restrict__ sh,
                         const float* __restrict__ dsP, const int* __restrict__ slotOf,
                         float* __restrict__ out) {
  int t = blockIdx.y;
  int d4 = (blockIdx.x * 256 + threadIdx.x) * 4;
  if (d4 < D_MODEL) {
    int s0 = slotOf[t * 2], s1 = slotOf[t * 2 + 1];
    f32x4 a = *(const f32x4*)&hidden[(size_t)t * D_MODEL + d4];
    f32x4 b = *(const f32x4*)&sh[(size_t)t * D_MODEL + d4];
    f32x4 acc = a + b;
    const size_t PL = (size_t)NSLOTP * D_MODEL;
#pragma unroll
    for (int z = 0; z < 3; z++) {
      acc += *(const f32x4*)&dsP[z * PL + (size_t)s0 * D_MODEL + d4];
      acc += *(const f32x4*)&dsP[z * PL + (size_t)s1 * D_MODEL + d4];
    }
    *(f32x4*)&out[(size_t)t * D_MODEL + d4] = acc;
  }
}

// ---------------- launch ----------------
extern "C" void kernel_launch(void* const* d_in, const int* in_sizes, int n_in,
                              void* d_out, int out_size, void* d_ws, size_t ws_size,
                              hipStream_t stream) {
  const float* hs = (const float*)d_in[0];
  const float* w_in = (const float*)d_in[1];
  const float* conv_w = (const float*)d_in[2];
  const float* conv_b = (const float*)d_in[3];
  const float* dt_bias = (const float*)d_in[4];
  const float* A_log = (const float*)d_in[5];
  const float* Dv = (const float*)d_in[6];
  const float* mnw = (const float*)d_in[7];
  const float* w_out = (const float*)d_in[8];
  const float* ln1 = (const float*)d_in[9];
  const float* ln2 = (const float*)d_in[10];
  const float* router_w = (const float*)d_in[11];
  const float* we_gate = (const float*)d_in[12];
  const float* we_up = (const float*)d_in[13];
  const float* we_down = (const float*)d_in[14];
  const float* ws_gate = (const float*)d_in[15];
  const float* ws_up = (const float*)d_in[16];
  const float* ws_down = (const float*)d_in[17];

  char* base = (char*)d_ws;
  size_t off = 0;
  auto A = [&](size_t bytes) -> void* {
    void* p = base + off;
    off += (bytes + 255) & ~(size_t)255;
    return p;
  };
  float* zx = (float*)A((size_t)SEQ * D_INPROJ * 4);
  float* xbc = (float*)A((size_t)SEQ * CONV_DIM * 4);
  float* xmf = (float*)A((size_t)SEQ * D_MODEL * 4);
  float* dtp = (float*)A((size_t)SEQ * HEADS * 4);
  float* dtA = (float*)A((size_t)SEQ * HEADS * 4);
  float* yf = (float*)A((size_t)SEQ * D_INNER * 4);
  float* cumA = (float*)A((size_t)NCHUNK * HEADS * 64 * 4);
  float* Atot = (float*)A((size_t)NCHUNK * HEADS * 4);
  float* Sbuf = (float*)A((size_t)NCHUNK * HEADS * 64 * 128 * 4);
  float* hidden = (float*)A((size_t)SEQ * D_MODEL * 4);
  float* shout = (float*)A((size_t)SEQ * D_MODEL * 4);
  float* top_v = (float*)A(8192);
  float* slotw = (float*)A(8192);
  int* top_i = (int*)A(8192);
  int* counts = (int*)A(64);
  int* offs = (int*)A(64);
  int* cursor = (int*)A(64);
  int* perm = (int*)A(8192);
  int* slotOf = (int*)A(8192);
  __bf16* xp_h = (__bf16*)A((size_t)SEQ * D_MODEL * 2);
  __bf16* xp_l = (__bf16*)A((size_t)SEQ * D_MODEL * 2);
  __bf16* ybp_h = (__bf16*)A((size_t)SEQ * D_INNER * 2);
  __bf16* ybp_l = (__bf16*)A((size_t)SEQ * D_INNER * 2);
  __bf16* gbuf_bh = (__bf16*)A((size_t)SEQ * MS_INTER * 2);
  char* REG = (char*)A((size_t)146000000);

  // Phase M aliases
  __bf16* winT_h = (__bf16*)REG;                       // [10624][2560]
  __bf16* winT_l = (__bf16*)(REG + 54394880);
  __bf16* woutT_h = (__bf16*)REG;                      // [2560][5120]
  __bf16* woutT_l = (__bf16*)(REG + 26214400);
  float* partials = (float*)(REG + 60000000);          // 4x1024x2560 f32
  // Phase S aliases
  __bf16* guT = (__bf16*)REG;                          // [3456][2560] (gate | up)
  __bf16* downT = (__bf16*)(REG + 18350080);           // [2560][1728]
  float* partials4 = (float*)(REG + 30000000);         // 4x[1024][3456] f32 (56.6 MB)
  // Phase R aliases
  __bf16* Aslots = (__bf16*)REG;                       // [2176][2560]
  __bf16* gsl = (__bf16*)(REG + 12000000);             // [2176][864]
  float* gateP = (float*)(REG + 16000000);             // 4x[2176][864]
  float* upP = (float*)(REG + 47000000);
  float* dslotsP = (float*)(REG + 78000000);           // 3x[2176][2560]

  // ---- Mamba sub-block ----
  k_rmsnorm_p<<<SEQ, 256, 0, stream>>>(hs, ln1, nullptr, xp_h, xp_l, D_MODEL);
  k_transW<true><<<dim3(166, 40), 256, 0, stream>>>(w_in, D_MODEL, D_INPROJ, winT_h, winT_l);
  k_gemm2<true><<<dim3(8, 83, 1), 256, 0, stream>>>(xp_h, xp_l, winT_h, winT_l, zx,
                                                    SEQ, D_INPROJ, D_MODEL, 1, 80);
  k_dt<<<SEQ, 128, 0, stream>>>(zx, dt_bias, A_log, dtp, dtA);
  k_conv<<<dim3(21, SEQ), 256, 0, stream>>>(zx, conv_w, conv_b, xbc);
  k_scan_intra<<<dim3(NCHUNK, HEADS), 256, 0, stream>>>(xbc, dtp, dtA, yf, Sbuf, cumA, Atot);
  k_scan_state<<<2560, 256, 0, stream>>>(Sbuf, Atot);
  k_scan_inter<<<dim3(NCHUNK, HEADS), 256, 0, stream>>>(xbc, Sbuf, cumA, Dv, yf);
  k_gatednorm_p<<<SEQ, 256, 0, stream>>>(yf, zx, mnw, ybp_h, ybp_l);
  k_transW<true><<<dim3(40, 80), 256, 0, stream>>>(w_out, D_INNER, D_MODEL, woutT_h, woutT_l);
  k_gemm2<true><<<dim3(8, 20, 4), 256, 0, stream>>>(ybp_h, ybp_l, woutT_h, woutT_l, partials,
                                                    SEQ, D_MODEL, D_INNER, 4, 160);
  k_reduce<true><<<2048, 256, 0, stream>>>(partials, 4, SEQ * D_MODEL / 4, hs, hidden);

  // ---- MoE sub-block ----
  k_rmsnorm_p<<<SEQ, 256, 0, stream>>>(hidden, ln2, xmf, xp_h, nullptr, D_MODEL);
  k_zero<<<1, 64, 0, stream>>>(counts, cursor);
  k_router<<<SEQ, 256, 0, stream>>>(xmf, router_w, top_i, top_v, counts);
  k_offsets<<<1, 32, 0, stream>>>(counts, offs, cursor);
  k_scatter<<<4, 256, 0, stream>>>(top_i, top_v, cursor, perm, slotOf, slotw);

  // shared experts: combined gate|up GEMM (N=3456), fused reduce+silu
  k_transW<false><<<dim3(27, 40), 256, 0, stream>>>(ws_gate, D_MODEL, MS_INTER, guT, nullptr);
  k_transW<false><<<dim3(27, 40), 256, 0, stream>>>(ws_up, D_MODEL, MS_INTER,
                                                    guT + (size_t)MS_INTER * D_MODEL, nullptr);
  k_gemm2<false><<<dim3(8, 27, 4), 256, 0, stream>>>(xp_h, nullptr, guT, nullptr, partials4,
                                                     SEQ, 3456, D_MODEL, 4, 80);
  k_silumul_sh2<<<SEQ, 256, 0, stream>>>(partials4, gbuf_bh);
  k_transW<false><<<dim3(40, 27), 256, 0, stream>>>(ws_down, MS_INTER, D_MODEL, downT, nullptr);
  k_gemm2<false><<<dim3(8, 20, 4), 256, 0, stream>>>(gbuf_bh, nullptr, downT, nullptr, partials4,
                                                     SEQ, D_MODEL, MS_INTER, 4, 54);
  k_reduce<false><<<2048, 256, 0, stream>>>(partials4, 4, SEQ * D_MODEL / 4, nullptr, shout);

  // routed experts
  k_gatherA<<<NSLOT, 256, 0, stream>>>(xmf, perm, Aslots);
  k_gemmE2<4><<<dim3(7, 4, NEXP), 256, 0, stream>>>(Aslots, we_gate, gateP, offs, counts,
                                                    M_INTER, D_MODEL, (long long)D_MODEL * M_INTER);
  k_gemmE2<4><<<dim3(7, 4, NEXP), 256, 0, stream>>>(Aslots, we_up, upP, offs, counts,
                                                    M_INTER, D_MODEL, (long long)D_MODEL * M_INTER);
  k_silumulE<<<NSLOT, 256, 0, stream>>>(gateP, upP, slotw, gsl);
  k_gemmE2<3><<<dim3(20, 3, NEXP), 256, 0, stream>>>(gsl, we_down, dslotsP, offs, counts,
                                                     D_MODEL, M_INTER, (long long)M_INTER * D_MODEL);

  k_final2<<<dim3(3, SEQ), 256, 0, stream>>>(hidden, shout, dslotsP, slotOf, (float*)d_out);
}

// Round 6
// 934.232 us; speedup vs baseline: 2.8939x; 1.0463x over previous
//
#include <hip/hip_runtime.h>

// ---------------- types ----------------
typedef __attribute__((ext_vector_type(4))) float f32x4;
typedef __attribute__((ext_vector_type(8))) __bf16 bf16x8;
typedef __attribute__((ext_vector_type(4))) __bf16 bf16x4;

#define D_MODEL 2560
#define D_INNER 5120
#define N_STATE 128
#define HEADS 80
#define P_HEAD 64
#define CONV_DIM 5376
#define D_INPROJ 10576
#define SEQ 1024
#define NCHUNK 16
#define QCHUNK 64
#define NEXP 16
#define M_INTER 864
#define MS_INTER 1728
#define NSLOT 2048
#define NSLOTP 2176   // padded slot rows

__device__ __forceinline__ float siluf(float x) { return x / (1.f + __expf(-x)); }

// swizzled chunk position: within each 32-elem K-group, 16B chunk c stored at c ^ P
__device__ __forceinline__ int swz_p(int k4, int P) {
  return (k4 & ~31) | ((((k4 >> 3) & 3) ^ P) << 3) | (k4 & 7);
}

__device__ __forceinline__ void gl16(const __bf16* g, __bf16* l) {
  __builtin_amdgcn_global_load_lds((const __attribute__((address_space(1))) unsigned int*)g,
                                   (__attribute__((address_space(3))) unsigned int*)l, 16, 0, 0);
}

__device__ __forceinline__ float block_sum256(float v, float* red) {
#pragma unroll
  for (int m = 32; m > 0; m >>= 1) v += __shfl_xor(v, m, 64);
  int w = threadIdx.x >> 6;
  if ((threadIdx.x & 63) == 0) red[w] = v;
  __syncthreads();
  return red[0] + red[1] + red[2] + red[3];
}

// ---------------- RMSNorm -> f32 (optional) + swizzled bf16 planes ----------------
__global__ __launch_bounds__(256) void k_rmsnorm_p(const float* __restrict__ in,
                                                   const float* __restrict__ w,
                                                   float* __restrict__ f32out,
                                                   __bf16* __restrict__ ph,
                                                   __bf16* __restrict__ pl, int D) {
  __shared__ float red[4];
  int t = blockIdx.x, tid = threadIdx.x;
  const float* x = in + (size_t)t * D;
  int nd4 = D >> 2;
  float ss = 0.f;
  for (int i = tid; i < nd4; i += 256) {
    float4 v = ((const float4*)x)[i];
    ss += v.x * v.x + v.y * v.y + v.z * v.z + v.w * v.w;
  }
  float tot = block_sum256(ss, red);
  float r = rsqrtf(tot / (float)D + 1e-6f);
  int P = (t >> 1) & 3;
  for (int i = tid; i < nd4; i += 256) {
    float4 v = ((const float4*)x)[i];
    float4 wv = ((const float4*)w)[i];
    float4 o;
    o.x = wv.x * v.x * r; o.y = wv.y * v.y * r; o.z = wv.z * v.z * r; o.w = wv.w * v.w * r;
    if (f32out) ((float4*)(f32out + (size_t)t * D))[i] = o;
    int p = swz_p(i * 4, P);
    bf16x4 hv;
    hv[0] = (__bf16)o.x; hv[1] = (__bf16)o.y; hv[2] = (__bf16)o.z; hv[3] = (__bf16)o.w;
    *(bf16x4*)&ph[(size_t)t * D + p] = hv;
    if (pl) {
      bf16x4 lv;
      lv[0] = (__bf16)(o.x - (float)hv[0]); lv[1] = (__bf16)(o.y - (float)hv[1]);
      lv[2] = (__bf16)(o.z - (float)hv[2]); lv[3] = (__bf16)(o.w - (float)hv[3]);
      *(bf16x4*)&pl[(size_t)t * D + p] = lv;
    }
  }
}

// ---------------- weight transpose+convert: f32 [K][N] -> bf16 [Npad][K] (swizzled) ----------------
template <bool SPLIT>
__global__ __launch_bounds__(256) void k_transW(const float* __restrict__ W, int K, int N,
                                                __bf16* __restrict__ Th, __bf16* __restrict__ Tl) {
  __shared__ float T[64][65];
  const int n0 = blockIdx.x * 64, k0 = blockIdx.y * 64, tid = threadIdx.x;
#pragma unroll
  for (int i = 0; i < 16; i++) {
    int idx = tid + i * 256;
    int k = idx >> 6, n = idx & 63;
    float v = 0.f;
    if (n0 + n < N) v = W[(size_t)(k0 + k) * N + n0 + n];
    T[k][n] = v;
  }
  __syncthreads();
#pragma unroll
  for (int i = 0; i < 4; i++) {
    int idx = tid + i * 256;
    int n = idx >> 4, p4 = (idx & 15) * 4;
    int nn = n0 + n;
    int P = (nn >> 1) & 3;
    bf16x4 hv, lv;
#pragma unroll
    for (int e = 0; e < 4; e++) {
      int p = p4 + e;
      int kk = (p & ~31) | ((((p >> 3) & 3) ^ P) << 3) | (p & 7);
      float v = T[kk][n];
      __bf16 h = (__bf16)v;
      hv[e] = h;
      if constexpr (SPLIT) lv[e] = (__bf16)(v - (float)h);
    }
    *(bf16x4*)&Th[(size_t)nn * K + k0 + p4] = hv;
    if constexpr (SPLIT) *(bf16x4*)&Tl[(size_t)nn * K + k0 + p4] = lv;
  }
}

// ---------------- m97-style bf16 MFMA GEMM, single-buffer, XCD-grouped remap ----------------
// logical grid: (bm=8, bn, z) — all launches have gridDim.x == 8, total % 8 == 0.
// remap puts the 8 blocks sharing one B panel on the SAME XCD (L2 reuse).
template <bool SPLIT>
__global__ __launch_bounds__(256) void k_gemm2(const __bf16* __restrict__ Ah,
                                               const __bf16* __restrict__ Al,
                                               const __bf16* __restrict__ Bh,
                                               const __bf16* __restrict__ Bl,
                                               float* __restrict__ C,
                                               int M, int N, int K, int ks, int nst) {
  constexpr int NP = SPLIT ? 4 : 2;
  __shared__ __bf16 lds[NP * 4096];
  __bf16* const AsH = lds;
  __bf16* const BsH = lds + (SPLIT ? 2 : 1) * 4096;
  __bf16* const AsL = SPLIT ? (lds + 4096) : nullptr;
  __bf16* const BsL = SPLIT ? (lds + 3 * 4096) : nullptr;

  const int tid = threadIdx.x;
  // ---- XCD-grouped remap (bijective; hw xcd = linear % 8) ----
  const int T = gridDim.x * gridDim.y * gridDim.z;
  const int linear = blockIdx.x + gridDim.x * (blockIdx.y + gridDim.y * blockIdx.z);
  const int s_idx = (linear & 7) * (T >> 3) + (linear >> 3);
  const int bm = s_idx & 7;
  const int g = s_idx >> 3;
  const int bn = g % gridDim.y;
  const int z = g / gridDim.y;

  const int m0 = bm * 128, n0 = bn * 128;
  const int s0 = (int)(((long long)z * nst) / ks);
  const int s1 = (int)(((long long)(z + 1) * nst) / ks);
  float* __restrict__ Cp = C + (size_t)z * M * N;

  const int lane = tid & 63, wid = tid >> 6;
  const int wr = wid >> 1, wc = wid & 1;
  const int l16 = lane & 15, kl = lane >> 4;

  const int srow = tid >> 2;
  const int schunk = (tid & 3) * 8;
  const size_t aB0 = (size_t)(m0 + srow) * K + schunk;
  const size_t aB1 = aB0 + (size_t)64 * K;
  const size_t bB0 = (size_t)(n0 + srow) * K + schunk;
  const size_t bB1 = bB0 + (size_t)64 * K;
  __bf16* const lA0 = AsH + tid * 8;
  __bf16* const lA1 = AsH + (tid + 256) * 8;
  __bf16* const lB0 = BsH + tid * 8;
  __bf16* const lB1 = BsH + (tid + 256) * 8;

  int aoff[4], boff[4];
#pragma unroll
  for (int mi = 0; mi < 4; mi++) {
    int r = wr * 64 + mi * 16 + l16;
    aoff[mi] = r * 64 + ((kl ^ ((r >> 1) & 3)) << 4);   // bytes within plane
  }
#pragma unroll
  for (int ni = 0; ni < 4; ni++) {
    int r = wc * 64 + ni * 16 + l16;
    boff[ni] = r * 64 + ((kl ^ ((r >> 1) & 3)) << 4);
  }

  f32x4 acc[4][4];
#pragma unroll
  for (int mi = 0; mi < 4; mi++)
#pragma unroll
    for (int ni = 0; ni < 4; ni++) acc[mi][ni] = f32x4{0.f, 0.f, 0.f, 0.f};

  for (int s = s0; s < s1; ++s) {
    const int k0 = s << 5;
    __syncthreads();
    gl16(Ah + aB0 + k0, lA0);
    gl16(Ah + aB1 + k0, lA1);
    gl16(Bh + bB0 + k0, lB0);
    gl16(Bh + bB1 + k0, lB1);
    if constexpr (SPLIT) {
      gl16(Al + aB0 + k0, AsL + tid * 8);
      gl16(Al + aB1 + k0, AsL + (tid + 256) * 8);
      gl16(Bl + bB0 + k0, BsL + tid * 8);
      gl16(Bl + bB1 + k0, BsL + (tid + 256) * 8);
    }
    __syncthreads();
    bf16x8 ah[4], bh[4];
#pragma unroll
    for (int mi = 0; mi < 4; mi++) ah[mi] = *(const bf16x8*)((const char*)AsH + aoff[mi]);
#pragma unroll
    for (int ni = 0; ni < 4; ni++) bh[ni] = *(const bf16x8*)((const char*)BsH + boff[ni]);
#pragma unroll
    for (int mi = 0; mi < 4; mi++)
#pragma unroll
      for (int ni = 0; ni < 4; ni++)
        acc[mi][ni] = __builtin_amdgcn_mfma_f32_16x16x32_bf16(ah[mi], bh[ni], acc[mi][ni], 0, 0, 0);
    if constexpr (SPLIT) {
      bf16x8 al[4], bl[4];
#pragma unroll
      for (int mi = 0; mi < 4; mi++) al[mi] = *(const bf16x8*)((const char*)AsL + aoff[mi]);
#pragma unroll
      for (int ni = 0; ni < 4; ni++) bl[ni] = *(const bf16x8*)((const char*)BsL + boff[ni]);
#pragma unroll
      for (int mi = 0; mi < 4; mi++)
#pragma unroll
        for (int ni = 0; ni < 4; ni++) {
          acc[mi][ni] = __builtin_amdgcn_mfma_f32_16x16x32_bf16(ah[mi], bl[ni], acc[mi][ni], 0, 0, 0);
          acc[mi][ni] = __builtin_amdgcn_mfma_f32_16x16x32_bf16(al[mi], bh[ni], acc[mi][ni], 0, 0, 0);
        }
    }
  }
#pragma unroll
  for (int mi = 0; mi < 4; mi++)
#pragma unroll
    for (int ni = 0; ni < 4; ni++)
#pragma unroll
      for (int r = 0; r < 4; r++) {
        int row = m0 + wr * 64 + mi * 16 + kl * 4 + r;
        int col = n0 + wc * 64 + ni * 16 + l16;
        if (col < N) Cp[(size_t)row * N + col] = acc[mi][ni][r];
      }
}

// ---------------- partial reduce (+ optional residual) ----------------
template <bool RES>
__global__ void k_reduce(const float* __restrict__ Pp, int np, int n4,
                         const float* __restrict__ res, float* __restrict__ out) {
  int i = blockIdx.x * 256 + threadIdx.x;
  int stride = gridDim.x * 256;
  for (; i < n4; i += stride) {
    float4 a = ((const float4*)Pp)[i];
    for (int z = 1; z < np; z++) {
      float4 b = ((const float4*)Pp)[(size_t)z * n4 + i];
      a.x += b.x; a.y += b.y; a.z += b.z; a.w += b.w;
    }
    if constexpr (RES) {
      float4 r0 = ((const float4*)res)[i];
      a.x += r0.x; a.y += r0.y; a.z += r0.z; a.w += r0.w;
    }
    ((float4*)out)[i] = a;
  }
}

// ---------------- gather slot activations -> swizzled bf16 ----------------
__global__ __launch_bounds__(256) void k_gatherA(const float* __restrict__ xm,
                                                 const int* __restrict__ perm,
                                                 __bf16* __restrict__ Aslots) {
  int s = blockIdx.x, tid = threadIdx.x;
  int t = perm[s];
  int P = (s >> 1) & 3;
  const float* src = xm + (size_t)t * D_MODEL;
  __bf16* dst = Aslots + (size_t)s * D_MODEL;
  for (int i = tid; i < D_MODEL / 4; i += 256) {
    float4 v = ((const float4*)src)[i];
    int p = swz_p(i * 4, P);
    bf16x4 h;
    h[0] = (__bf16)v.x; h[1] = (__bf16)v.y; h[2] = (__bf16)v.z; h[3] = (__bf16)v.w;
    *(bf16x4*)&dst[p] = h;
  }
}

// ---------------- routed expert GEMM: A bf16 slots (swizzled), B f32 [K][N], split-K ----------------
template <int KS>
__global__ __launch_bounds__(256) void k_gemmE2(const __bf16* __restrict__ Aall,
                                                const float* __restrict__ Bg,
                                                float* __restrict__ Cp,
                                                const int* __restrict__ expOff,
                                                const int* __restrict__ expCnt,
                                                int N, int K, long long strideB) {
  __shared__ __bf16 Asl[2][128 * 32];
  __shared__ __bf16 Bsl[2][128][40];
  const int tid = threadIdx.x;
  const int bn = blockIdx.x, ks = blockIdx.y, e = blockIdx.z;
  const int cnt = expCnt[e], base = expOff[e];
  if (cnt == 0) return;
  const float* Bp = Bg + (long long)e * strideB;
  const int n0 = bn * 128;
  const int kChunk = K / KS, kBeg = ks * kChunk, nIter = kChunk / 32;
  float* __restrict__ Cpl = Cp + (size_t)ks * NSLOTP * N;
  const int lane = tid & 63, wid = tid >> 6;
  const int wr = wid >> 1, wc = wid & 1;
  const int l16 = lane & 15, kl = lane >> 4;
  const int kb = tid >> 5, cb = tid & 31;
  const int arow = tid >> 2, achk = (tid & 3) * 8;
  const bool bok = (n0 + cb * 4) < N;

  int boffs[4];
#pragma unroll
  for (int ni = 0; ni < 4; ni++) boffs[ni] = (wc * 64 + ni * 16 + l16) * 40 + kl * 8;

  for (int bm = 0; bm * 128 < cnt; ++bm) {
    const int rbase = base + bm * 128;
    int aoff[4];
#pragma unroll
    for (int mi = 0; mi < 4; mi++) {
      int r = wr * 64 + mi * 16 + l16;
      int P = ((rbase + r) >> 1) & 3;
      aoff[mi] = r * 64 + ((kl ^ P) << 4);
    }
    f32x4 acc[4][4];
#pragma unroll
    for (int mi = 0; mi < 4; mi++)
#pragma unroll
      for (int ni = 0; ni < 4; ni++) acc[mi][ni] = f32x4{0.f, 0.f, 0.f, 0.f};

    const size_t aBase = (size_t)(rbase + arow) * K + achk + kBeg;
    const size_t aBase2 = aBase + (size_t)64 * K;

    gl16(Aall + aBase, &Asl[0][tid * 8]);
    gl16(Aall + aBase2, &Asl[0][(tid + 256) * 8]);
    {
      const float* src = Bp + (size_t)(kBeg + kb * 4) * N + n0 + cb * 4;
      f32x4 bv[4];
#pragma unroll
      for (int j = 0; j < 4; j++)
        bv[j] = bok ? *(const f32x4*)(src + (size_t)j * N) : f32x4{0.f, 0.f, 0.f, 0.f};
#pragma unroll
      for (int e4 = 0; e4 < 4; e4++) {
        bf16x4 h;
        h[0] = (__bf16)bv[0][e4]; h[1] = (__bf16)bv[1][e4];
        h[2] = (__bf16)bv[2][e4]; h[3] = (__bf16)bv[3][e4];
        *(bf16x4*)&Bsl[0][cb * 4 + e4][kb * 4] = h;
      }
    }
    __syncthreads();
    int cur = 0;
    for (int kt = 0; kt < nIter; ++kt) {
      const bool more = (kt + 1 < nIter);
      f32x4 nv[4];
      if (more) {
        const int kOff = (kt + 1) * 32;
        gl16(Aall + aBase + kOff, &Asl[cur ^ 1][tid * 8]);
        gl16(Aall + aBase2 + kOff, &Asl[cur ^ 1][(tid + 256) * 8]);
        const float* src = Bp + (size_t)(kBeg + kOff + kb * 4) * N + n0 + cb * 4;
#pragma unroll
        for (int j = 0; j < 4; j++)
          nv[j] = bok ? *(const f32x4*)(src + (size_t)j * N) : f32x4{0.f, 0.f, 0.f, 0.f};
      }
      bf16x8 ah[4], bh[4];
#pragma unroll
      for (int mi = 0; mi < 4; mi++) ah[mi] = *(const bf16x8*)((const char*)&Asl[cur][0] + aoff[mi]);
#pragma unroll
      for (int ni = 0; ni < 4; ni++) bh[ni] = *(const bf16x8*)&Bsl[cur][0][boffs[ni]];
#pragma unroll
      for (int mi = 0; mi < 4; mi++)
#pragma unroll
        for (int ni = 0; ni < 4; ni++)
          acc[mi][ni] = __builtin_amdgcn_mfma_f32_16x16x32_bf16(ah[mi], bh[ni], acc[mi][ni], 0, 0, 0);
      if (more) {
#pragma unroll
        for (int e4 = 0; e4 < 4; e4++) {
          bf16x4 h;
          h[0] = (__bf16)nv[0][e4]; h[1] = (__bf16)nv[1][e4];
          h[2] = (__bf16)nv[2][e4]; h[3] = (__bf16)nv[3][e4];
          *(bf16x4*)&Bsl[cur ^ 1][cb * 4 + e4][kb * 4] = h;
        }
      }
      __syncthreads();
      cur ^= 1;
    }
#pragma unroll
    for (int mi = 0; mi < 4; mi++)
#pragma unroll
      for (int ni = 0; ni < 4; ni++)
#pragma unroll
        for (int r = 0; r < 4; r++) {
          int rl = bm * 128 + wr * 64 + mi * 16 + kl * 4 + r;
          int col = n0 + wc * 64 + ni * 16 + l16;
          if (rl < cnt && col < N) Cpl[(size_t)(base + rl) * N + col] = acc[mi][ni][r];
        }
  }
}

// ---------------- routed: reduce gate/up partials + silu-mul + scale -> swizzled bf16 ----------------
__global__ __launch_bounds__(256) void k_silumulE(const float* __restrict__ gP,
                                                  const float* __restrict__ uP,
                                                  const float* __restrict__ slotw,
                                                  __bf16* __restrict__ outp) {
  int s = blockIdx.x, tid = threadIdx.x;
  float w = slotw[s];
  int P = (s >> 1) & 3;
  const size_t PL = (size_t)NSLOTP * M_INTER;
  for (int i = tid; i < M_INTER / 4; i += 256) {
    f32x4 g = f32x4{0.f, 0.f, 0.f, 0.f}, u = f32x4{0.f, 0.f, 0.f, 0.f};
#pragma unroll
    for (int z = 0; z < 4; z++) {
      g += *(const f32x4*)&gP[z * PL + (size_t)s * M_INTER + i * 4];
      u += *(const f32x4*)&uP[z * PL + (size_t)s * M_INTER + i * 4];
    }
    int p = swz_p(i * 4, P);
    bf16x4 h;
    h[0] = (__bf16)(siluf(g[0]) * u[0] * w);
    h[1] = (__bf16)(siluf(g[1]) * u[1] * w);
    h[2] = (__bf16)(siluf(g[2]) * u[2] * w);
    h[3] = (__bf16)(siluf(g[3]) * u[3] * w);
    *(bf16x4*)&outp[(size_t)s * M_INTER + p] = h;
  }
}

// ---------------- shared: reduce combined gate|up partials + silu-mul -> swizzled bf16 ----------------
__global__ __launch_bounds__(256) void k_silumul_sh2(const float* __restrict__ P4,
                                                     __bf16* __restrict__ outp) {
  int t = blockIdx.x, tid = threadIdx.x;
  int P = (t >> 1) & 3;
  const size_t PL = (size_t)SEQ * 3456;
  for (int i = tid; i < MS_INTER / 4; i += 256) {
    f32x4 g = f32x4{0.f, 0.f, 0.f, 0.f}, u = f32x4{0.f, 0.f, 0.f, 0.f};
#pragma unroll
    for (int z = 0; z < 4; z++) {
      g += *(const f32x4*)&P4[z * PL + (size_t)t * 3456 + i * 4];
      u += *(const f32x4*)&P4[z * PL + (size_t)t * 3456 + 1728 + i * 4];
    }
    int p = swz_p(i * 4, P);
    bf16x4 h;
    h[0] = (__bf16)(siluf(g[0]) * u[0]);
    h[1] = (__bf16)(siluf(g[1]) * u[1]);
    h[2] = (__bf16)(siluf(g[2]) * u[2]);
    h[3] = (__bf16)(siluf(g[3]) * u[3]);
    *(bf16x4*)&outp[(size_t)t * MS_INTER + p] = h;
  }
}

// ---------------- dt softplus ----------------
__global__ void k_dt(const float* __restrict__ zx, const float* __restrict__ dt_bias,
                     const float* __restrict__ A_log, float* __restrict__ dtp,
                     float* __restrict__ dtA) {
  int t = blockIdx.x, h = threadIdx.x;
  if (h < HEADS) {
    float v = zx[(size_t)t * D_INPROJ + 10496 + h] + dt_bias[h];
    float sp = fmaxf(v, 0.f) + log1pf(expf(-fabsf(v)));
    dtp[t * HEADS + h] = sp;
    dtA[t * HEADS + h] = sp * (-expf(A_log[h]));
  }
}

// ---------------- causal depthwise conv + SiLU ----------------
__global__ void k_conv(const float* __restrict__ zx, const float* __restrict__ cw,
                       const float* __restrict__ cb, float* __restrict__ xBC) {
  int cidx = blockIdx.x * 256 + threadIdx.x;
  int t = blockIdx.y;
  if (cidx < CONV_DIM) {
    float acc = cb[cidx];
#pragma unroll
    for (int j = 0; j < 4; j++) {
      int tt = t - 3 + j;
      if (tt >= 0) acc += zx[(size_t)tt * D_INPROJ + D_INNER + cidx] * cw[cidx * 4 + j];
    }
    xBC[(size_t)t * CONV_DIM + cidx] = siluf(acc);
  }
}

// ---------------- scan: intra-chunk ----------------
__global__ __launch_bounds__(256) void k_scan_intra(
    const float* __restrict__ xBC, const float* __restrict__ dtp,
    const float* __restrict__ dtA, float* __restrict__ y, float* __restrict__ S,
    float* __restrict__ cumA, float* __restrict__ Atot) {
  __shared__ float Bs[64][132];
  __shared__ float Cs[64][132];
  __shared__ float Xs[64][68];
  __shared__ float Gs[64][65];
  __shared__ float da_s[64], a_s[64], dt_sh[64], w_sh[64];
  int c = blockIdx.x, h = blockIdx.y, tid = threadIdx.x;
  int t0 = c * QCHUNK;
#pragma unroll
  for (int i = 0; i < 8; i++) {
    int id = tid + 256 * i;
    int r = id >> 5, c4 = (id & 31) * 4;
    *(float4*)&Bs[r][c4] = *(const float4*)&xBC[(size_t)(t0 + r) * CONV_DIM + D_INNER + c4];
    *(float4*)&Cs[r][c4] = *(const float4*)&xBC[(size_t)(t0 + r) * CONV_DIM + D_INNER + N_STATE + c4];
  }
#pragma unroll
  for (int i = 0; i < 4; i++) {
    int id = tid + 256 * i;
    int r = id >> 4, p4 = (id & 15) * 4;
    *(float4*)&Xs[r][p4] = *(const float4*)&xBC[(size_t)(t0 + r) * CONV_DIM + h * P_HEAD + p4];
  }
  if (tid < 64) {
    da_s[tid] = dtA[(size_t)(t0 + tid) * HEADS + h];
    dt_sh[tid] = dtp[(size_t)(t0 + tid) * HEADS + h];
  }
  __syncthreads();
  if (tid < 64) {
    float a = 0.f;
    for (int i = 0; i <= tid; i++) a += da_s[i];
    a_s[tid] = a;
    cumA[((size_t)c * HEADS + h) * 64 + tid] = a;
  }
  __syncthreads();
  if (tid < 64) {
    w_sh[tid] = __expf(a_s[63] - a_s[tid]) * dt_sh[tid];
    if (tid == 0) Atot[c * HEADS + h] = a_s[63];
  }
  __syncthreads();
  {
    int tq = tid >> 4, sq = tid & 15;
    float gacc[4][4];
#pragma unroll
    for (int j = 0; j < 4; j++)
#pragma unroll
      for (int jj = 0; jj < 4; jj++) gacc[j][jj] = 0.f;
    for (int n4 = 0; n4 < 128; n4 += 4) {
      float4 cv[4], bv[4];
#pragma unroll
      for (int j = 0; j < 4; j++) cv[j] = *(const float4*)&Cs[tq * 4 + j][n4];
#pragma unroll
      for (int j = 0; j < 4; j++) bv[j] = *(const float4*)&Bs[sq * 4 + j][n4];
#pragma unroll
      for (int j = 0; j < 4; j++)
#pragma unroll
        for (int jj = 0; jj < 4; jj++)
          gacc[j][jj] += cv[j].x * bv[jj].x + cv[j].y * bv[jj].y + cv[j].z * bv[jj].z + cv[j].w * bv[jj].w;
    }
#pragma unroll
    for (int j = 0; j < 4; j++)
#pragma unroll
      for (int jj = 0; jj < 4; jj++) {
        int t = tq * 4 + j, s = sq * 4 + jj;
        float arg = fminf(a_s[t] - a_s[s], 0.f);
        Gs[t][s] = (s <= t) ? gacc[j][jj] * __expf(arg) * dt_sh[s] : 0.f;
      }
  }
  __syncthreads();
  {
    int tq = tid >> 4, pq = tid & 15;
    float4 acc[4];
#pragma unroll
    for (int j = 0; j < 4; j++) acc[j] = float4{0.f, 0.f, 0.f, 0.f};
    for (int s = 0; s < 64; s++) {
      float4 xv = *(const float4*)&Xs[s][pq * 4];
#pragma unroll
      for (int j = 0; j < 4; j++) {
        float g = Gs[tq * 4 + j][s];
        acc[j].x += g * xv.x; acc[j].y += g * xv.y; acc[j].z += g * xv.z; acc[j].w += g * xv.w;
      }
    }
#pragma unroll
    for (int j = 0; j < 4; j++) {
      int t = tq * 4 + j;
      *(float4*)&y[(size_t)(t0 + t) * D_INNER + h * P_HEAD + pq * 4] = acc[j];
    }
  }
  {
    int p2 = tid >> 5, n4 = (tid & 31) * 4;
    float4 acc[8];
#pragma unroll
    for (int j = 0; j < 8; j++) acc[j] = float4{0.f, 0.f, 0.f, 0.f};
    for (int s = 0; s < 64; s++) {
      float4 bv = *(const float4*)&Bs[s][n4];
#pragma unroll
      for (int j = 0; j < 8; j++) {
        float xw = Xs[s][p2 * 8 + j] * w_sh[s];
        acc[j].x += xw * bv.x; acc[j].y += xw * bv.y; acc[j].z += xw * bv.z; acc[j].w += xw * bv.w;
      }
    }
    size_t bb = ((size_t)(c * HEADS + h) * 64) * 128;
#pragma unroll
    for (int j = 0; j < 8; j++)
      *(float4*)&S[bb + (size_t)(p2 * 8 + j) * 128 + n4] = acc[j];
  }
}

// ---------------- scan: inter-chunk state recurrence ----------------
__global__ void k_scan_state(float* __restrict__ S, const float* __restrict__ Atot) {
  int gid = blockIdx.x * 256 + threadIdx.x;
  int h = gid >> 13;
  int rem = gid & 8191;
  float run = 0.f;
#pragma unroll
  for (int c = 0; c < NCHUNK; c++) {
    size_t idx = ((size_t)(c * HEADS + h) << 13) + rem;
    float s = S[idx];
    S[idx] = run;
    run = run * __expf(Atot[c * HEADS + h]) + s;
  }
}

// ---------------- scan: inter-chunk contribution + D*x ----------------
__global__ __launch_bounds__(256) void k_scan_inter(
    const float* __restrict__ xBC, const float* __restrict__ Hin,
    const float* __restrict__ cumA, const float* __restrict__ Dv,
    float* __restrict__ y) {
  __shared__ float Hs[64][132];
  __shared__ float Cs[64][132];
  __shared__ float a_l[64];
  int c = blockIdx.x, h = blockIdx.y, tid = threadIdx.x;
  int t0 = c * QCHUNK;
#pragma unroll
  for (int i = 0; i < 8; i++) {
    int id = tid + 256 * i;
    int r = id >> 5, n4 = (id & 31) * 4;
    *(float4*)&Hs[r][n4] = *(const float4*)&Hin[(((size_t)(c * HEADS + h) * 64 + r) << 7) + n4];
    *(float4*)&Cs[r][n4] = *(const float4*)&xBC[(size_t)(t0 + r) * CONV_DIM + D_INNER + N_STATE + n4];
  }
  if (tid < 64) a_l[tid] = cumA[((size_t)c * HEADS + h) * 64 + tid];
  __syncthreads();
  float Dh = Dv[h];
  int tq = tid >> 4, pq = tid & 15;
  float4 acc[4];
#pragma unroll
  for (int j = 0; j < 4; j++) acc[j] = float4{0.f, 0.f, 0.f, 0.f};
  for (int n4 = 0; n4 < 128; n4 += 4) {
    float4 hv[4], cv[4];
#pragma unroll
    for (int jj = 0; jj < 4; jj++) hv[jj] = *(const float4*)&Hs[pq * 4 + jj][n4];
#pragma unroll
    for (int j = 0; j < 4; j++) cv[j] = *(const float4*)&Cs[tq * 4 + j][n4];
#pragma unroll
    for (int j = 0; j < 4; j++) {
      acc[j].x += cv[j].x * hv[0].x + cv[j].y * hv[0].y + cv[j].z * hv[0].z + cv[j].w * hv[0].w;
      acc[j].y += cv[j].x * hv[1].x + cv[j].y * hv[1].y + cv[j].z * hv[1].z + cv[j].w * hv[1].w;
      acc[j].z += cv[j].x * hv[2].x + cv[j].y * hv[2].y + cv[j].z * hv[2].z + cv[j].w * hv[2].w;
      acc[j].w += cv[j].x * hv[3].x + cv[j].y * hv[3].y + cv[j].z * hv[3].z + cv[j].w * hv[3].w;
    }
  }
#pragma unroll
  for (int j = 0; j < 4; j++) {
    int t = tq * 4 + j;
    float e = __expf(a_l[t]);
    float4 xv = *(const float4*)&xBC[(size_t)(t0 + t) * CONV_DIM + h * P_HEAD + pq * 4];
    size_t yoff = (size_t)(t0 + t) * D_INNER + h * P_HEAD + pq * 4;
    float4 yv = *(float4*)&y[yoff];
    yv.x += e * acc[j].x + Dh * xv.x;
    yv.y += e * acc[j].y + Dh * xv.y;
    yv.z += e * acc[j].z + Dh * xv.z;
    yv.w += e * acc[j].w + Dh * xv.w;
    *(float4*)&y[yoff] = yv;
  }
}

// ---------------- gated RMSNorm -> swizzled bf16 planes ----------------
__global__ __launch_bounds__(256) void k_gatednorm_p(const float* __restrict__ y,
                                                     const float* __restrict__ zx,
                                                     const float* __restrict__ w,
                                                     __bf16* __restrict__ ph,
                                                     __bf16* __restrict__ pl) {
  __shared__ float vbuf[D_INNER];
  __shared__ float red[4];
  int t = blockIdx.x, tid = threadIdx.x;
  float ss = 0.f;
  for (int i = tid; i < D_INNER / 4; i += 256) {
    float4 yv = *(const float4*)&y[(size_t)t * D_INNER + i * 4];
    float4 zv = *(const float4*)&zx[(size_t)t * D_INPROJ + i * 4];
    float4 v;
    v.x = yv.x * siluf(zv.x); v.y = yv.y * siluf(zv.y);
    v.z = yv.z * siluf(zv.z); v.w = yv.w * siluf(zv.w);
    *(float4*)&vbuf[i * 4] = v;
    ss += v.x * v.x + v.y * v.y + v.z * v.z + v.w * v.w;
  }
  float tot = block_sum256(ss, red);
  float r = rsqrtf(tot / (float)D_INNER + 1e-6f);
  int P = (t >> 1) & 3;
  for (int i = tid; i < D_INNER / 4; i += 256) {
    float4 v = *(const float4*)&vbuf[i * 4];
    float4 wv = *(const float4*)&w[i * 4];
    float4 o;
    o.x = wv.x * v.x * r; o.y = wv.y * v.y * r; o.z = wv.z * v.z * r; o.w = wv.w * v.w * r;
    int p = swz_p(i * 4, P);
    bf16x4 hv;
    hv[0] = (__bf16)o.x; hv[1] = (__bf16)o.y; hv[2] = (__bf16)o.z; hv[3] = (__bf16)o.w;
    *(bf16x4*)&ph[(size_t)t * D_INNER + p] = hv;
    bf16x4 lv;
    lv[0] = (__bf16)(o.x - (float)hv[0]); lv[1] = (__bf16)(o.y - (float)hv[1]);
    lv[2] = (__bf16)(o.z - (float)hv[2]); lv[3] = (__bf16)(o.w - (float)hv[3]);
    *(bf16x4*)&pl[(size_t)t * D_INNER + p] = lv;
  }
}

// ---------------- router ----------------
__global__ void k_zero(int* counts, int* cursor) {
  int i = threadIdx.x;
  if (i < NEXP) { counts[i] = 0; cursor[i] = 0; }
}

__global__ __launch_bounds__(256) void k_router(const float* __restrict__ xm,
                                                const float* __restrict__ Wr,
                                                int* __restrict__ top_i,
                                                float* __restrict__ top_v,
                                                int* __restrict__ counts) {
  __shared__ float part[16][17];
  __shared__ float lg[16];
  int t = blockIdx.x, tid = threadIdx.x;
  int e = tid & 15, seg = tid >> 4;
  const float* xr = xm + (size_t)t * D_MODEL;
  float s = 0.f;
  for (int i = 0; i < 160; i++) {
    int k = seg * 160 + i;
    s += xr[k] * Wr[(size_t)k * NEXP + e];
  }
  part[seg][e] = s;
  __syncthreads();
  if (tid < 16) {
    float l = 0.f;
    for (int g = 0; g < 16; g++) l += part[g][tid];
    lg[tid] = l;
  }
  __syncthreads();
  if (tid == 0) {
    float mx = lg[0];
    for (int i = 1; i < 16; i++) mx = fmaxf(mx, lg[i]);
    float pe[16];
    for (int i = 0; i < 16; i++) pe[i] = expf(lg[i] - mx);
    int i0 = 0; float v0 = pe[0];
    for (int i = 1; i < 16; i++) if (pe[i] > v0) { v0 = pe[i]; i0 = i; }
    int i1 = -1; float v1 = -1.f;
    for (int i = 0; i < 16; i++) if (i != i0 && pe[i] > v1) { v1 = pe[i]; i1 = i; }
    float inv = 1.f / (v0 + v1);
    top_i[t * 2] = i0; top_i[t * 2 + 1] = i1;
    top_v[t * 2] = v0 * inv; top_v[t * 2 + 1] = v1 * inv;
    atomicAdd(&counts[i0], 1);
    atomicAdd(&counts[i1], 1);
  }
}

__global__ void k_offsets(const int* counts, int* offs, int* cursor) {
  if (threadIdx.x == 0) {
    int s = 0;
    for (int e = 0; e < NEXP; e++) { offs[e] = s; cursor[e] = s; s += counts[e]; }
  }
}

__global__ void k_scatter(const int* __restrict__ top_i, const float* __restrict__ top_v,
                          int* __restrict__ cursor, int* __restrict__ perm,
                          int* __restrict__ slotOf, float* __restrict__ slotw) {
  int t = blockIdx.x * 256 + threadIdx.x;
  if (t < SEQ) {
    for (int k = 0; k < 2; k++) {
      int e = top_i[t * 2 + k];
      int pos = atomicAdd(&cursor[e], 1);
      perm[pos] = t;
      slotOf[t * 2 + k] = pos;
      slotw[pos] = top_v[t * 2 + k];
    }
  }
}

// ---------------- final combine (3 down-partial planes) ----------------
__global__ void k_final2(const float* __restrict__ hidden, const float* __restrict__ sh,
                         const float* __restrict__ dsP, const int* __restrict__ slotOf,
                         float* __restrict__ out) {
  int t = blockIdx.y;
  int d4 = (blockIdx.x * 256 + threadIdx.x) * 4;
  if (d4 < D_MODEL) {
    int s0 = slotOf[t * 2], s1 = slotOf[t * 2 + 1];
    f32x4 a = *(const f32x4*)&hidden[(size_t)t * D_MODEL + d4];
    f32x4 b = *(const f32x4*)&sh[(size_t)t * D_MODEL + d4];
    f32x4 acc = a + b;
    const size_t PL = (size_t)NSLOTP * D_MODEL;
#pragma unroll
    for (int z = 0; z < 3; z++) {
      acc += *(const f32x4*)&dsP[z * PL + (size_t)s0 * D_MODEL + d4];
      acc += *(const f32x4*)&dsP[z * PL + (size_t)s1 * D_MODEL + d4];
    }
    *(f32x4*)&out[(size_t)t * D_MODEL + d4] = acc;
  }
}

// ---------------- launch ----------------
extern "C" void kernel_launch(void* const* d_in, const int* in_sizes, int n_in,
                              void* d_out, int out_size, void* d_ws, size_t ws_size,
                              hipStream_t stream) {
  const float* hs = (const float*)d_in[0];
  const float* w_in = (const float*)d_in[1];
  const float* conv_w = (const float*)d_in[2];
  const float* conv_b = (const float*)d_in[3];
  const float* dt_bias = (const float*)d_in[4];
  const float* A_log = (const float*)d_in[5];
  const float* Dv = (const float*)d_in[6];
  const float* mnw = (const float*)d_in[7];
  const float* w_out = (const float*)d_in[8];
  const float* ln1 = (const float*)d_in[9];
  const float* ln2 = (const float*)d_in[10];
  const float* router_w = (const float*)d_in[11];
  const float* we_gate = (const float*)d_in[12];
  const float* we_up = (const float*)d_in[13];
  const float* we_down = (const float*)d_in[14];
  const float* ws_gate = (const float*)d_in[15];
  const float* ws_up = (const float*)d_in[16];
  const float* ws_down = (const float*)d_in[17];

  char* base = (char*)d_ws;
  size_t off = 0;
  auto A = [&](size_t bytes) -> void* {
    void* p = base + off;
    off += (bytes + 255) & ~(size_t)255;
    return p;
  };
  float* zx = (float*)A((size_t)SEQ * D_INPROJ * 4);
  float* xbc = (float*)A((size_t)SEQ * CONV_DIM * 4);
  float* xmf = (float*)A((size_t)SEQ * D_MODEL * 4);
  float* dtp = (float*)A((size_t)SEQ * HEADS * 4);
  float* dtA = (float*)A((size_t)SEQ * HEADS * 4);
  float* yf = (float*)A((size_t)SEQ * D_INNER * 4);
  float* cumA = (float*)A((size_t)NCHUNK * HEADS * 64 * 4);
  float* Atot = (float*)A((size_t)NCHUNK * HEADS * 4);
  float* Sbuf = (float*)A((size_t)NCHUNK * HEADS * 64 * 128 * 4);
  float* hidden = (float*)A((size_t)SEQ * D_MODEL * 4);
  float* shout = (float*)A((size_t)SEQ * D_MODEL * 4);
  float* top_v = (float*)A(8192);
  float* slotw = (float*)A(8192);
  int* top_i = (int*)A(8192);
  int* counts = (int*)A(64);
  int* offs = (int*)A(64);
  int* cursor = (int*)A(64);
  int* perm = (int*)A(8192);
  int* slotOf = (int*)A(8192);
  __bf16* xp_h = (__bf16*)A((size_t)SEQ * D_MODEL * 2);
  __bf16* xp_l = (__bf16*)A((size_t)SEQ * D_MODEL * 2);
  __bf16* ybp_h = (__bf16*)A((size_t)SEQ * D_INNER * 2);
  __bf16* ybp_l = (__bf16*)A((size_t)SEQ * D_INNER * 2);
  __bf16* gbuf_bh = (__bf16*)A((size_t)SEQ * MS_INTER * 2);
  char* REG = (char*)A((size_t)146000000);

  // Phase M aliases
  __bf16* winT_h = (__bf16*)REG;                       // [10624][2560]
  __bf16* winT_l = (__bf16*)(REG + 54394880);
  __bf16* woutT_h = (__bf16*)REG;                      // [2560][5120]
  __bf16* woutT_l = (__bf16*)(REG + 26214400);
  float* partials = (float*)(REG + 60000000);          // 4x1024x2560 f32
  // Phase S aliases
  __bf16* guT = (__bf16*)REG;                          // [3456][2560] (gate | up)
  __bf16* downT = (__bf16*)(REG + 18350080);           // [2560][1728]
  float* partials4 = (float*)(REG + 30000000);         // 4x[1024][3456] f32 (56.6 MB)
  // Phase R aliases
  __bf16* Aslots = (__bf16*)REG;                       // [2176][2560]
  __bf16* gsl = (__bf16*)(REG + 12000000);             // [2176][864]
  float* gateP = (float*)(REG + 16000000);             // 4x[2176][864]
  float* upP = (float*)(REG + 47000000);
  float* dslotsP = (float*)(REG + 78000000);           // 3x[2176][2560]

  // ---- Mamba sub-block ----
  k_rmsnorm_p<<<SEQ, 256, 0, stream>>>(hs, ln1, nullptr, xp_h, xp_l, D_MODEL);
  k_transW<true><<<dim3(166, 40), 256, 0, stream>>>(w_in, D_MODEL, D_INPROJ, winT_h, winT_l);
  k_gemm2<true><<<dim3(8, 83, 1), 256, 0, stream>>>(xp_h, xp_l, winT_h, winT_l, zx,
                                                    SEQ, D_INPROJ, D_MODEL, 1, 80);
  k_dt<<<SEQ, 128, 0, stream>>>(zx, dt_bias, A_log, dtp, dtA);
  k_conv<<<dim3(21, SEQ), 256, 0, stream>>>(zx, conv_w, conv_b, xbc);
  k_scan_intra<<<dim3(NCHUNK, HEADS), 256, 0, stream>>>(xbc, dtp, dtA, yf, Sbuf, cumA, Atot);
  k_scan_state<<<2560, 256, 0, stream>>>(Sbuf, Atot);
  k_scan_inter<<<dim3(NCHUNK, HEADS), 256, 0, stream>>>(xbc, Sbuf, cumA, Dv, yf);
  k_gatednorm_p<<<SEQ, 256, 0, stream>>>(yf, zx, mnw, ybp_h, ybp_l);
  k_transW<true><<<dim3(40, 80), 256, 0, stream>>>(w_out, D_INNER, D_MODEL, woutT_h, woutT_l);
  k_gemm2<true><<<dim3(8, 20, 4), 256, 0, stream>>>(ybp_h, ybp_l, woutT_h, woutT_l, partials,
                                                    SEQ, D_MODEL, D_INNER, 4, 160);
  k_reduce<true><<<2048, 256, 0, stream>>>(partials, 4, SEQ * D_MODEL / 4, hs, hidden);

  // ---- MoE sub-block ----
  k_rmsnorm_p<<<SEQ, 256, 0, stream>>>(hidden, ln2, xmf, xp_h, nullptr, D_MODEL);
  k_zero<<<1, 64, 0, stream>>>(counts, cursor);
  k_router<<<SEQ, 256, 0, stream>>>(xmf, router_w, top_i, top_v, counts);
  k_offsets<<<1, 32, 0, stream>>>(counts, offs, cursor);
  k_scatter<<<4, 256, 0, stream>>>(top_i, top_v, cursor, perm, slotOf, slotw);

  // shared experts: combined gate|up GEMM (N=3456), fused reduce+silu
  k_transW<false><<<dim3(27, 40), 256, 0, stream>>>(ws_gate, D_MODEL, MS_INTER, guT, nullptr);
  k_transW<false><<<dim3(27, 40), 256, 0, stream>>>(ws_up, D_MODEL, MS_INTER,
                                                    guT + (size_t)MS_INTER * D_MODEL, nullptr);
  k_gemm2<false><<<dim3(8, 27, 4), 256, 0, stream>>>(xp_h, nullptr, guT, nullptr, partials4,
                                                     SEQ, 3456, D_MODEL, 4, 80);
  k_silumul_sh2<<<SEQ, 256, 0, stream>>>(partials4, gbuf_bh);
  k_transW<false><<<dim3(40, 27), 256, 0, stream>>>(ws_down, MS_INTER, D_MODEL, downT, nullptr);
  k_gemm2<false><<<dim3(8, 20, 4), 256, 0, stream>>>(gbuf_bh, nullptr, downT, nullptr, partials4,
                                                     SEQ, D_MODEL, MS_INTER, 4, 54);
  k_reduce<false><<<2048, 256, 0, stream>>>(partials4, 4, SEQ * D_MODEL / 4, nullptr, shout);

  // routed experts
  k_gatherA<<<NSLOT, 256, 0, stream>>>(xmf, perm, Aslots);
  k_gemmE2<4><<<dim3(7, 4, NEXP), 256, 0, stream>>>(Aslots, we_gate, gateP, offs, counts,
                                                    M_INTER, D_MODEL, (long long)D_MODEL * M_INTER);
  k_gemmE2<4><<<dim3(7, 4, NEXP), 256, 0, stream>>>(Aslots, we_up, upP, offs, counts,
                                                    M_INTER, D_MODEL, (long long)D_MODEL * M_INTER);
  k_silumulE<<<NSLOT, 256, 0, stream>>>(gateP, upP, slotw, gsl);
  k_gemmE2<3><<<dim3(20, 3, NEXP), 256, 0, stream>>>(gsl, we_down, dslotsP, offs, counts,
                                                     D_MODEL, M_INTER, (long long)M_INTER * D_MODEL);

  k_final2<<<dim3(3, SEQ), 256, 0, stream>>>(hidden, shout, dslotsP, slotOf, (float*)d_out);
}